// Round 8
// baseline (925.917 us; speedup 1.0000x reference)
//
#include <hip/hip_runtime.h>
#include <stdint.h>

#define SEQ  5120
#define DIMX 512
#define E2   2048
#define DI   1024
#define NST  16
#define DTR  32
#define KXP  64
#define LGS  2048
#define NSL  5
#define NSEG 8
#define SEGL 640

typedef unsigned short ushort_t;
typedef __attribute__((ext_vector_type(8))) __bf16 bf16x8;
typedef __attribute__((ext_vector_type(4))) float f32x4;

__device__ __forceinline__ float b2f(ushort_t u) {
  union { unsigned int i; float f; } v; v.i = ((unsigned int)u) << 16; return v.f;
}
__device__ __forceinline__ ushort_t f2b(float f) {
  union { float f; unsigned int i; } v; v.f = f;
  unsigned int u = v.i;
  return (ushort_t)((u + 0x7FFFu + ((u >> 16) & 1u)) >> 16);
}

#define AS1 __attribute__((address_space(1)))
#define AS3 __attribute__((address_space(3)))
__device__ __forceinline__ void glds16(const void* g, void* l) {
  __builtin_amdgcn_global_load_lds((const AS1 void*)g, (AS3 void*)l, 16, 0, 0);
}

__device__ __forceinline__ int pmap(int br, int t) {   // scan pos -> data pos
  return (br == 0) ? t : (br == 1) ? (SEQ - 1 - t) : ((t % NSL) * 1024 + t / NSL);
}
__device__ __forceinline__ int omap(int br, int t) {   // scan pos -> output pos
  return (br == 0) ? t : (br == 1) ? (SEQ - 1 - t) : ((t & 1023) * NSL + (t >> 10));
}

// 16-state transpose-reduce butterfly: input hC[k] per lane(n) holding state n,
// output: lane n holds sum over states for timestep-slot n.
__device__ __forceinline__ float bfly16(const float* hC, int n) {
  float a8[8], a4[4], a2[2], y;
#pragma unroll
  for (int j = 0; j < 8; j++) {
    float keep = (n & 8) ? hC[j+8] : hC[j];
    float send = (n & 8) ? hC[j]   : hC[j+8];
    a8[j] = keep + __shfl_xor(send, 8, 64);
  }
#pragma unroll
  for (int j = 0; j < 4; j++) {
    float keep = (n & 4) ? a8[j+4] : a8[j];
    float send = (n & 4) ? a8[j]   : a8[j+4];
    a4[j] = keep + __shfl_xor(send, 4, 64);
  }
#pragma unroll
  for (int j = 0; j < 2; j++) {
    float keep = (n & 2) ? a4[j+2] : a4[j];
    float send = (n & 2) ? a4[j]   : a4[j+2];
    a2[j] = keep + __shfl_xor(send, 2, 64);
  }
  {
    float keep = (n & 1) ? a2[1] : a2[0];
    float send = (n & 1) ? a2[0] : a2[1];
    y = keep + __shfl_xor(send, 1, 64);
  }
  return y;
}

// ---------------- workspace layout (bytes) ------------------------------------
#define OFF_LWB   ((size_t)256)
#define OFF_LNGF  ((size_t)1280)
#define OFF_LNBF  ((size_t)3328)
#define OFF_LBF   ((size_t)5376)
#define OFF_CWF   ((size_t)5632)
#define OFF_CBF   ((size_t)54784)
#define OFF_DTBF  ((size_t)67072)
#define OFF_ALF   ((size_t)79360)
#define OFF_DDF   ((size_t)275968)
#define OFF_WEFF  ((size_t)288256)
#define OFF_SC    ((size_t)292352)
#define OFF_DTWB  ((size_t)333312)      // bf16 dt_w, 3*1024*32*2 = 196,608
#define OFF_XPWB  ((size_t)529920)
#define OFF_OPWB  ((size_t)923136)
#define OFF_INWB  ((size_t)1971712)     // ends 4,068,864
#define OFF_XD    ((size_t)4068864)     // 6*5120*64*2 = 3,932,160 -> 8,001,024
#define OFF_DLTB  ((size_t)8001024)     // 6*5120*1024*2 = 62,914,560 -> 70,915,584
#define OFF_XZ    OFF_DLTB              // xz (42 MB) nested; dead before k_delta writes
#define OFF_BF    ((size_t)70915584)    // 1,966,080 -> 72,881,664
#define OFF_CF    ((size_t)72881664)    // 1,966,080 -> 74,847,744
#define OFF_HLOC  ((size_t)74847744)    // 3,145,728 -> 77,993,472
#define OFF_HIN   ((size_t)77993472)    // 3,145,728 -> 81,139,200
#define OFF_STOT  ((size_t)81139200)    // 196,608  -> 81,335,808
#define OFF_UB    ((size_t)81335808)    // 62,914,560 -> 144,250,368
#define OFF_H     OFF_UB                // ln-out h (10 MB) nested; dead before conv
#define OFF_ZGB   ((size_t)144250368)   // 20,971,520 -> 165,221,888
// total ~165.2 MiB

// ---------------- K0: batched import (f32 params -> ws, bf16 or f32) ----------
struct Ent { const void* s; void* d; int n; int fmt; };
struct Tab { Ent e[32]; };

__global__ __launch_bounds__(256) void k_import(Tab t, int cnt) {
  int id = blockIdx.y;
  if (id >= cnt) return;
  Ent E = t.e[id];
  int stride = gridDim.x * 256;
  const float* s = (const float*)E.s;
  if (E.fmt == 0) {
    ushort_t* dst = (ushort_t*)E.d;
    for (int i = blockIdx.x * 256 + threadIdx.x; i < E.n; i += stride) dst[i] = f2b(s[i]);
  } else {
    float* dst = (float*)E.d;
    for (int i = blockIdx.x * 256 + threadIdx.x; i < E.n; i += stride) dst[i] = s[i];
  }
}

// ---------------- K1: LayerNorm + ReLU -> h (bf16, both batches) --------------
__global__ __launch_bounds__(256) void k_ln(const float* __restrict__ x,
    const float* __restrict__ gam, const float* __restrict__ bet,
    ushort_t* __restrict__ h) {
  int token = blockIdx.x * 4 + (threadIdx.x >> 6);
  int lane = threadIdx.x & 63;
  const float* row = x + (size_t)token * DIMX + lane * 8;
  float4 a0 = *(const float4*)(row);
  float4 a1 = *(const float4*)(row + 4);
  float v[8] = {a0.x,a0.y,a0.z,a0.w,a1.x,a1.y,a1.z,a1.w};
  float s = 0.f, ss = 0.f;
#pragma unroll
  for (int i = 0; i < 8; i++) { s += v[i]; ss += v[i]*v[i]; }
#pragma unroll
  for (int m = 1; m < 64; m <<= 1) { s += __shfl_xor(s, m, 64); ss += __shfl_xor(ss, m, 64); }
  float mean = s * (1.f / DIMX);
  float rs = rsqrtf(ss * (1.f / DIMX) - mean * mean + 1e-5f);
  ushort_t o[8];
#pragma unroll
  for (int i = 0; i < 8; i++) {
    float y = (v[i] - mean) * rs * gam[lane*8+i] + bet[lane*8+i];
    o[i] = f2b(fmaxf(y, 0.f));
  }
  ushort_t* orow = h + (size_t)token * DIMX + lane * 8;
  *(ushort4*)(orow)     = make_ushort4(o[0],o[1],o[2],o[3]);
  *(ushort4*)(orow + 4) = make_ushort4(o[4],o[5],o[6],o[7]);
}

// ---------------- K2: in_proj GEMM (M=10240): xz[bl][e] = h @ W^T -------------
__global__ __launch_bounds__(256) void k_inproj(const ushort_t* __restrict__ hA,
    const ushort_t* __restrict__ Wb, ushort_t* __restrict__ xz) {
  __shared__ ushort_t As[128*32];
  __shared__ ushort_t Bs[128*32];
  const int tid = threadIdx.x;
  const int w = tid >> 6, lane = tid & 63;
  const int wr = w >> 1, wc = w & 1;
  const int m0 = blockIdx.x * 128, n0 = blockIdx.y * 128;
  const int lrow = lane & 15, lko = (lane >> 4) * 8;
  f32x4 acc[4][4];
#pragma unroll
  for (int i = 0; i < 4; i++)
#pragma unroll
    for (int j = 0; j < 4; j++) acc[i][j] = (f32x4){0.f,0.f,0.f,0.f};
  for (int k0 = 0; k0 < DIMX; k0 += 32) {
    __syncthreads();
#pragma unroll
    for (int r = 0; r < 2; r++) {
      int e = r * 256 + tid;
      int row = e >> 2, seg = e & 3;
      glds16(hA + (size_t)(m0 + row) * DIMX + k0 + seg * 8, &As[row*32 + seg*8]);
      glds16(Wb + (size_t)(n0 + row) * DIMX + k0 + seg * 8, &Bs[row*32 + seg*8]);
    }
    __syncthreads();
    bf16x8 aF[4], bF[4];
#pragma unroll
    for (int i = 0; i < 4; i++)
      aF[i] = *(const bf16x8*)&As[(wr*64 + i*16 + lrow)*32 + lko];
#pragma unroll
    for (int j = 0; j < 4; j++)
      bF[j] = *(const bf16x8*)&Bs[(wc*64 + j*16 + lrow)*32 + lko];
#pragma unroll
    for (int i = 0; i < 4; i++)
#pragma unroll
      for (int j = 0; j < 4; j++)
        acc[i][j] = __builtin_amdgcn_mfma_f32_16x16x32_bf16(aF[i], bF[j], acc[i][j], 0, 0, 0);
  }
#pragma unroll
  for (int i = 0; i < 4; i++)
#pragma unroll
    for (int j = 0; j < 4; j++)
#pragma unroll
      for (int r = 0; r < 4; r++) {
        int m = m0 + wr*64 + i*16 + (lane>>4)*4 + r;
        int n = n0 + wc*64 + j*16 + lrow;
        xz[(size_t)m * E2 + n] = f2b(acc[i][j][r]);
      }
}

// ---------------- K4: conv + silu -> uB[ch][d>>4][t][16] (blocked) ------------
__global__ __launch_bounds__(256) void k_conv(const ushort_t* __restrict__ xz,
    const float* __restrict__ cwA, const float* __restrict__ cbA,
    ushort_t* __restrict__ uB) {
  __shared__ ushort_t xs[67][64];
  int ch = blockIdx.z, br = ch >> 1, b = ch & 1;
  int t0 = blockIdx.x * 64, d0 = blockIdx.y * 64;
  int tid = threadIdx.x, col = tid & 63, rg = tid >> 6;
  const float* cw = cwA + (size_t)br * DI * 4;
  const float* cb = cbA + (size_t)br * DI;
#pragma unroll
  for (int i = 0; i < 17; i++) {
    int row = rg + i * 4;
    if (row < 67) {
      int tau = t0 - 3 + row;
      ushort_t val = 0;
      if (tau >= 0) val = xz[((size_t)b * SEQ + pmap(br, tau)) * E2 + d0 + col];
      xs[row][col] = val;
    }
  }
  __syncthreads();
  int d = d0 + col;
  float w0 = cw[d*4+0], w1 = cw[d*4+1], w2 = cw[d*4+2], w3 = cw[d*4+3];
  float bias = cb[d];
  size_t dbbase = ((size_t)(ch * 64 + (d >> 4))) * SEQ;
#pragma unroll
  for (int i = 0; i < 16; i++) {
    int ti = rg + i * 4;
    float a = bias + w0*b2f(xs[ti][col]) + w1*b2f(xs[ti+1][col])
                   + w2*b2f(xs[ti+2][col]) + w3*b2f(xs[ti+3][col]);
    float val = a / (1.f + __expf(-a));
    uB[(dbbase + t0 + ti) * 16 + (col & 15)] = f2b(val);
  }
}

// ---------------- K4b: gate precompute -> zgB[b][d>>4][l][16] (blocked) -------
__global__ __launch_bounds__(256) void k_zg(const ushort_t* __restrict__ xz,
    const float* __restrict__ weff, ushort_t* __restrict__ zgB) {
  int b = blockIdx.z;
  int l0 = blockIdx.x * 64, d0 = blockIdx.y * 64;
  int tid = threadIdx.x, col = tid & 63, rg = tid >> 6;
  int d = d0 + col;
  float wef = weff[d];
  size_t dbbase = ((size_t)(b * 64 + (d >> 4))) * SEQ;
#pragma unroll
  for (int i = 0; i < 16; i++) {
    int l = l0 + rg + i * 4;
    float zr = b2f(xz[((size_t)b * SEQ + l) * E2 + DI + d]);
    float z = zr / (1.f + __expf(-zr));
    zgB[(dbbase + l) * 16 + (col & 15)] = f2b(z * wef);
  }
}

// ---------------- K5: x_dbl GEMM (reads blocked uB): xd[ch][t][64] ------------
__global__ __launch_bounds__(256) void k_xdbl(const ushort_t* __restrict__ uB,
    const ushort_t* __restrict__ xpwA, ushort_t* __restrict__ xdA) {
  __shared__ ushort_t As[64*32];
  __shared__ ushort_t Bs[64*32];
  int ch = blockIdx.y, br = ch >> 1;
  const ushort_t* xpw = xpwA + (size_t)br * KXP * DI;
  ushort_t* xd = xdA + (size_t)ch * SEQ * KXP;
  int t0 = blockIdx.x * 64;
  int tid = threadIdx.x, w = tid >> 6, lane = tid & 63;
  int lrow = lane & 15, lko = (lane >> 4) * 8;
  int row = tid >> 2, seg = tid & 3;
  f32x4 acc[4];
#pragma unroll
  for (int j = 0; j < 4; j++) acc[j] = (f32x4){0.f,0.f,0.f,0.f};
  for (int k0 = 0; k0 < DI; k0 += 32) {
    __syncthreads();
    glds16(uB + (((size_t)(ch*64 + (k0>>4) + (seg>>1)) * SEQ + t0 + row) * 16 + (seg&1)*8),
           &As[row*32 + seg*8]);
    glds16(xpw + (size_t)row * DI + k0 + seg * 8, &Bs[row*32 + seg*8]);
    __syncthreads();
    bf16x8 aF = *(const bf16x8*)&As[(w*16 + lrow)*32 + lko];
#pragma unroll
    for (int j = 0; j < 4; j++) {
      bf16x8 bF = *(const bf16x8*)&Bs[(j*16 + lrow)*32 + lko];
      acc[j] = __builtin_amdgcn_mfma_f32_16x16x32_bf16(aF, bF, acc[j], 0, 0, 0);
    }
  }
#pragma unroll
  for (int j = 0; j < 4; j++)
#pragma unroll
    for (int r = 0; r < 4; r++) {
      int t = t0 + w*16 + (lane>>4)*4 + r;
      xd[(size_t)t * KXP + j*16 + lrow] = f2b(acc[j][r]);
    }
}

// ---------------- K5b: expand xd B/C -> Bf/Cf[ch][n][t] f32 -------------------
__global__ __launch_bounds__(256) void k_bc(const ushort_t* __restrict__ xdA,
    float* __restrict__ Bf, float* __restrict__ Cf) {
  __shared__ float tb[128][34];
  int ch = blockIdx.y, t0 = blockIdx.x * 128;
  int tid = threadIdx.x;
  const ushort_t* xdb = xdA + (size_t)ch * SEQ * KXP;
#pragma unroll
  for (int i = 0; i < 2; i++) {
    int r = (tid >> 2) + i * 64;
    int q = tid & 3;
    const ushort_t* p = xdb + (size_t)(t0 + r) * KXP + 32 + q * 8;
    uint4 v = *(const uint4*)p;
    unsigned int wd[4] = {v.x, v.y, v.z, v.w};
    float* dst = &tb[r][q * 8];
#pragma unroll
    for (int j = 0; j < 4; j++) {
      dst[2*j]   = __uint_as_float(wd[j] << 16);
      dst[2*j+1] = __uint_as_float(wd[j] & 0xFFFF0000u);
    }
  }
  __syncthreads();
  int nn = tid >> 4, sg = tid & 15;
  float ob[8], oc[8];
#pragma unroll
  for (int j = 0; j < 8; j++) {
    ob[j] = tb[sg*8 + j][nn];
    oc[j] = tb[sg*8 + j][16 + nn];
  }
  float* Bp = Bf + ((size_t)ch * NST + nn) * SEQ + t0 + sg * 8;
  float* Cp = Cf + ((size_t)ch * NST + nn) * SEQ + t0 + sg * 8;
  *(float4*)Bp       = make_float4(ob[0],ob[1],ob[2],ob[3]);
  *(float4*)(Bp + 4) = make_float4(ob[4],ob[5],ob[6],ob[7]);
  *(float4*)Cp       = make_float4(oc[0],oc[1],oc[2],oc[3]);
  *(float4*)(Cp + 4) = make_float4(oc[4],oc[5],oc[6],oc[7]);
}

// ---------------- K6: delta GEMM (K=32) + softplus -> dltB (blocked) ----------
// grid (40 t-tiles, 8 d-tiles, 6 ch)
__global__ __launch_bounds__(256) void k_delta(const ushort_t* __restrict__ xdA,
    const ushort_t* __restrict__ dtwb, const float* __restrict__ dtbf,
    ushort_t* __restrict__ dltB) {
  __shared__ ushort_t As[128*32];
  __shared__ ushort_t Bs[128*32];
  int ch = blockIdx.z, br = ch >> 1;
  int t0 = blockIdx.x * 128, d0 = blockIdx.y * 128;
  int tid = threadIdx.x, w = tid >> 6, lane = tid & 63;
  int wr = w >> 1, wc = w & 1;
  int lrow = lane & 15, lko = (lane >> 4) * 8;
  const ushort_t* xdb = xdA + (size_t)ch * SEQ * KXP;
  const ushort_t* dwp = dtwb + (size_t)br * DI * DTR;
#pragma unroll
  for (int r = 0; r < 2; r++) {
    int e = r * 256 + tid;
    int row = e >> 2, seg = e & 3;
    glds16(xdb + (size_t)(t0 + row) * KXP + seg * 8, &As[row*32 + seg*8]);
    glds16(dwp + (size_t)(d0 + row) * DTR + seg * 8, &Bs[row*32 + seg*8]);
  }
  __syncthreads();
  bf16x8 aF[4], bF[4];
#pragma unroll
  for (int i = 0; i < 4; i++)
    aF[i] = *(const bf16x8*)&As[(wr*64 + i*16 + lrow)*32 + lko];
#pragma unroll
  for (int j = 0; j < 4; j++)
    bF[j] = *(const bf16x8*)&Bs[(wc*64 + j*16 + lrow)*32 + lko];
  f32x4 acc[4][4];
#pragma unroll
  for (int i = 0; i < 4; i++)
#pragma unroll
    for (int j = 0; j < 4; j++) {
      acc[i][j] = (f32x4){0.f,0.f,0.f,0.f};
      acc[i][j] = __builtin_amdgcn_mfma_f32_16x16x32_bf16(aF[i], bF[j], acc[i][j], 0, 0, 0);
    }
#pragma unroll
  for (int i = 0; i < 4; i++)
#pragma unroll
    for (int j = 0; j < 4; j++)
#pragma unroll
      for (int r = 0; r < 4; r++) {
        int t = t0 + wr*64 + i*16 + (lane>>4)*4 + r;
        int d = d0 + wc*64 + j*16 + lrow;
        float xv = acc[i][j][r] + dtbf[br * DI + d];
        float sp = (xv > 20.f) ? xv : log1pf(__expf(xv));
        dltB[(((size_t)(ch*64 + (d>>4))) * SEQ + t) * 16 + (d & 15)] = f2b(sp);
      }
}

// ---------------- K7a: segmented local scan (8 ch/wave, merged butterfly) -----
// grid 3072 = ch(bid>>9) x seg((bid>>6)&7) x dblk(bid&63); 128-thread blocks.
__global__ __launch_bounds__(128, 5) void k_scan1(
    const ushort_t* __restrict__ dltB, const ushort_t* __restrict__ uB,
    const ushort_t* __restrict__ zgB, const float* __restrict__ Bf,
    const float* __restrict__ Cf, const float* __restrict__ alf,
    const float* __restrict__ ddf, float* __restrict__ sc,
    float* __restrict__ Hloc, float* __restrict__ Stot) {
  __shared__ __align__(16) float BS[2][16][18];
  __shared__ __align__(16) float CS[2][16][18];
  __shared__ __align__(16) float4 dd4[2][4][17];   // (dltA, duA, dltB, duB)
  __shared__ float2 gS[2][4][17];                  // (gateA, gateB)
  int bid = blockIdx.x;
  int dblk = bid & 63, seg = (bid >> 6) & 7, ch = bid >> 9;
  int br = ch >> 1, b = ch & 1;
  int tid = threadIdx.x, w = tid >> 6, lane = tid & 63, g = lane >> 4, n = lane & 15;
  int da = w * 8 + g;            // channel A position within the 16-block
  int db = da + 4;               // channel B
  int dA = dblk * 16 + da, dB = dblk * 16 + db;
  const float L2E = 1.4426950408889634f;
  float ApA = -__expf(alf[br * (DI*NST) + dA * NST + n]) * L2E;
  float ApB = -__expf(alf[br * (DI*NST) + dB * NST + n]) * L2E;
  float DdA = ddf[br * DI + dA], DdB = ddf[br * DI + dB];
  const ushort_t* dlp = dltB + ((size_t)(ch * 64 + dblk) * SEQ) * 16;
  const ushort_t* uBp = uB   + ((size_t)(ch * 64 + dblk) * SEQ) * 16;
  const ushort_t* zgp = zgB  + ((size_t)(b  * 64 + dblk) * SEQ) * 16;
  const float* Bfp = Bf + ((size_t)ch * NST) * SEQ;
  const float* Cfp = Cf + ((size_t)ch * NST) * SEQ;
  float* srow = sc + (size_t)b * SEQ;
  float hstA = 0.f, hstB = 0.f, SaccA = 0.f, SaccB = 0.f;
  int sn = lane >> 2, sq = lane & 3;
  for (int t0 = seg * SEGL; t0 < seg * SEGL + SEGL; t0 += 16) {
    // stage B/C window (per-wave copy; wave-lockstep, no sync needed)
    *(float4*)&BS[w][sn][sq*4] = *(const float4*)&Bfp[(size_t)sn * SEQ + t0 + sq*4];
    *(float4*)&CS[w][sn][sq*4] = *(const float4*)&Cfp[(size_t)sn * SEQ + t0 + sq*4];
    size_t rowo = (size_t)(t0 + n) * 16;
    float dltA = b2f(dlp[rowo + da]);
    float dltBv = b2f(dlp[rowo + db]);
    float uA = b2f(uBp[rowo + da]);
    float uBv = b2f(uBp[rowo + db]);
    size_t growo = (size_t)pmap(br, t0 + n) * 16;
    float gA = b2f(zgp[growo + da]);
    float gB = b2f(zgp[growo + db]);
    SaccA += dltA; SaccB += dltBv;
    dd4[w][g][n] = make_float4(dltA, dltA * uA, dltBv, dltBv * uBv);
    gS[w][g][n]  = make_float2(gA, gB);
    float dug = fmaf(DdA * uA, gA, DdB * uBv * gB);  // per-timestep skip term
    float Bk[16], Ck[16];
#pragma unroll
    for (int j = 0; j < 4; j++) {
      *(float4*)&Bk[j*4] = *(const float4*)&BS[w][n][j*4];
      *(float4*)&Ck[j*4] = *(const float4*)&CS[w][n][j*4];
    }
    float hC[16];
#pragma unroll
    for (int k = 0; k < 16; k++) {
      float4 v = dd4[w][g][k];
      float2 gg = gS[w][g][k];
      hstA = fmaf(__builtin_amdgcn_exp2f(v.x * ApA), hstA, v.y * Bk[k]);
      hstB = fmaf(__builtin_amdgcn_exp2f(v.z * ApB), hstB, v.w * Bk[k]);
      hC[k] = fmaf(hstA, gg.x, hstB * gg.y) * Ck[k];
    }
    float y = bfly16(hC, n) + dug;     // both channels of this lane, gated
    y += __shfl_xor(y, 16, 64);        // + across g (4 groups = 8 channels)
    y += __shfl_xor(y, 32, 64);
    if (lane < 16) atomicAdd(srow + omap(br, t0 + lane), y);
  }
  Hloc[(((size_t)ch * NSEG + seg) * 1024 + dA) * 16 + n] = hstA;
  Hloc[(((size_t)ch * NSEG + seg) * 1024 + dB) * 16 + n] = hstB;
#pragma unroll
  for (int m = 1; m < 16; m <<= 1) {
    SaccA += __shfl_xor(SaccA, m, 64);
    SaccB += __shfl_xor(SaccB, m, 64);
  }
  if (n == 0) {
    Stot[((size_t)ch * NSEG + seg) * 1024 + dA] = SaccA;
    Stot[((size_t)ch * NSEG + seg) * 1024 + dB] = SaccB;
  }
}

// ---------------- K7b: stitch segment states ----------------------------------
__global__ __launch_bounds__(256) void k_stitch(const float* __restrict__ Stot,
    const float* __restrict__ Hloc, const float* __restrict__ alf,
    float* __restrict__ Hin) {
  int idx = blockIdx.x * 256 + threadIdx.x;     // 98304 = 6*1024*16
  int ch = idx >> 14, rem = idx & 16383, d = rem >> 4, n = rem & 15;
  int br = ch >> 1;
  float A = -__expf(alf[(size_t)br * (DI*NST) + d * NST + n]);
  float h = 0.f;
  for (int s = 0; s < NSEG; s++) {
    size_t base = ((size_t)ch * NSEG + s) * 1024 + d;
    Hin[base * 16 + n] = h;
    h = __expf(A * Stot[base]) * h + Hloc[base * 16 + n];
  }
}

// ---------------- K7c: carry correction (coalesced LDS-staged) ----------------
// grid 1536 = ch(bid>>8) x cg(bid&255); all blocks co-resident at 6/CU.
// Old version: per-lane 2-byte reads of dlt/zg at stride 32B = 16x cacheline
// amplification on the window critical path. New: the 256 threads stage the
// full [64 t][16 dsub] dlt+zg tiles into LDS with coalesced 8B loads; waves
// then read their dsub column (stride 36B -> bank-stride 9, conflict-free).
// Same 2 barriers/window as before (stage->bar1->compute+red->bar2).
__global__ __launch_bounds__(256, 6) void k_scan2(
    const ushort_t* __restrict__ zgB, const ushort_t* __restrict__ dltB,
    const float* __restrict__ Cf, const float* __restrict__ alf,
    const float* __restrict__ Hin, float* __restrict__ sc) {
  __shared__ float red[4][72];
  __shared__ ushort_t dltS[64][18];   // [t][dsub], +2 pad
  __shared__ ushort_t zgS[64][18];
  int ch = blockIdx.x >> 8, cg = blockIdx.x & 255;
  int br = ch >> 1, b = ch & 1;
  int tid = threadIdx.x, w = tid >> 6, lane = tid & 63;
  int d = cg * 4 + w;
  const float L2E = 1.4426950408889634f;
  float A2_[16];
#pragma unroll
  for (int nn = 0; nn < 16; nn++)
    A2_[nn] = -__expf(alf[(size_t)br * (DI*NST) + d * NST + nn]) * L2E;
  const ushort_t* dlp = dltB + ((size_t)(ch * 64 + (d >> 4)) * SEQ) * 16;
  const ushort_t* zgp = zgB  + ((size_t)(b  * 64 + (d >> 4)) * SEQ) * 16;
  const float* Cfp = Cf + (size_t)ch * NST * SEQ;
  int dsub = d & 15;
  int srow_t = tid >> 2, sq4 = (tid & 3) * 4;    // staging coords
  float* srow = sc + (size_t)b * SEQ;
  for (int seg = 1; seg < NSEG; seg++) {
    float Hn[16];
    const float* hp = Hin + (((size_t)ch * NSEG + seg) * 1024 + d) * 16;
#pragma unroll
    for (int nn = 0; nn < 16; nn++) Hn[nn] = hp[nn];
    float carry = 0.f;
    for (int w0 = seg * SEGL; w0 < seg * SEGL + SEGL; w0 += 64) {
      // ---- cooperative stage: [64][16] tiles, 8B per thread, coalesced ----
      {
        int tg = w0 + srow_t;
        uint2 dv = *(const uint2*)(dlp + (size_t)tg * 16 + sq4);
        uint2 zv = *(const uint2*)(zgp + (size_t)pmap(br, tg) * 16 + sq4);
        *(uint2*)&dltS[srow_t][sq4] = dv;
        *(uint2*)&zgS[srow_t][sq4]  = zv;
      }
      __syncthreads();
      int t = w0 + lane;
      float dlt = b2f(dltS[lane][dsub]);
      float S = dlt;
#pragma unroll
      for (int ofs = 1; ofs < 64; ofs <<= 1) {
        float v = __shfl_up(S, ofs, 64);
        if (lane >= ofs) S += v;
      }
      float tot = __shfl(S, 63, 64);
      S += carry; carry += tot;
      float corr = 0.f;
#pragma unroll
      for (int nn = 0; nn < 16; nn++) {
        float Cn = Cfp[(size_t)nn * SEQ + t];
        corr = fmaf(Cn * Hn[nn], __builtin_amdgcn_exp2f(A2_[nn] * S), corr);
      }
      float gate = b2f(zgS[lane][dsub]);
      float y = corr * gate;
      red[w][lane] = y;
      __syncthreads();
      if (w == 0) {
        float ytot = red[0][lane] + red[1][lane] + red[2][lane] + red[3][lane];
        atomicAdd(srow + omap(br, t), ytot);
      }
    }
  }
}

// ---------------- K8: w_eff[d] = lin_w . out_proj_w[:,d]; zero score_acc ------
__global__ __launch_bounds__(256) void k_weff_init(const ushort_t* __restrict__ opwb,
    const ushort_t* __restrict__ lwb, float* __restrict__ weff, float* __restrict__ sc) {
  int i = blockIdx.x * 256 + threadIdx.x;
  if (i < DI) {
    float s = 0.f;
    for (int o = 0; o < DIMX; o++) s += b2f(lwb[o]) * b2f(opwb[(size_t)o * DI + i]);
    weff[i] = s;
  }
  int j = i - DI;
  if (j >= 0 && j < 2 * SEQ) sc[j] = 0.f;
}

// ---------------- K9: outputs (f32): group interp+sigmoid, individual ---------
__global__ __launch_bounds__(256) void k_out(const float* __restrict__ g0,
    const float* __restrict__ g1, const float* __restrict__ g2,
    const float* __restrict__ sc, const float* __restrict__ lbf,
    float* __restrict__ out) {
  int idx = blockIdx.x * 256 + threadIdx.x;
  if (idx < 3 * SEQ) {
    int j = idx / SEQ, t = idx % SEQ;
    const float* g = (j == 0) ? g0 : (j == 1) ? g1 : g2;
    float pos = t * ((float)(LGS - 1) / (float)(SEQ - 1));
    int i0 = (int)floorf(pos);
    if (i0 < 0) i0 = 0; if (i0 > LGS - 2) i0 = LGS - 2;
    float wt = pos - (float)i0;
    float v = g[i0] * (1.f - wt) + g[i0 + 1] * wt;
    out[idx] = 1.f / (1.f + __expf(-v));
  } else if (idx < 5 * SEQ) {
    float t = sc[idx - 3 * SEQ] + lbf[0];
    out[idx] = 1.f / (1.f + __expf(-t));
  }
}

extern "C" void kernel_launch(void* const* d_in, const int* in_sizes, int n_in,
                              void* d_out, int out_size, void* d_ws, size_t ws_size,
                              hipStream_t stream) {
  char* ws = (char*)d_ws;
  ushort_t* lwb   = (ushort_t*)(ws + OFF_LWB);
  float*    lngf  = (float*)(ws + OFF_LNGF);
  float*    lnbf  = (float*)(ws + OFF_LNBF);
  float*    lbf   = (float*)(ws + OFF_LBF);
  float*    cwf   = (float*)(ws + OFF_CWF);
  float*    cbf   = (float*)(ws + OFF_CBF);
  float*    dtbf  = (float*)(ws + OFF_DTBF);
  float*    alf   = (float*)(ws + OFF_ALF);
  float*    ddf   = (float*)(ws + OFF_DDF);
  float*    weff  = (float*)(ws + OFF_WEFF);
  float*    sc    = (float*)(ws + OFF_SC);
  ushort_t* dtwb  = (ushort_t*)(ws + OFF_DTWB);
  ushort_t* xpwb  = (ushort_t*)(ws + OFF_XPWB);
  ushort_t* opwb  = (ushort_t*)(ws + OFF_OPWB);
  ushort_t* inwb  = (ushort_t*)(ws + OFF_INWB);
  ushort_t* xd    = (ushort_t*)(ws + OFF_XD);
  ushort_t* dltB  = (ushort_t*)(ws + OFF_DLTB);
  ushort_t* xz    = (ushort_t*)(ws + OFF_XZ);
  float*    Bf    = (float*)(ws + OFF_BF);
  float*    Cf    = (float*)(ws + OFF_CF);
  ushort_t* uB    = (ushort_t*)(ws + OFF_UB);
  ushort_t* h     = (ushort_t*)(ws + OFF_H);
  ushort_t* zgB   = (ushort_t*)(ws + OFF_ZGB);
  float*    Hloc  = (float*)(ws + OFF_HLOC);
  float*    Hin   = (float*)(ws + OFF_HIN);
  float*    Stot  = (float*)(ws + OFF_STOT);
  float*    OUT   = (float*)d_out;

  Tab tab;
  int c = 0;
  tab.e[c++] = {d_in[3], inwb, E2 * DIMX, 0};
  tab.e[c++] = {d_in[4], opwb, DIMX * DI, 0};
  tab.e[c++] = {d_in[5], lwb, DIMX, 0};
  for (int br = 0; br < 3; br++) {
    int base = 10 + br * 7;
    tab.e[c++] = {d_in[base + 2], xpwb + (size_t)br * KXP * DI, KXP * DI, 0};
    tab.e[c++] = {d_in[base + 3], dtwb + (size_t)br * DI * DTR, DI * DTR, 0};
  }
  tab.e[c++] = {d_in[1], lngf, DIMX, 1};
  tab.e[c++] = {d_in[2], lnbf, DIMX, 1};
  tab.e[c++] = {d_in[6], lbf, 1, 1};
  for (int br = 0; br < 3; br++) {
    int base = 10 + br * 7;
    tab.e[c++] = {d_in[base + 0], cwf + (size_t)br * DI * 4, DI * 4, 1};
    tab.e[c++] = {d_in[base + 1], cbf + (size_t)br * DI, DI, 1};
    tab.e[c++] = {d_in[base + 4], dtbf + (size_t)br * DI, DI, 1};
    tab.e[c++] = {d_in[base + 5], alf + (size_t)br * DI * NST, DI * NST, 1};
    tab.e[c++] = {d_in[base + 6], ddf + (size_t)br * DI, DI, 1};
  }

  dim3 blk(256);
  k_import<<<dim3(64, c), blk, 0, stream>>>(tab, c);
  k_weff_init<<<44, blk, 0, stream>>>(opwb, lwb, weff, sc);
  k_ln<<<2560, blk, 0, stream>>>((const float*)d_in[0], lngf, lnbf, h);
  k_inproj<<<dim3(80, 16), blk, 0, stream>>>(h, inwb, xz);
  k_conv<<<dim3(80, 16, 6), blk, 0, stream>>>(xz, cwf, cbf, uB);
  k_zg<<<dim3(80, 16, 2), blk, 0, stream>>>(xz, weff, zgB);
  k_xdbl<<<dim3(80, 6), blk, 0, stream>>>(uB, xpwb, xd);
  k_bc<<<dim3(40, 6), blk, 0, stream>>>(xd, Bf, Cf);
  k_delta<<<dim3(40, 8, 6), blk, 0, stream>>>(xd, dtwb, dtbf, dltB);   // xz dead now
  k_scan1<<<3072, dim3(128), 0, stream>>>(dltB, uB, zgB, Bf, Cf, alf, ddf,
                                          sc, Hloc, Stot);
  k_stitch<<<384, blk, 0, stream>>>(Stot, Hloc, alf, Hin);
  k_scan2<<<1536, blk, 0, stream>>>(zgB, dltB, Cf, alf, Hin, sc);
  k_out<<<100, blk, 0, stream>>>((const float*)d_in[7], (const float*)d_in[8],
                                 (const float*)d_in[9], sc, lbf, OUT);
}

// Round 9
// 844.745 us; speedup vs baseline: 1.0961x; 1.0961x over previous
//
#include <hip/hip_runtime.h>
#include <stdint.h>

#define SEQ  5120
#define DIMX 512
#define E2   2048
#define DI   1024
#define NST  16
#define DTR  32
#define KXP  64
#define LGS  2048
#define NSL  5
#define NSEG 8
#define SEGL 640

typedef unsigned short ushort_t;
typedef __attribute__((ext_vector_type(8))) __bf16 bf16x8;
typedef __attribute__((ext_vector_type(4))) float f32x4;

__device__ __forceinline__ float b2f(ushort_t u) {
  union { unsigned int i; float f; } v; v.i = ((unsigned int)u) << 16; return v.f;
}
__device__ __forceinline__ ushort_t f2b(float f) {
  union { float f; unsigned int i; } v; v.f = f;
  unsigned int u = v.i;
  return (ushort_t)((u + 0x7FFFu + ((u >> 16) & 1u)) >> 16);
}

#define AS1 __attribute__((address_space(1)))
#define AS3 __attribute__((address_space(3)))
__device__ __forceinline__ void glds16(const void* g, void* l) {
  __builtin_amdgcn_global_load_lds((const AS1 void*)g, (AS3 void*)l, 16, 0, 0);
}

__device__ __forceinline__ int pmap(int br, int t) {   // scan pos -> data pos
  return (br == 0) ? t : (br == 1) ? (SEQ - 1 - t) : ((t % NSL) * 1024 + t / NSL);
}
__device__ __forceinline__ int omap(int br, int t) {   // scan pos -> output pos
  return (br == 0) ? t : (br == 1) ? (SEQ - 1 - t) : ((t & 1023) * NSL + (t >> 10));
}

// 16-state transpose-reduce butterfly: input hC[k] per lane(n) holding state n,
// output: lane n holds sum over states for timestep-slot n.
__device__ __forceinline__ float bfly16(const float* hC, int n) {
  float a8[8], a4[4], a2[2], y;
#pragma unroll
  for (int j = 0; j < 8; j++) {
    float keep = (n & 8) ? hC[j+8] : hC[j];
    float send = (n & 8) ? hC[j]   : hC[j+8];
    a8[j] = keep + __shfl_xor(send, 8, 64);
  }
#pragma unroll
  for (int j = 0; j < 4; j++) {
    float keep = (n & 4) ? a8[j+4] : a8[j];
    float send = (n & 4) ? a8[j]   : a8[j+4];
    a4[j] = keep + __shfl_xor(send, 4, 64);
  }
#pragma unroll
  for (int j = 0; j < 2; j++) {
    float keep = (n & 2) ? a4[j+2] : a4[j];
    float send = (n & 2) ? a4[j]   : a4[j+2];
    a2[j] = keep + __shfl_xor(send, 2, 64);
  }
  {
    float keep = (n & 1) ? a2[1] : a2[0];
    float send = (n & 1) ? a2[0] : a2[1];
    y = keep + __shfl_xor(send, 1, 64);
  }
  return y;
}

// ---------------- workspace layout (bytes) ------------------------------------
#define OFF_LWB   ((size_t)256)
#define OFF_LNGF  ((size_t)1280)
#define OFF_LNBF  ((size_t)3328)
#define OFF_LBF   ((size_t)5376)
#define OFF_CWF   ((size_t)5632)
#define OFF_CBF   ((size_t)54784)
#define OFF_DTBF  ((size_t)67072)
#define OFF_ALF   ((size_t)79360)
#define OFF_DDF   ((size_t)275968)
#define OFF_WEFF  ((size_t)288256)
#define OFF_SC    ((size_t)292352)
#define OFF_DTWB  ((size_t)333312)      // bf16 dt_w, 3*1024*32*2 = 196,608
#define OFF_XPWB  ((size_t)529920)
#define OFF_OPWB  ((size_t)923136)
#define OFF_INWB  ((size_t)1971712)     // ends 4,068,864
#define OFF_XD    ((size_t)4068864)     // 6*5120*64*2 = 3,932,160 -> 8,001,024
#define OFF_DLTB  ((size_t)8001024)     // 6*5120*1024*2 = 62,914,560 -> 70,915,584
#define OFF_XZ    OFF_DLTB              // xz (42 MB) nested; dead before k_delta writes
#define OFF_BF    ((size_t)70915584)    // 1,966,080 -> 72,881,664
#define OFF_CF    ((size_t)72881664)    // 1,966,080 -> 74,847,744
#define OFF_HLOC  ((size_t)74847744)    // 3,145,728 -> 77,993,472
#define OFF_HIN   ((size_t)77993472)    // 3,145,728 -> 81,139,200
#define OFF_STOT  ((size_t)81139200)    // 196,608  -> 81,335,808
#define OFF_UB    ((size_t)81335808)    // 62,914,560 -> 144,250,368
#define OFF_H     OFF_UB                // ln-out h (10 MB) nested; dead before conv
#define OFF_ZGB   ((size_t)144250368)   // 20,971,520 -> 165,221,888
// total ~165.2 MiB

// ---------------- K0: batched import (f32 params -> ws, bf16 or f32) ----------
struct Ent { const void* s; void* d; int n; int fmt; };
struct Tab { Ent e[32]; };

__global__ __launch_bounds__(256) void k_import(Tab t, int cnt) {
  int id = blockIdx.y;
  if (id >= cnt) return;
  Ent E = t.e[id];
  int stride = gridDim.x * 256;
  const float* s = (const float*)E.s;
  if (E.fmt == 0) {
    ushort_t* dst = (ushort_t*)E.d;
    for (int i = blockIdx.x * 256 + threadIdx.x; i < E.n; i += stride) dst[i] = f2b(s[i]);
  } else {
    float* dst = (float*)E.d;
    for (int i = blockIdx.x * 256 + threadIdx.x; i < E.n; i += stride) dst[i] = s[i];
  }
}

// ---------------- K1: LayerNorm + ReLU -> h (bf16, both batches) --------------
__global__ __launch_bounds__(256) void k_ln(const float* __restrict__ x,
    const float* __restrict__ gam, const float* __restrict__ bet,
    ushort_t* __restrict__ h) {
  int token = blockIdx.x * 4 + (threadIdx.x >> 6);
  int lane = threadIdx.x & 63;
  const float* row = x + (size_t)token * DIMX + lane * 8;
  float4 a0 = *(const float4*)(row);
  float4 a1 = *(const float4*)(row + 4);
  float v[8] = {a0.x,a0.y,a0.z,a0.w,a1.x,a1.y,a1.z,a1.w};
  float s = 0.f, ss = 0.f;
#pragma unroll
  for (int i = 0; i < 8; i++) { s += v[i]; ss += v[i]*v[i]; }
#pragma unroll
  for (int m = 1; m < 64; m <<= 1) { s += __shfl_xor(s, m, 64); ss += __shfl_xor(ss, m, 64); }
  float mean = s * (1.f / DIMX);
  float rs = rsqrtf(ss * (1.f / DIMX) - mean * mean + 1e-5f);
  ushort_t o[8];
#pragma unroll
  for (int i = 0; i < 8; i++) {
    float y = (v[i] - mean) * rs * gam[lane*8+i] + bet[lane*8+i];
    o[i] = f2b(fmaxf(y, 0.f));
  }
  ushort_t* orow = h + (size_t)token * DIMX + lane * 8;
  *(ushort4*)(orow)     = make_ushort4(o[0],o[1],o[2],o[3]);
  *(ushort4*)(orow + 4) = make_ushort4(o[4],o[5],o[6],o[7]);
}

// ---------------- K2: in_proj GEMM + fused z-gate epilogue --------------------
// Blocks with n0 < DI write xz (x half) as before. Blocks with n0 >= DI apply
// silu(z)*weff and write zgB directly (k_zg kernel deleted; xz z-half never
// materialized). conv reads only the x half, so xz z-half is dead.
__global__ __launch_bounds__(256) void k_inproj(const ushort_t* __restrict__ hA,
    const ushort_t* __restrict__ Wb, const float* __restrict__ weff,
    ushort_t* __restrict__ xz, ushort_t* __restrict__ zgB) {
  __shared__ ushort_t As[128*32];
  __shared__ ushort_t Bs[128*32];
  const int tid = threadIdx.x;
  const int w = tid >> 6, lane = tid & 63;
  const int wr = w >> 1, wc = w & 1;
  const int m0 = blockIdx.x * 128, n0 = blockIdx.y * 128;
  const int lrow = lane & 15, lko = (lane >> 4) * 8;
  f32x4 acc[4][4];
#pragma unroll
  for (int i = 0; i < 4; i++)
#pragma unroll
    for (int j = 0; j < 4; j++) acc[i][j] = (f32x4){0.f,0.f,0.f,0.f};
  for (int k0 = 0; k0 < DIMX; k0 += 32) {
    __syncthreads();
#pragma unroll
    for (int r = 0; r < 2; r++) {
      int e = r * 256 + tid;
      int row = e >> 2, seg = e & 3;
      glds16(hA + (size_t)(m0 + row) * DIMX + k0 + seg * 8, &As[row*32 + seg*8]);
      glds16(Wb + (size_t)(n0 + row) * DIMX + k0 + seg * 8, &Bs[row*32 + seg*8]);
    }
    __syncthreads();
    bf16x8 aF[4], bF[4];
#pragma unroll
    for (int i = 0; i < 4; i++)
      aF[i] = *(const bf16x8*)&As[(wr*64 + i*16 + lrow)*32 + lko];
#pragma unroll
    for (int j = 0; j < 4; j++)
      bF[j] = *(const bf16x8*)&Bs[(wc*64 + j*16 + lrow)*32 + lko];
#pragma unroll
    for (int i = 0; i < 4; i++)
#pragma unroll
      for (int j = 0; j < 4; j++)
        acc[i][j] = __builtin_amdgcn_mfma_f32_16x16x32_bf16(aF[i], bF[j], acc[i][j], 0, 0, 0);
  }
  if (n0 < DI) {
#pragma unroll
    for (int i = 0; i < 4; i++)
#pragma unroll
      for (int j = 0; j < 4; j++)
#pragma unroll
        for (int r = 0; r < 4; r++) {
          int m = m0 + wr*64 + i*16 + (lane>>4)*4 + r;
          int n = n0 + wc*64 + j*16 + lrow;
          xz[(size_t)m * E2 + n] = f2b(acc[i][j][r]);
        }
  } else {
#pragma unroll
    for (int i = 0; i < 4; i++)
#pragma unroll
      for (int j = 0; j < 4; j++) {
        int d = n0 - DI + wc*64 + j*16 + lrow;
        float wef = weff[d];
        size_t dbrow = (size_t)(d >> 4) * SEQ;   // + b*64*SEQ below
        int dsub = d & 15;
#pragma unroll
        for (int r = 0; r < 4; r++) {
          int m = m0 + wr*64 + i*16 + (lane>>4)*4 + r;
          int b = (m >= SEQ) ? 1 : 0;
          int l = m - b * SEQ;
          float zr = acc[i][j][r];
          float z = zr / (1.f + __expf(-zr)) * wef;
          zgB[((size_t)b * 64 * SEQ + dbrow + l) * 16 + dsub] = f2b(z);
        }
      }
  }
}

// ---------------- K4: conv + silu -> uB[ch][d>>4][t][16] (blocked) ------------
__global__ __launch_bounds__(256) void k_conv(const ushort_t* __restrict__ xz,
    const float* __restrict__ cwA, const float* __restrict__ cbA,
    ushort_t* __restrict__ uB) {
  __shared__ ushort_t xs[67][64];
  int ch = blockIdx.z, br = ch >> 1, b = ch & 1;
  int t0 = blockIdx.x * 64, d0 = blockIdx.y * 64;
  int tid = threadIdx.x, col = tid & 63, rg = tid >> 6;
  const float* cw = cwA + (size_t)br * DI * 4;
  const float* cb = cbA + (size_t)br * DI;
#pragma unroll
  for (int i = 0; i < 17; i++) {
    int row = rg + i * 4;
    if (row < 67) {
      int tau = t0 - 3 + row;
      ushort_t val = 0;
      if (tau >= 0) val = xz[((size_t)b * SEQ + pmap(br, tau)) * E2 + d0 + col];
      xs[row][col] = val;
    }
  }
  __syncthreads();
  int d = d0 + col;
  float w0 = cw[d*4+0], w1 = cw[d*4+1], w2 = cw[d*4+2], w3 = cw[d*4+3];
  float bias = cb[d];
  size_t dbbase = ((size_t)(ch * 64 + (d >> 4))) * SEQ;
#pragma unroll
  for (int i = 0; i < 16; i++) {
    int ti = rg + i * 4;
    float a = bias + w0*b2f(xs[ti][col]) + w1*b2f(xs[ti+1][col])
                   + w2*b2f(xs[ti+2][col]) + w3*b2f(xs[ti+3][col]);
    float val = a / (1.f + __expf(-a));
    uB[(dbbase + t0 + ti) * 16 + (col & 15)] = f2b(val);
  }
}

// ---------------- K5: x_dbl GEMM (reads blocked uB): xd[ch][t][64] ------------
__global__ __launch_bounds__(256) void k_xdbl(const ushort_t* __restrict__ uB,
    const ushort_t* __restrict__ xpwA, ushort_t* __restrict__ xdA) {
  __shared__ ushort_t As[64*32];
  __shared__ ushort_t Bs[64*32];
  int ch = blockIdx.y, br = ch >> 1;
  const ushort_t* xpw = xpwA + (size_t)br * KXP * DI;
  ushort_t* xd = xdA + (size_t)ch * SEQ * KXP;
  int t0 = blockIdx.x * 64;
  int tid = threadIdx.x, w = tid >> 6, lane = tid & 63;
  int lrow = lane & 15, lko = (lane >> 4) * 8;
  int row = tid >> 2, seg = tid & 3;
  f32x4 acc[4];
#pragma unroll
  for (int j = 0; j < 4; j++) acc[j] = (f32x4){0.f,0.f,0.f,0.f};
  for (int k0 = 0; k0 < DI; k0 += 32) {
    __syncthreads();
    glds16(uB + (((size_t)(ch*64 + (k0>>4) + (seg>>1)) * SEQ + t0 + row) * 16 + (seg&1)*8),
           &As[row*32 + seg*8]);
    glds16(xpw + (size_t)row * DI + k0 + seg * 8, &Bs[row*32 + seg*8]);
    __syncthreads();
    bf16x8 aF = *(const bf16x8*)&As[(w*16 + lrow)*32 + lko];
#pragma unroll
    for (int j = 0; j < 4; j++) {
      bf16x8 bF = *(const bf16x8*)&Bs[(j*16 + lrow)*32 + lko];
      acc[j] = __builtin_amdgcn_mfma_f32_16x16x32_bf16(aF, bF, acc[j], 0, 0, 0);
    }
  }
#pragma unroll
  for (int j = 0; j < 4; j++)
#pragma unroll
    for (int r = 0; r < 4; r++) {
      int t = t0 + w*16 + (lane>>4)*4 + r;
      xd[(size_t)t * KXP + j*16 + lrow] = f2b(acc[j][r]);
    }
}

// ---------------- K5b: expand xd B/C -> Bf/Cf[ch][n][t] f32 -------------------
__global__ __launch_bounds__(256) void k_bc(const ushort_t* __restrict__ xdA,
    float* __restrict__ Bf, float* __restrict__ Cf) {
  __shared__ float tb[128][34];
  int ch = blockIdx.y, t0 = blockIdx.x * 128;
  int tid = threadIdx.x;
  const ushort_t* xdb = xdA + (size_t)ch * SEQ * KXP;
#pragma unroll
  for (int i = 0; i < 2; i++) {
    int r = (tid >> 2) + i * 64;
    int q = tid & 3;
    const ushort_t* p = xdb + (size_t)(t0 + r) * KXP + 32 + q * 8;
    uint4 v = *(const uint4*)p;
    unsigned int wd[4] = {v.x, v.y, v.z, v.w};
    float* dst = &tb[r][q * 8];
#pragma unroll
    for (int j = 0; j < 4; j++) {
      dst[2*j]   = __uint_as_float(wd[j] << 16);
      dst[2*j+1] = __uint_as_float(wd[j] & 0xFFFF0000u);
    }
  }
  __syncthreads();
  int nn = tid >> 4, sg = tid & 15;
  float ob[8], oc[8];
#pragma unroll
  for (int j = 0; j < 8; j++) {
    ob[j] = tb[sg*8 + j][nn];
    oc[j] = tb[sg*8 + j][16 + nn];
  }
  float* Bp = Bf + ((size_t)ch * NST + nn) * SEQ + t0 + sg * 8;
  float* Cp = Cf + ((size_t)ch * NST + nn) * SEQ + t0 + sg * 8;
  *(float4*)Bp       = make_float4(ob[0],ob[1],ob[2],ob[3]);
  *(float4*)(Bp + 4) = make_float4(ob[4],ob[5],ob[6],ob[7]);
  *(float4*)Cp       = make_float4(oc[0],oc[1],oc[2],oc[3]);
  *(float4*)(Cp + 4) = make_float4(oc[4],oc[5],oc[6],oc[7]);
}

// ---------------- K6: delta GEMM (K=32) + softplus -> dltB (blocked) ----------
// grid (40 t-tiles, 8 d-tiles, 6 ch)
__global__ __launch_bounds__(256) void k_delta(const ushort_t* __restrict__ xdA,
    const ushort_t* __restrict__ dtwb, const float* __restrict__ dtbf,
    ushort_t* __restrict__ dltB) {
  __shared__ ushort_t As[128*32];
  __shared__ ushort_t Bs[128*32];
  int ch = blockIdx.z, br = ch >> 1;
  int t0 = blockIdx.x * 128, d0 = blockIdx.y * 128;
  int tid = threadIdx.x, w = tid >> 6, lane = tid & 63;
  int wr = w >> 1, wc = w & 1;
  int lrow = lane & 15, lko = (lane >> 4) * 8;
  const ushort_t* xdb = xdA + (size_t)ch * SEQ * KXP;
  const ushort_t* dwp = dtwb + (size_t)br * DI * DTR;
#pragma unroll
  for (int r = 0; r < 2; r++) {
    int e = r * 256 + tid;
    int row = e >> 2, seg = e & 3;
    glds16(xdb + (size_t)(t0 + row) * KXP + seg * 8, &As[row*32 + seg*8]);
    glds16(dwp + (size_t)(d0 + row) * DTR + seg * 8, &Bs[row*32 + seg*8]);
  }
  __syncthreads();
  bf16x8 aF[4], bF[4];
#pragma unroll
  for (int i = 0; i < 4; i++)
    aF[i] = *(const bf16x8*)&As[(wr*64 + i*16 + lrow)*32 + lko];
#pragma unroll
  for (int j = 0; j < 4; j++)
    bF[j] = *(const bf16x8*)&Bs[(wc*64 + j*16 + lrow)*32 + lko];
  f32x4 acc[4][4];
#pragma unroll
  for (int i = 0; i < 4; i++)
#pragma unroll
    for (int j = 0; j < 4; j++) {
      acc[i][j] = (f32x4){0.f,0.f,0.f,0.f};
      acc[i][j] = __builtin_amdgcn_mfma_f32_16x16x32_bf16(aF[i], bF[j], acc[i][j], 0, 0, 0);
    }
#pragma unroll
  for (int i = 0; i < 4; i++)
#pragma unroll
    for (int j = 0; j < 4; j++)
#pragma unroll
      for (int r = 0; r < 4; r++) {
        int t = t0 + wr*64 + i*16 + (lane>>4)*4 + r;
        int d = d0 + wc*64 + j*16 + lrow;
        float xv = acc[i][j][r] + dtbf[br * DI + d];
        float sp = (xv > 20.f) ? xv : log1pf(__expf(xv));
        dltB[(((size_t)(ch*64 + (d>>4))) * SEQ + t) * 16 + (d & 15)] = f2b(sp);
      }
}

// ---------------- K7a: segmented local scan (8 ch/wave, merged butterfly) -----
// grid 3072 = ch(bid>>9) x seg((bid>>6)&7) x dblk(bid&63); 128-thread blocks.
__global__ __launch_bounds__(128, 5) void k_scan1(
    const ushort_t* __restrict__ dltB, const ushort_t* __restrict__ uB,
    const ushort_t* __restrict__ zgB, const float* __restrict__ Bf,
    const float* __restrict__ Cf, const float* __restrict__ alf,
    const float* __restrict__ ddf, float* __restrict__ sc,
    float* __restrict__ Hloc, float* __restrict__ Stot) {
  __shared__ __align__(16) float BS[2][16][18];
  __shared__ __align__(16) float CS[2][16][18];
  __shared__ __align__(16) float4 dd4[2][4][17];   // (dltA, duA, dltB, duB)
  __shared__ __align__(16) float2 gS[2][4][18];    // (gateA, gateB), 16B-paired
  int bid = blockIdx.x;
  int dblk = bid & 63, seg = (bid >> 6) & 7, ch = bid >> 9;
  int br = ch >> 1, b = ch & 1;
  int tid = threadIdx.x, w = tid >> 6, lane = tid & 63, g = lane >> 4, n = lane & 15;
  int da = w * 8 + g;            // channel A position within the 16-block
  int db = da + 4;               // channel B
  int dA = dblk * 16 + da, dB = dblk * 16 + db;
  const float L2E = 1.4426950408889634f;
  float ApA = -__expf(alf[br * (DI*NST) + dA * NST + n]) * L2E;
  float ApB = -__expf(alf[br * (DI*NST) + dB * NST + n]) * L2E;
  float DdA = ddf[br * DI + dA], DdB = ddf[br * DI + dB];
  const ushort_t* dlp = dltB + ((size_t)(ch * 64 + dblk) * SEQ) * 16;
  const ushort_t* uBp = uB   + ((size_t)(ch * 64 + dblk) * SEQ) * 16;
  const ushort_t* zgp = zgB  + ((size_t)(b  * 64 + dblk) * SEQ) * 16;
  const float* Bfp = Bf + ((size_t)ch * NST) * SEQ;
  const float* Cfp = Cf + ((size_t)ch * NST) * SEQ;
  float* srow = sc + (size_t)b * SEQ;
  float hstA = 0.f, hstB = 0.f, SaccA = 0.f, SaccB = 0.f;
  int sn = lane >> 2, sq = lane & 3;
  for (int t0 = seg * SEGL; t0 < seg * SEGL + SEGL; t0 += 16) {
    // stage B/C window (per-wave copy; wave-lockstep, no sync needed)
    *(float4*)&BS[w][sn][sq*4] = *(const float4*)&Bfp[(size_t)sn * SEQ + t0 + sq*4];
    *(float4*)&CS[w][sn][sq*4] = *(const float4*)&Cfp[(size_t)sn * SEQ + t0 + sq*4];
    size_t rowo = (size_t)(t0 + n) * 16;
    float dltA = b2f(dlp[rowo + da]);
    float dltBv = b2f(dlp[rowo + db]);
    float uA = b2f(uBp[rowo + da]);
    float uBv = b2f(uBp[rowo + db]);
    size_t growo = (size_t)pmap(br, t0 + n) * 16;
    float gA = b2f(zgp[growo + da]);
    float gB = b2f(zgp[growo + db]);
    SaccA += dltA; SaccB += dltBv;
    dd4[w][g][n] = make_float4(dltA, dltA * uA, dltBv, dltBv * uBv);
    gS[w][g][n]  = make_float2(gA, gB);
    float dug = fmaf(DdA * uA, gA, DdB * uBv * gB);  // per-timestep skip term
    float Bk[16], Ck[16];
#pragma unroll
    for (int j = 0; j < 4; j++) {
      *(float4*)&Bk[j*4] = *(const float4*)&BS[w][n][j*4];
      *(float4*)&Ck[j*4] = *(const float4*)&CS[w][n][j*4];
    }
    float hC[16];
#pragma unroll
    for (int k = 0; k < 16; k += 2) {
      float4 gg2 = *(const float4*)&gS[w][g][k];   // (gA_k,gB_k,gA_k+1,gB_k+1)
      float4 v0 = dd4[w][g][k];
      float4 v1 = dd4[w][g][k+1];
      hstA = fmaf(__builtin_amdgcn_exp2f(v0.x * ApA), hstA, v0.y * Bk[k]);
      hstB = fmaf(__builtin_amdgcn_exp2f(v0.z * ApB), hstB, v0.w * Bk[k]);
      hC[k] = fmaf(hstA, gg2.x, hstB * gg2.y) * Ck[k];
      hstA = fmaf(__builtin_amdgcn_exp2f(v1.x * ApA), hstA, v1.y * Bk[k+1]);
      hstB = fmaf(__builtin_amdgcn_exp2f(v1.z * ApB), hstB, v1.w * Bk[k+1]);
      hC[k+1] = fmaf(hstA, gg2.z, hstB * gg2.w) * Ck[k+1];
    }
    float y = bfly16(hC, n) + dug;     // both channels of this lane, gated
    y += __shfl_xor(y, 16, 64);        // + across g (4 groups = 8 channels)
    y += __shfl_xor(y, 32, 64);
    if (lane < 16) atomicAdd(srow + omap(br, t0 + lane), y);
  }
  Hloc[(((size_t)ch * NSEG + seg) * 1024 + dA) * 16 + n] = hstA;
  Hloc[(((size_t)ch * NSEG + seg) * 1024 + dB) * 16 + n] = hstB;
#pragma unroll
  for (int m = 1; m < 16; m <<= 1) {
    SaccA += __shfl_xor(SaccA, m, 64);
    SaccB += __shfl_xor(SaccB, m, 64);
  }
  if (n == 0) {
    Stot[((size_t)ch * NSEG + seg) * 1024 + dA] = SaccA;
    Stot[((size_t)ch * NSEG + seg) * 1024 + dB] = SaccB;
  }
}

// ---------------- K7b: stitch segment states ----------------------------------
__global__ __launch_bounds__(256) void k_stitch(const float* __restrict__ Stot,
    const float* __restrict__ Hloc, const float* __restrict__ alf,
    float* __restrict__ Hin) {
  int idx = blockIdx.x * 256 + threadIdx.x;     // 98304 = 6*1024*16
  int ch = idx >> 14, rem = idx & 16383, d = rem >> 4, n = rem & 15;
  int br = ch >> 1;
  float A = -__expf(alf[(size_t)br * (DI*NST) + d * NST + n]);
  float h = 0.f;
  for (int s = 0; s < NSEG; s++) {
    size_t base = ((size_t)ch * NSEG + s) * 1024 + d;
    Hin[base * 16 + n] = h;
    h = __expf(A * Stot[base]) * h + Hloc[base * 16 + n];
  }
}

// ---------------- K7c: carry correction (R7 structure, per-lane cached loads) -
// grid 1536 = ch(bid>>8) x cg(bid&255); all blocks co-resident at 6/CU.
// R8's cooperative-stage variant doubled this kernel (4x over-fetch + stage
// barrier on critical path) -- reverted; per-lane 2B loads are L1-cached.
__global__ __launch_bounds__(256, 6) void k_scan2(
    const ushort_t* __restrict__ zgB, const ushort_t* __restrict__ dltB,
    const float* __restrict__ Cf, const float* __restrict__ alf,
    const float* __restrict__ Hin, float* __restrict__ sc) {
  __shared__ float red[4][72];
  int ch = blockIdx.x >> 8, cg = blockIdx.x & 255;
  int br = ch >> 1, b = ch & 1;
  int tid = threadIdx.x, w = tid >> 6, lane = tid & 63;
  int d = cg * 4 + w;
  const float L2E = 1.4426950408889634f;
  float A2_[16];
#pragma unroll
  for (int nn = 0; nn < 16; nn++)
    A2_[nn] = -__expf(alf[(size_t)br * (DI*NST) + d * NST + nn]) * L2E;
  const ushort_t* dlp = dltB + ((size_t)(ch * 64 + (d >> 4)) * SEQ) * 16;
  const ushort_t* zgp = zgB  + ((size_t)(b  * 64 + (d >> 4)) * SEQ) * 16;
  const float* Cfp = Cf + (size_t)ch * NST * SEQ;
  int dsub = d & 15;
  float* srow = sc + (size_t)b * SEQ;
  for (int seg = 1; seg < NSEG; seg++) {
    float Hn[16];
    const float* hp = Hin + (((size_t)ch * NSEG + seg) * 1024 + d) * 16;
#pragma unroll
    for (int nn = 0; nn < 16; nn++) Hn[nn] = hp[nn];
    float carry = 0.f;
    for (int w0 = seg * SEGL; w0 < seg * SEGL + SEGL; w0 += 64) {
      int t = w0 + lane;
      float dlt = b2f(dlp[(size_t)t * 16 + dsub]);
      float S = dlt;
#pragma unroll
      for (int ofs = 1; ofs < 64; ofs <<= 1) {
        float v = __shfl_up(S, ofs, 64);
        if (lane >= ofs) S += v;
      }
      float tot = __shfl(S, 63, 64);
      S += carry; carry += tot;
      float corr = 0.f;
#pragma unroll
      for (int nn = 0; nn < 16; nn++) {
        float Cn = Cfp[(size_t)nn * SEQ + t];
        corr = fmaf(Cn * Hn[nn], __builtin_amdgcn_exp2f(A2_[nn] * S), corr);
      }
      float gate = b2f(zgp[(size_t)pmap(br, t) * 16 + dsub]);
      float y = corr * gate;
      red[w][lane] = y;
      __syncthreads();
      if (w == 0) {
        float ytot = red[0][lane] + red[1][lane] + red[2][lane] + red[3][lane];
        atomicAdd(srow + omap(br, t), ytot);
      }
      __syncthreads();
    }
  }
}

// ---------------- K8: w_eff[d] = lin_w . out_proj_w[:,d]; zero score_acc ------
__global__ __launch_bounds__(256) void k_weff_init(const ushort_t* __restrict__ opwb,
    const ushort_t* __restrict__ lwb, float* __restrict__ weff, float* __restrict__ sc) {
  int i = blockIdx.x * 256 + threadIdx.x;
  if (i < DI) {
    float s = 0.f;
    for (int o = 0; o < DIMX; o++) s += b2f(lwb[o]) * b2f(opwb[(size_t)o * DI + i]);
    weff[i] = s;
  }
  int j = i - DI;
  if (j >= 0 && j < 2 * SEQ) sc[j] = 0.f;
}

// ---------------- K9: outputs (f32): group interp+sigmoid, individual ---------
__global__ __launch_bounds__(256) void k_out(const float* __restrict__ g0,
    const float* __restrict__ g1, const float* __restrict__ g2,
    const float* __restrict__ sc, const float* __restrict__ lbf,
    float* __restrict__ out) {
  int idx = blockIdx.x * 256 + threadIdx.x;
  if (idx < 3 * SEQ) {
    int j = idx / SEQ, t = idx % SEQ;
    const float* g = (j == 0) ? g0 : (j == 1) ? g1 : g2;
    float pos = t * ((float)(LGS - 1) / (float)(SEQ - 1));
    int i0 = (int)floorf(pos);
    if (i0 < 0) i0 = 0; if (i0 > LGS - 2) i0 = LGS - 2;
    float wt = pos - (float)i0;
    float v = g[i0] * (1.f - wt) + g[i0 + 1] * wt;
    out[idx] = 1.f / (1.f + __expf(-v));
  } else if (idx < 5 * SEQ) {
    float t = sc[idx - 3 * SEQ] + lbf[0];
    out[idx] = 1.f / (1.f + __expf(-t));
  }
}

extern "C" void kernel_launch(void* const* d_in, const int* in_sizes, int n_in,
                              void* d_out, int out_size, void* d_ws, size_t ws_size,
                              hipStream_t stream) {
  char* ws = (char*)d_ws;
  ushort_t* lwb   = (ushort_t*)(ws + OFF_LWB);
  float*    lngf  = (float*)(ws + OFF_LNGF);
  float*    lnbf  = (float*)(ws + OFF_LNBF);
  float*    lbf   = (float*)(ws + OFF_LBF);
  float*    cwf   = (float*)(ws + OFF_CWF);
  float*    cbf   = (float*)(ws + OFF_CBF);
  float*    dtbf  = (float*)(ws + OFF_DTBF);
  float*    alf   = (float*)(ws + OFF_ALF);
  float*    ddf   = (float*)(ws + OFF_DDF);
  float*    weff  = (float*)(ws + OFF_WEFF);
  float*    sc    = (float*)(ws + OFF_SC);
  ushort_t* dtwb  = (ushort_t*)(ws + OFF_DTWB);
  ushort_t* xpwb  = (ushort_t*)(ws + OFF_XPWB);
  ushort_t* opwb  = (ushort_t*)(ws + OFF_OPWB);
  ushort_t* inwb  = (ushort_t*)(ws + OFF_INWB);
  ushort_t* xd    = (ushort_t*)(ws + OFF_XD);
  ushort_t* dltB  = (ushort_t*)(ws + OFF_DLTB);
  ushort_t* xz    = (ushort_t*)(ws + OFF_XZ);
  float*    Bf    = (float*)(ws + OFF_BF);
  float*    Cf    = (float*)(ws + OFF_CF);
  ushort_t* uB    = (ushort_t*)(ws + OFF_UB);
  ushort_t* h     = (ushort_t*)(ws + OFF_H);
  ushort_t* zgB   = (ushort_t*)(ws + OFF_ZGB);
  float*    Hloc  = (float*)(ws + OFF_HLOC);
  float*    Hin   = (float*)(ws + OFF_HIN);
  float*    Stot  = (float*)(ws + OFF_STOT);
  float*    OUT   = (float*)d_out;

  Tab tab;
  int c = 0;
  tab.e[c++] = {d_in[3], inwb, E2 * DIMX, 0};
  tab.e[c++] = {d_in[4], opwb, DIMX * DI, 0};
  tab.e[c++] = {d_in[5], lwb, DIMX, 0};
  for (int br = 0; br < 3; br++) {
    int base = 10 + br * 7;
    tab.e[c++] = {d_in[base + 2], xpwb + (size_t)br * KXP * DI, KXP * DI, 0};
    tab.e[c++] = {d_in[base + 3], dtwb + (size_t)br * DI * DTR, DI * DTR, 0};
  }
  tab.e[c++] = {d_in[1], lngf, DIMX, 1};
  tab.e[c++] = {d_in[2], lnbf, DIMX, 1};
  tab.e[c++] = {d_in[6], lbf, 1, 1};
  for (int br = 0; br < 3; br++) {
    int base = 10 + br * 7;
    tab.e[c++] = {d_in[base + 0], cwf + (size_t)br * DI * 4, DI * 4, 1};
    tab.e[c++] = {d_in[base + 1], cbf + (size_t)br * DI, DI, 1};
    tab.e[c++] = {d_in[base + 4], dtbf + (size_t)br * DI, DI, 1};
    tab.e[c++] = {d_in[base + 5], alf + (size_t)br * DI * NST, DI * NST, 1};
    tab.e[c++] = {d_in[base + 6], ddf + (size_t)br * DI, DI, 1};
  }

  dim3 blk(256);
  k_import<<<dim3(64, c), blk, 0, stream>>>(tab, c);
  k_weff_init<<<44, blk, 0, stream>>>(opwb, lwb, weff, sc);
  k_ln<<<2560, blk, 0, stream>>>((const float*)d_in[0], lngf, lnbf, h);
  k_inproj<<<dim3(80, 16), blk, 0, stream>>>(h, inwb, weff, xz, zgB);
  k_conv<<<dim3(80, 16, 6), blk, 0, stream>>>(xz, cwf, cbf, uB);
  k_xdbl<<<dim3(80, 6), blk, 0, stream>>>(uB, xpwb, xd);
  k_bc<<<dim3(40, 6), blk, 0, stream>>>(xd, Bf, Cf);
  k_delta<<<dim3(40, 8, 6), blk, 0, stream>>>(xd, dtwb, dtbf, dltB);   // xz dead now
  k_scan1<<<3072, dim3(128), 0, stream>>>(dltB, uB, zgB, Bf, Cf, alf, ddf,
                                          sc, Hloc, Stot);
  k_stitch<<<384, blk, 0, stream>>>(Stot, Hloc, alf, Hin);
  k_scan2<<<1536, blk, 0, stream>>>(zgB, dltB, Cf, alf, Hin, sc);
  k_out<<<100, blk, 0, stream>>>((const float*)d_in[7], (const float*)d_in[8],
                                 (const float*)d_in[9], sc, lbf, OUT);
}

// Round 11
// 775.461 us; speedup vs baseline: 1.1940x; 1.0893x over previous
//
#include <hip/hip_runtime.h>
#include <stdint.h>

#define SEQ  5120
#define DIMX 512
#define E2   2048
#define DI   1024
#define NST  16
#define DTR  32
#define KXP  64
#define LGS  2048
#define NSL  5
#define NSEG 8
#define SEGL 640

typedef unsigned short ushort_t;
typedef __attribute__((ext_vector_type(8))) __bf16 bf16x8;
typedef __attribute__((ext_vector_type(4))) float f32x4;

__device__ __forceinline__ float b2f(ushort_t u) {
  union { unsigned int i; float f; } v; v.i = ((unsigned int)u) << 16; return v.f;
}
__device__ __forceinline__ ushort_t f2b(float f) {
  union { float f; unsigned int i; } v; v.f = f;
  unsigned int u = v.i;
  return (ushort_t)((u + 0x7FFFu + ((u >> 16) & 1u)) >> 16);
}

#define AS1 __attribute__((address_space(1)))
#define AS3 __attribute__((address_space(3)))
__device__ __forceinline__ void glds16(const void* g, void* l) {
  __builtin_amdgcn_global_load_lds((const AS1 void*)g, (AS3 void*)l, 16, 0, 0);
}

__device__ __forceinline__ int pmap(int br, int t) {   // scan pos -> data pos
  return (br == 0) ? t : (br == 1) ? (SEQ - 1 - t) : ((t % NSL) * 1024 + t / NSL);
}
__device__ __forceinline__ int omap(int br, int t) {   // scan pos -> output pos
  return (br == 0) ? t : (br == 1) ? (SEQ - 1 - t) : ((t & 1023) * NSL + (t >> 10));
}

// DPP lane-exchange (VALU pipe, not LDS/ds_swizzle):
//   xor1 = quad_perm(1,0,3,2)=0xB1; xor2 = quad_perm(2,3,0,1)=0x4E;
//   xor8 within 16-lane row = row_ror:8 = 0x128 ((i+8) mod 16 == i^8).
// All lanes valid in every exchange -> old=0/bound_ctrl irrelevant.
#define DPP_XOR1 0xB1
#define DPP_XOR2 0x4E
#define DPP_XOR8 0x128
template <int CTRL>
__device__ __forceinline__ float dpp_xchg(float x) {
  return __int_as_float(
      __builtin_amdgcn_update_dpp(0, __float_as_int(x), CTRL, 0xf, 0xf, true));
}

// 16-state transpose-reduce butterfly; xor8/2/1 stages on VALU via DPP,
// only the xor4 stage remains a ds_swizzle (no DPP encoding for i^4 in 16).
__device__ __forceinline__ float bfly16(const float* hC, int n) {
  float a8[8], a4[4], a2[2], y;
#pragma unroll
  for (int j = 0; j < 8; j++) {
    float keep = (n & 8) ? hC[j+8] : hC[j];
    float send = (n & 8) ? hC[j]   : hC[j+8];
    a8[j] = keep + dpp_xchg<DPP_XOR8>(send);
  }
#pragma unroll
  for (int j = 0; j < 4; j++) {
    float keep = (n & 4) ? a8[j+4] : a8[j];
    float send = (n & 4) ? a8[j]   : a8[j+4];
    a4[j] = keep + __shfl_xor(send, 4, 64);
  }
#pragma unroll
  for (int j = 0; j < 2; j++) {
    float keep = (n & 2) ? a4[j+2] : a4[j];
    float send = (n & 2) ? a4[j]   : a4[j+2];
    a2[j] = keep + dpp_xchg<DPP_XOR2>(send);
  }
  {
    float keep = (n & 1) ? a2[1] : a2[0];
    float send = (n & 1) ? a2[0] : a2[1];
    y = keep + dpp_xchg<DPP_XOR1>(send);
  }
  return y;
}

// ---------------- workspace layout (bytes) ------------------------------------
#define OFF_LWB   ((size_t)256)
#define OFF_LNGF  ((size_t)1280)
#define OFF_LNBF  ((size_t)3328)
#define OFF_LBF   ((size_t)5376)
#define OFF_CWF   ((size_t)5632)
#define OFF_CBF   ((size_t)54784)
#define OFF_DTBF  ((size_t)67072)
#define OFF_ALF   ((size_t)79360)
#define OFF_DDF   ((size_t)275968)
#define OFF_WEFF  ((size_t)288256)
#define OFF_SC    ((size_t)292352)
#define OFF_DTWB  ((size_t)333312)      // bf16 dt_w, 3*1024*32*2 = 196,608
#define OFF_XPWB  ((size_t)529920)
#define OFF_OPWB  ((size_t)923136)
#define OFF_INWB  ((size_t)1971712)     // ends 4,068,864
#define OFF_XD    ((size_t)4068864)     // 6*5120*64*2 = 3,932,160 -> 8,001,024
#define OFF_DLTB  ((size_t)8001024)     // 6*5120*1024*2 = 62,914,560 -> 70,915,584
#define OFF_XZ    OFF_DLTB              // xz (42 MB) nested; dead before k_delta writes
#define OFF_BF    ((size_t)70915584)    // 1,966,080 -> 72,881,664
#define OFF_CF    ((size_t)72881664)    // 1,966,080 -> 74,847,744
#define OFF_HLOC  ((size_t)74847744)    // 3,145,728 -> 77,993,472
#define OFF_HIN   ((size_t)77993472)    // 3,145,728 -> 81,139,200
#define OFF_STOT  ((size_t)81139200)    // 196,608  -> 81,335,808
#define OFF_UB    ((size_t)81335808)    // 62,914,560 -> 144,250,368
#define OFF_H     OFF_UB                // ln-out h (10 MB) nested; dead before conv
#define OFF_ZGB   ((size_t)144250368)   // 20,971,520 -> 165,221,888
// total ~165.2 MiB

// ---------------- K0: batched import (f32 params -> ws, bf16 or f32) ----------
struct Ent { const void* s; void* d; int n; int fmt; };
struct Tab { Ent e[32]; };

__global__ __launch_bounds__(256) void k_import(Tab t, int cnt) {
  int id = blockIdx.y;
  if (id >= cnt) return;
  Ent E = t.e[id];
  int stride = gridDim.x * 256;
  const float* s = (const float*)E.s;
  if (E.fmt == 0) {
    ushort_t* dst = (ushort_t*)E.d;
    for (int i = blockIdx.x * 256 + threadIdx.x; i < E.n; i += stride) dst[i] = f2b(s[i]);
  } else {
    float* dst = (float*)E.d;
    for (int i = blockIdx.x * 256 + threadIdx.x; i < E.n; i += stride) dst[i] = s[i];
  }
}

// ---------------- K1: LayerNorm + ReLU -> h (bf16, both batches) --------------
__global__ __launch_bounds__(256) void k_ln(const float* __restrict__ x,
    const float* __restrict__ gam, const float* __restrict__ bet,
    ushort_t* __restrict__ h) {
  int token = blockIdx.x * 4 + (threadIdx.x >> 6);
  int lane = threadIdx.x & 63;
  const float* row = x + (size_t)token * DIMX + lane * 8;
  float4 a0 = *(const float4*)(row);
  float4 a1 = *(const float4*)(row + 4);
  float v[8] = {a0.x,a0.y,a0.z,a0.w,a1.x,a1.y,a1.z,a1.w};
  float s = 0.f, ss = 0.f;
#pragma unroll
  for (int i = 0; i < 8; i++) { s += v[i]; ss += v[i]*v[i]; }
#pragma unroll
  for (int m = 1; m < 64; m <<= 1) { s += __shfl_xor(s, m, 64); ss += __shfl_xor(ss, m, 64); }
  float mean = s * (1.f / DIMX);
  float rs = rsqrtf(ss * (1.f / DIMX) - mean * mean + 1e-5f);
  ushort_t o[8];
#pragma unroll
  for (int i = 0; i < 8; i++) {
    float y = (v[i] - mean) * rs * gam[lane*8+i] + bet[lane*8+i];
    o[i] = f2b(fmaxf(y, 0.f));
  }
  ushort_t* orow = h + (size_t)token * DIMX + lane * 8;
  *(ushort4*)(orow)     = make_ushort4(o[0],o[1],o[2],o[3]);
  *(ushort4*)(orow + 4) = make_ushort4(o[4],o[5],o[6],o[7]);
}

// ---------------- K2: in_proj GEMM (M=10240): xz[bl][e] = h @ W^T -------------
__global__ __launch_bounds__(256) void k_inproj(const ushort_t* __restrict__ hA,
    const ushort_t* __restrict__ Wb, ushort_t* __restrict__ xz) {
  __shared__ ushort_t As[128*32];
  __shared__ ushort_t Bs[128*32];
  const int tid = threadIdx.x;
  const int w = tid >> 6, lane = tid & 63;
  const int wr = w >> 1, wc = w & 1;
  const int m0 = blockIdx.x * 128, n0 = blockIdx.y * 128;
  const int lrow = lane & 15, lko = (lane >> 4) * 8;
  f32x4 acc[4][4];
#pragma unroll
  for (int i = 0; i < 4; i++)
#pragma unroll
    for (int j = 0; j < 4; j++) acc[i][j] = (f32x4){0.f,0.f,0.f,0.f};
  for (int k0 = 0; k0 < DIMX; k0 += 32) {
    __syncthreads();
#pragma unroll
    for (int r = 0; r < 2; r++) {
      int e = r * 256 + tid;
      int row = e >> 2, seg = e & 3;
      glds16(hA + (size_t)(m0 + row) * DIMX + k0 + seg * 8, &As[row*32 + seg*8]);
      glds16(Wb + (size_t)(n0 + row) * DIMX + k0 + seg * 8, &Bs[row*32 + seg*8]);
    }
    __syncthreads();
    bf16x8 aF[4], bF[4];
#pragma unroll
    for (int i = 0; i < 4; i++)
      aF[i] = *(const bf16x8*)&As[(wr*64 + i*16 + lrow)*32 + lko];
#pragma unroll
    for (int j = 0; j < 4; j++)
      bF[j] = *(const bf16x8*)&Bs[(wc*64 + j*16 + lrow)*32 + lko];
#pragma unroll
    for (int i = 0; i < 4; i++)
#pragma unroll
      for (int j = 0; j < 4; j++)
        acc[i][j] = __builtin_amdgcn_mfma_f32_16x16x32_bf16(aF[i], bF[j], acc[i][j], 0, 0, 0);
  }
#pragma unroll
  for (int i = 0; i < 4; i++)
#pragma unroll
    for (int j = 0; j < 4; j++)
#pragma unroll
      for (int r = 0; r < 4; r++) {
        int m = m0 + wr*64 + i*16 + (lane>>4)*4 + r;
        int n = n0 + wc*64 + j*16 + lrow;
        xz[(size_t)m * E2 + n] = f2b(acc[i][j][r]);
      }
}

// ---------------- K4: conv + silu -> uB[ch][d>>4][t][16] (blocked) ------------
__global__ __launch_bounds__(256) void k_conv(const ushort_t* __restrict__ xz,
    const float* __restrict__ cwA, const float* __restrict__ cbA,
    ushort_t* __restrict__ uB) {
  __shared__ ushort_t xs[67][64];
  int ch = blockIdx.z, br = ch >> 1, b = ch & 1;
  int t0 = blockIdx.x * 64, d0 = blockIdx.y * 64;
  int tid = threadIdx.x, col = tid & 63, rg = tid >> 6;
  const float* cw = cwA + (size_t)br * DI * 4;
  const float* cb = cbA + (size_t)br * DI;
#pragma unroll
  for (int i = 0; i < 17; i++) {
    int row = rg + i * 4;
    if (row < 67) {
      int tau = t0 - 3 + row;
      ushort_t val = 0;
      if (tau >= 0) val = xz[((size_t)b * SEQ + pmap(br, tau)) * E2 + d0 + col];
      xs[row][col] = val;
    }
  }
  __syncthreads();
  int d = d0 + col;
  float w0 = cw[d*4+0], w1 = cw[d*4+1], w2 = cw[d*4+2], w3 = cw[d*4+3];
  float bias = cb[d];
  size_t dbbase = ((size_t)(ch * 64 + (d >> 4))) * SEQ;
#pragma unroll
  for (int i = 0; i < 16; i++) {
    int ti = rg + i * 4;
    float a = bias + w0*b2f(xs[ti][col]) + w1*b2f(xs[ti+1][col])
                   + w2*b2f(xs[ti+2][col]) + w3*b2f(xs[ti+3][col]);
    float val = a / (1.f + __expf(-a));
    uB[(dbbase + t0 + ti) * 16 + (col & 15)] = f2b(val);
  }
}

// ---------------- K4b: gate precompute -> zgB[b][d>>4][l][16] (blocked) -------
__global__ __launch_bounds__(256) void k_zg(const ushort_t* __restrict__ xz,
    const float* __restrict__ weff, ushort_t* __restrict__ zgB) {
  int b = blockIdx.z;
  int l0 = blockIdx.x * 64, d0 = blockIdx.y * 64;
  int tid = threadIdx.x, col = tid & 63, rg = tid >> 6;
  int d = d0 + col;
  float wef = weff[d];
  size_t dbbase = ((size_t)(b * 64 + (d >> 4))) * SEQ;
#pragma unroll
  for (int i = 0; i < 16; i++) {
    int l = l0 + rg + i * 4;
    float zr = b2f(xz[((size_t)b * SEQ + l) * E2 + DI + d]);
    float z = zr / (1.f + __expf(-zr));
    zgB[(dbbase + l) * 16 + (col & 15)] = f2b(z * wef);
  }
}

// ---------------- K5: x_dbl GEMM (reads blocked uB): xd[ch][t][64] ------------
__global__ __launch_bounds__(256) void k_xdbl(const ushort_t* __restrict__ uB,
    const ushort_t* __restrict__ xpwA, ushort_t* __restrict__ xdA) {
  __shared__ ushort_t As[64*32];
  __shared__ ushort_t Bs[64*32];
  int ch = blockIdx.y, br = ch >> 1;
  const ushort_t* xpw = xpwA + (size_t)br * KXP * DI;
  ushort_t* xd = xdA + (size_t)ch * SEQ * KXP;
  int t0 = blockIdx.x * 64;
  int tid = threadIdx.x, w = tid >> 6, lane = tid & 63;
  int lrow = lane & 15, lko = (lane >> 4) * 8;
  int row = tid >> 2, seg = tid & 3;
  f32x4 acc[4];
#pragma unroll
  for (int j = 0; j < 4; j++) acc[j] = (f32x4){0.f,0.f,0.f,0.f};
  for (int k0 = 0; k0 < DI; k0 += 32) {
    __syncthreads();
    glds16(uB + (((size_t)(ch*64 + (k0>>4) + (seg>>1)) * SEQ + t0 + row) * 16 + (seg&1)*8),
           &As[row*32 + seg*8]);
    glds16(xpw + (size_t)row * DI + k0 + seg * 8, &Bs[row*32 + seg*8]);
    __syncthreads();
    bf16x8 aF = *(const bf16x8*)&As[(w*16 + lrow)*32 + lko];
#pragma unroll
    for (int j = 0; j < 4; j++) {
      bf16x8 bF = *(const bf16x8*)&Bs[(j*16 + lrow)*32 + lko];
      acc[j] = __builtin_amdgcn_mfma_f32_16x16x32_bf16(aF, bF, acc[j], 0, 0, 0);
    }
  }
#pragma unroll
  for (int j = 0; j < 4; j++)
#pragma unroll
    for (int r = 0; r < 4; r++) {
      int t = t0 + w*16 + (lane>>4)*4 + r;
      xd[(size_t)t * KXP + j*16 + lrow] = f2b(acc[j][r]);
    }
}

// ---------------- K5b: expand xd B/C -> Bf/Cf[ch][n][t] f32 -------------------
__global__ __launch_bounds__(256) void k_bc(const ushort_t* __restrict__ xdA,
    float* __restrict__ Bf, float* __restrict__ Cf) {
  __shared__ float tb[128][34];
  int ch = blockIdx.y, t0 = blockIdx.x * 128;
  int tid = threadIdx.x;
  const ushort_t* xdb = xdA + (size_t)ch * SEQ * KXP;
#pragma unroll
  for (int i = 0; i < 2; i++) {
    int r = (tid >> 2) + i * 64;
    int q = tid & 3;
    const ushort_t* p = xdb + (size_t)(t0 + r) * KXP + 32 + q * 8;
    uint4 v = *(const uint4*)p;
    unsigned int wd[4] = {v.x, v.y, v.z, v.w};
    float* dst = &tb[r][q * 8];
#pragma unroll
    for (int j = 0; j < 4; j++) {
      dst[2*j]   = __uint_as_float(wd[j] << 16);
      dst[2*j+1] = __uint_as_float(wd[j] & 0xFFFF0000u);
    }
  }
  __syncthreads();
  int nn = tid >> 4, sg = tid & 15;
  float ob[8], oc[8];
#pragma unroll
  for (int j = 0; j < 8; j++) {
    ob[j] = tb[sg*8 + j][nn];
    oc[j] = tb[sg*8 + j][16 + nn];
  }
  float* Bp = Bf + ((size_t)ch * NST + nn) * SEQ + t0 + sg * 8;
  float* Cp = Cf + ((size_t)ch * NST + nn) * SEQ + t0 + sg * 8;
  *(float4*)Bp       = make_float4(ob[0],ob[1],ob[2],ob[3]);
  *(float4*)(Bp + 4) = make_float4(ob[4],ob[5],ob[6],ob[7]);
  *(float4*)Cp       = make_float4(oc[0],oc[1],oc[2],oc[3]);
  *(float4*)(Cp + 4) = make_float4(oc[4],oc[5],oc[6],oc[7]);
}

// ---------------- K6: delta GEMM (K=32) + softplus -> dltB (blocked) ----------
// grid (40 t-tiles, 8 d-tiles, 6 ch)
__global__ __launch_bounds__(256) void k_delta(const ushort_t* __restrict__ xdA,
    const ushort_t* __restrict__ dtwb, const float* __restrict__ dtbf,
    ushort_t* __restrict__ dltB) {
  __shared__ ushort_t As[128*32];
  __shared__ ushort_t Bs[128*32];
  int ch = blockIdx.z, br = ch >> 1;
  int t0 = blockIdx.x * 128, d0 = blockIdx.y * 128;
  int tid = threadIdx.x, w = tid >> 6, lane = tid & 63;
  int wr = w >> 1, wc = w & 1;
  int lrow = lane & 15, lko = (lane >> 4) * 8;
  const ushort_t* xdb = xdA + (size_t)ch * SEQ * KXP;
  const ushort_t* dwp = dtwb + (size_t)br * DI * DTR;
#pragma unroll
  for (int r = 0; r < 2; r++) {
    int e = r * 256 + tid;
    int row = e >> 2, seg = e & 3;
    glds16(xdb + (size_t)(t0 + row) * KXP + seg * 8, &As[row*32 + seg*8]);
    glds16(dwp + (size_t)(d0 + row) * DTR + seg * 8, &Bs[row*32 + seg*8]);
  }
  __syncthreads();
  bf16x8 aF[4], bF[4];
#pragma unroll
  for (int i = 0; i < 4; i++)
    aF[i] = *(const bf16x8*)&As[(wr*64 + i*16 + lrow)*32 + lko];
#pragma unroll
  for (int j = 0; j < 4; j++)
    bF[j] = *(const bf16x8*)&Bs[(wc*64 + j*16 + lrow)*32 + lko];
  f32x4 acc[4][4];
#pragma unroll
  for (int i = 0; i < 4; i++)
#pragma unroll
    for (int j = 0; j < 4; j++) {
      acc[i][j] = (f32x4){0.f,0.f,0.f,0.f};
      acc[i][j] = __builtin_amdgcn_mfma_f32_16x16x32_bf16(aF[i], bF[j], acc[i][j], 0, 0, 0);
    }
#pragma unroll
  for (int i = 0; i < 4; i++)
#pragma unroll
    for (int j = 0; j < 4; j++)
#pragma unroll
      for (int r = 0; r < 4; r++) {
        int t = t0 + wr*64 + i*16 + (lane>>4)*4 + r;
        int d = d0 + wc*64 + j*16 + lrow;
        float xv = acc[i][j][r] + dtbf[br * DI + d];
        float sp = (xv > 20.f) ? xv : log1pf(__expf(xv));
        dltB[(((size_t)(ch*64 + (d>>4))) * SEQ + t) * 16 + (d & 15)] = f2b(sp);
      }
}

// ---------------- K7a: segmented local scan (8 ch/wave, merged butterfly) -----
// grid 3072 = ch(bid>>9) x seg((bid>>6)&7) x dblk(bid&63); 128-thread blocks.
__global__ __launch_bounds__(128, 5) void k_scan1(
    const ushort_t* __restrict__ dltB, const ushort_t* __restrict__ uB,
    const ushort_t* __restrict__ zgB, const float* __restrict__ Bf,
    const float* __restrict__ Cf, const float* __restrict__ alf,
    const float* __restrict__ ddf, float* __restrict__ sc,
    float* __restrict__ Hloc, float* __restrict__ Stot) {
  __shared__ __align__(16) float BS[2][16][18];
  __shared__ __align__(16) float CS[2][16][18];
  __shared__ __align__(16) float4 dd4[2][4][17];   // (dltA, duA, dltB, duB)
  __shared__ float2 gS[2][4][17];                  // (gateA, gateB)
  int bid = blockIdx.x;
  int dblk = bid & 63, seg = (bid >> 6) & 7, ch = bid >> 9;
  int br = ch >> 1, b = ch & 1;
  int tid = threadIdx.x, w = tid >> 6, lane = tid & 63, g = lane >> 4, n = lane & 15;
  int da = w * 8 + g;            // channel A position within the 16-block
  int db = da + 4;               // channel B
  int dA = dblk * 16 + da, dB = dblk * 16 + db;
  const float L2E = 1.4426950408889634f;
  float ApA = -__expf(alf[br * (DI*NST) + dA * NST + n]) * L2E;
  float ApB = -__expf(alf[br * (DI*NST) + dB * NST + n]) * L2E;
  float DdA = ddf[br * DI + dA], DdB = ddf[br * DI + dB];
  const ushort_t* dlp = dltB + ((size_t)(ch * 64 + dblk) * SEQ) * 16;
  const ushort_t* uBp = uB   + ((size_t)(ch * 64 + dblk) * SEQ) * 16;
  const ushort_t* zgp = zgB  + ((size_t)(b  * 64 + dblk) * SEQ) * 16;
  const float* Bfp = Bf + ((size_t)ch * NST) * SEQ;
  const float* Cfp = Cf + ((size_t)ch * NST) * SEQ;
  float* srow = sc + (size_t)b * SEQ;
  float hstA = 0.f, hstB = 0.f, SaccA = 0.f, SaccB = 0.f;
  int sn = lane >> 2, sq = lane & 3;
  for (int t0 = seg * SEGL; t0 < seg * SEGL + SEGL; t0 += 16) {
    // stage B/C window (per-wave copy; wave-lockstep, no sync needed)
    *(float4*)&BS[w][sn][sq*4] = *(const float4*)&Bfp[(size_t)sn * SEQ + t0 + sq*4];
    *(float4*)&CS[w][sn][sq*4] = *(const float4*)&Cfp[(size_t)sn * SEQ + t0 + sq*4];
    size_t rowo = (size_t)(t0 + n) * 16;
    float dltA = b2f(dlp[rowo + da]);
    float dltBv = b2f(dlp[rowo + db]);
    float uA = b2f(uBp[rowo + da]);
    float uBv = b2f(uBp[rowo + db]);
    size_t growo = (size_t)pmap(br, t0 + n) * 16;
    float gA = b2f(zgp[growo + da]);
    float gB = b2f(zgp[growo + db]);
    SaccA += dltA; SaccB += dltBv;
    dd4[w][g][n] = make_float4(dltA, dltA * uA, dltBv, dltBv * uBv);
    gS[w][g][n]  = make_float2(gA, gB);
    float dug = fmaf(DdA * uA, gA, DdB * uBv * gB);  // per-timestep skip term
    float Bk[16], Ck[16];
#pragma unroll
    for (int j = 0; j < 4; j++) {
      *(float4*)&Bk[j*4] = *(const float4*)&BS[w][n][j*4];
      *(float4*)&Ck[j*4] = *(const float4*)&CS[w][n][j*4];
    }
    float hC[16];
#pragma unroll
    for (int k = 0; k < 16; k++) {
      float4 v = dd4[w][g][k];
      float2 gg = gS[w][g][k];
      hstA = fmaf(__builtin_amdgcn_exp2f(v.x * ApA), hstA, v.y * Bk[k]);
      hstB = fmaf(__builtin_amdgcn_exp2f(v.z * ApB), hstB, v.w * Bk[k]);
      hC[k] = fmaf(hstA, gg.x, hstB * gg.y) * Ck[k];
    }
    float y = bfly16(hC, n) + dug;     // both channels of this lane, gated
    y += __shfl_xor(y, 16, 64);        // + across g (4 groups = 8 channels)
    y += __shfl_xor(y, 32, 64);
    if (lane < 16) atomicAdd(srow + omap(br, t0 + lane), y);
  }
  Hloc[(((size_t)ch * NSEG + seg) * 1024 + dA) * 16 + n] = hstA;
  Hloc[(((size_t)ch * NSEG + seg) * 1024 + dB) * 16 + n] = hstB;
#pragma unroll
  for (int m = 1; m < 16; m <<= 1) {
    SaccA += __shfl_xor(SaccA, m, 64);
    SaccB += __shfl_xor(SaccB, m, 64);
  }
  if (n == 0) {
    Stot[((size_t)ch * NSEG + seg) * 1024 + dA] = SaccA;
    Stot[((size_t)ch * NSEG + seg) * 1024 + dB] = SaccB;
  }
}

// ---------------- K7b: stitch segment states ----------------------------------
__global__ __launch_bounds__(256) void k_stitch(const float* __restrict__ Stot,
    const float* __restrict__ Hloc, const float* __restrict__ alf,
    float* __restrict__ Hin) {
  int idx = blockIdx.x * 256 + threadIdx.x;     // 98304 = 6*1024*16
  int ch = idx >> 14, rem = idx & 16383, d = rem >> 4, n = rem & 15;
  int br = ch >> 1;
  float A = -__expf(alf[(size_t)br * (DI*NST) + d * NST + n]);
  float h = 0.f;
  for (int s = 0; s < NSEG; s++) {
    size_t base = ((size_t)ch * NSEG + s) * 1024 + d;
    Hin[base * 16 + n] = h;
    h = __expf(A * Stot[base]) * h + Hloc[base * 16 + n];
  }
}

// ---------------- K7c: carry correction (per-lane cached loads, exp2) ---------
// grid 1536 = ch(bid>>8) x cg(bid&255); all blocks co-resident at 6/CU.
__global__ __launch_bounds__(256, 6) void k_scan2(
    const ushort_t* __restrict__ zgB, const ushort_t* __restrict__ dltB,
    const float* __restrict__ Cf, const float* __restrict__ alf,
    const float* __restrict__ Hin, float* __restrict__ sc) {
  __shared__ float red[4][72];
  int ch = blockIdx.x >> 8, cg = blockIdx.x & 255;
  int br = ch >> 1, b = ch & 1;
  int tid = threadIdx.x, w = tid >> 6, lane = tid & 63;
  int d = cg * 4 + w;
  const float L2E = 1.4426950408889634f;
  float A2_[16];
#pragma unroll
  for (int nn = 0; nn < 16; nn++)
    A2_[nn] = -__expf(alf[(size_t)br * (DI*NST) + d * NST + nn]) * L2E;
  const ushort_t* dlp = dltB + ((size_t)(ch * 64 + (d >> 4)) * SEQ) * 16;
  const ushort_t* zgp = zgB  + ((size_t)(b  * 64 + (d >> 4)) * SEQ) * 16;
  const float* Cfp = Cf + (size_t)ch * NST * SEQ;
  int dsub = d & 15;
  float* srow = sc + (size_t)b * SEQ;
  for (int seg = 1; seg < NSEG; seg++) {
    float Hn[16];
    const float* hp = Hin + (((size_t)ch * NSEG + seg) * 1024 + d) * 16;
#pragma unroll
    for (int nn = 0; nn < 16; nn++) Hn[nn] = hp[nn];
    float carry = 0.f;
    for (int w0 = seg * SEGL; w0 < seg * SEGL + SEGL; w0 += 64) {
      int t = w0 + lane;
      float dlt = b2f(dlp[(size_t)t * 16 + dsub]);
      float S = dlt;
#pragma unroll
      for (int ofs = 1; ofs < 64; ofs <<= 1) {
        float v = __shfl_up(S, ofs, 64);
        if (lane >= ofs) S += v;
      }
      float tot = __shfl(S, 63, 64);
      S += carry; carry += tot;
      float corr = 0.f;
#pragma unroll
      for (int nn = 0; nn < 16; nn++) {
        float Cn = Cfp[(size_t)nn * SEQ + t];
        corr = fmaf(Cn * Hn[nn], __builtin_amdgcn_exp2f(A2_[nn] * S), corr);
      }
      float gate = b2f(zgp[(size_t)pmap(br, t) * 16 + dsub]);
      float y = corr * gate;
      red[w][lane] = y;
      __syncthreads();
      if (w == 0) {
        float ytot = red[0][lane] + red[1][lane] + red[2][lane] + red[3][lane];
        atomicAdd(srow + omap(br, t), ytot);
      }
      __syncthreads();
    }
  }
}

// ---------------- K8: w_eff[d] = lin_w . out_proj_w[:,d]; zero score_acc ------
__global__ __launch_bounds__(256) void k_weff_init(const ushort_t* __restrict__ opwb,
    const ushort_t* __restrict__ lwb, float* __restrict__ weff, float* __restrict__ sc) {
  int i = blockIdx.x * 256 + threadIdx.x;
  if (i < DI) {
    float s = 0.f;
    for (int o = 0; o < DIMX; o++) s += b2f(lwb[o]) * b2f(opwb[(size_t)o * DI + i]);
    weff[i] = s;
  }
  int j = i - DI;
  if (j >= 0 && j < 2 * SEQ) sc[j] = 0.f;
}

// ---------------- K9: outputs (f32): group interp+sigmoid, individual ---------
__global__ __launch_bounds__(256) void k_out(const float* __restrict__ g0,
    const float* __restrict__ g1, const float* __restrict__ g2,
    const float* __restrict__ sc, const float* __restrict__ lbf,
    float* __restrict__ out) {
  int idx = blockIdx.x * 256 + threadIdx.x;
  if (idx < 3 * SEQ) {
    int j = idx / SEQ, t = idx % SEQ;
    const float* g = (j == 0) ? g0 : (j == 1) ? g1 : g2;
    float pos = t * ((float)(LGS - 1) / (float)(SEQ - 1));
    int i0 = (int)floorf(pos);
    if (i0 < 0) i0 = 0; if (i0 > LGS - 2) i0 = LGS - 2;
    float wt = pos - (float)i0;
    float v = g[i0] * (1.f - wt) + g[i0 + 1] * wt;
    out[idx] = 1.f / (1.f + __expf(-v));
  } else if (idx < 5 * SEQ) {
    float t = sc[idx - 3 * SEQ] + lbf[0];
    out[idx] = 1.f / (1.f + __expf(-t));
  }
}

extern "C" void kernel_launch(void* const* d_in, const int* in_sizes, int n_in,
                              void* d_out, int out_size, void* d_ws, size_t ws_size,
                              hipStream_t stream) {
  char* ws = (char*)d_ws;
  ushort_t* lwb   = (ushort_t*)(ws + OFF_LWB);
  float*    lngf  = (float*)(ws + OFF_LNGF);
  float*    lnbf  = (float*)(ws + OFF_LNBF);
  float*    lbf   = (float*)(ws + OFF_LBF);
  float*    cwf   = (float*)(ws + OFF_CWF);
  float*    cbf   = (float*)(ws + OFF_CBF);
  float*    dtbf  = (float*)(ws + OFF_DTBF);
  float*    alf   = (float*)(ws + OFF_ALF);
  float*    ddf   = (float*)(ws + OFF_DDF);
  float*    weff  = (float*)(ws + OFF_WEFF);
  float*    sc    = (float*)(ws + OFF_SC);
  ushort_t* dtwb  = (ushort_t*)(ws + OFF_DTWB);
  ushort_t* xpwb  = (ushort_t*)(ws + OFF_XPWB);
  ushort_t* opwb  = (ushort_t*)(ws + OFF_OPWB);
  ushort_t* inwb  = (ushort_t*)(ws + OFF_INWB);
  ushort_t* xd    = (ushort_t*)(ws + OFF_XD);
  ushort_t* dltB  = (ushort_t*)(ws + OFF_DLTB);
  ushort_t* xz    = (ushort_t*)(ws + OFF_XZ);
  float*    Bf    = (float*)(ws + OFF_BF);
  float*    Cf    = (float*)(ws + OFF_CF);
  ushort_t* uB    = (ushort_t*)(ws + OFF_UB);
  ushort_t* h     = (ushort_t*)(ws + OFF_H);
  ushort_t* zgB   = (ushort_t*)(ws + OFF_ZGB);
  float*    Hloc  = (float*)(ws + OFF_HLOC);
  float*    Hin   = (float*)(ws + OFF_HIN);
  float*    Stot  = (float*)(ws + OFF_STOT);
  float*    OUT   = (float*)d_out;

  Tab tab;
  int c = 0;
  tab.e[c++] = {d_in[3], inwb, E2 * DIMX, 0};
  tab.e[c++] = {d_in[4], opwb, DIMX * DI, 0};
  tab.e[c++] = {d_in[5], lwb, DIMX, 0};
  for (int br = 0; br < 3; br++) {
    int base = 10 + br * 7;
    tab.e[c++] = {d_in[base + 2], xpwb + (size_t)br * KXP * DI, KXP * DI, 0};
    tab.e[c++] = {d_in[base + 3], dtwb + (size_t)br * DI * DTR, DI * DTR, 0};
  }
  tab.e[c++] = {d_in[1], lngf, DIMX, 1};
  tab.e[c++] = {d_in[2], lnbf, DIMX, 1};
  tab.e[c++] = {d_in[6], lbf, 1, 1};
  for (int br = 0; br < 3; br++) {
    int base = 10 + br * 7;
    tab.e[c++] = {d_in[base + 0], cwf + (size_t)br * DI * 4, DI * 4, 1};
    tab.e[c++] = {d_in[base + 1], cbf + (size_t)br * DI, DI, 1};
    tab.e[c++] = {d_in[base + 4], dtbf + (size_t)br * DI, DI, 1};
    tab.e[c++] = {d_in[base + 5], alf + (size_t)br * DI * NST, DI * NST, 1};
    tab.e[c++] = {d_in[base + 6], ddf + (size_t)br * DI, DI, 1};
  }

  dim3 blk(256);
  k_import<<<dim3(64, c), blk, 0, stream>>>(tab, c);
  k_weff_init<<<44, blk, 0, stream>>>(opwb, lwb, weff, sc);
  k_ln<<<2560, blk, 0, stream>>>((const float*)d_in[0], lngf, lnbf, h);
  k_inproj<<<dim3(80, 16), blk, 0, stream>>>(h, inwb, xz);
  k_conv<<<dim3(80, 16, 6), blk, 0, stream>>>(xz, cwf, cbf, uB);
  k_zg<<<dim3(80, 16, 2), blk, 0, stream>>>(xz, weff, zgB);
  k_xdbl<<<dim3(80, 6), blk, 0, stream>>>(uB, xpwb, xd);
  k_bc<<<dim3(40, 6), blk, 0, stream>>>(xd, Bf, Cf);
  k_delta<<<dim3(40, 8, 6), blk, 0, stream>>>(xd, dtwb, dtbf, dltB);   // xz dead now
  k_scan1<<<3072, dim3(128), 0, stream>>>(dltB, uB, zgB, Bf, Cf, alf, ddf,
                                          sc, Hloc, Stot);
  k_stitch<<<384, blk, 0, stream>>>(Stot, Hloc, alf, Hin);
  k_scan2<<<1536, blk, 0, stream>>>(zgB, dltB, Cf, alf, Hin, sc);
  k_out<<<100, blk, 0, stream>>>((const float*)d_in[7], (const float*)d_in[8],
                                 (const float*)d_in[9], sc, lbf, OUT);
}

// Round 12
// 750.847 us; speedup vs baseline: 1.2332x; 1.0328x over previous
//
#include <hip/hip_runtime.h>
#include <stdint.h>

#define SEQ  5120
#define DIMX 512
#define E2   2048
#define DI   1024
#define NST  16
#define DTR  32
#define KXP  64
#define LGS  2048
#define NSL  5
#define NSEG 8
#define SEGL 640

typedef unsigned short ushort_t;
typedef __attribute__((ext_vector_type(8))) __bf16 bf16x8;
typedef __attribute__((ext_vector_type(4))) float f32x4;

__device__ __forceinline__ float b2f(ushort_t u) {
  union { unsigned int i; float f; } v; v.i = ((unsigned int)u) << 16; return v.f;
}
__device__ __forceinline__ ushort_t f2b(float f) {
  union { float f; unsigned int i; } v; v.f = f;
  unsigned int u = v.i;
  return (ushort_t)((u + 0x7FFFu + ((u >> 16) & 1u)) >> 16);
}

#define AS1 __attribute__((address_space(1)))
#define AS3 __attribute__((address_space(3)))
__device__ __forceinline__ void glds16(const void* g, void* l) {
  __builtin_amdgcn_global_load_lds((const AS1 void*)g, (AS3 void*)l, 16, 0, 0);
}

__device__ __forceinline__ int pmap(int br, int t) {   // scan pos -> data pos
  return (br == 0) ? t : (br == 1) ? (SEQ - 1 - t) : ((t % NSL) * 1024 + t / NSL);
}
__device__ __forceinline__ int omap(int br, int t) {   // scan pos -> output pos
  return (br == 0) ? t : (br == 1) ? (SEQ - 1 - t) : ((t & 1023) * NSL + (t >> 10));
}

// 16-state transpose-reduce butterfly (proven R7 form; DPP variant regressed
// in R11: serial VALU dependency chains cost more than the ds_swizzles).
__device__ __forceinline__ float bfly16(const float* hC, int n) {
  float a8[8], a4[4], a2[2], y;
#pragma unroll
  for (int j = 0; j < 8; j++) {
    float keep = (n & 8) ? hC[j+8] : hC[j];
    float send = (n & 8) ? hC[j]   : hC[j+8];
    a8[j] = keep + __shfl_xor(send, 8, 64);
  }
#pragma unroll
  for (int j = 0; j < 4; j++) {
    float keep = (n & 4) ? a8[j+4] : a8[j];
    float send = (n & 4) ? a8[j]   : a8[j+4];
    a4[j] = keep + __shfl_xor(send, 4, 64);
  }
#pragma unroll
  for (int j = 0; j < 2; j++) {
    float keep = (n & 2) ? a4[j+2] : a4[j];
    float send = (n & 2) ? a4[j]   : a4[j+2];
    a2[j] = keep + __shfl_xor(send, 2, 64);
  }
  {
    float keep = (n & 1) ? a2[1] : a2[0];
    float send = (n & 1) ? a2[0] : a2[1];
    y = keep + __shfl_xor(send, 1, 64);
  }
  return y;
}

// ---------------- workspace layout (bytes) ------------------------------------
#define OFF_LWB   ((size_t)256)
#define OFF_LNGF  ((size_t)1280)
#define OFF_LNBF  ((size_t)3328)
#define OFF_LBF   ((size_t)5376)
#define OFF_CWF   ((size_t)5632)
#define OFF_CBF   ((size_t)54784)
#define OFF_DTBF  ((size_t)67072)
#define OFF_ALF   ((size_t)79360)
#define OFF_DDF   ((size_t)275968)
#define OFF_WEFF  ((size_t)288256)
#define OFF_SC    ((size_t)292352)
#define OFF_DTWB  ((size_t)333312)      // bf16 dt_w, 3*1024*32*2 = 196,608
#define OFF_XPWB  ((size_t)529920)
#define OFF_OPWB  ((size_t)923136)
#define OFF_INWB  ((size_t)1971712)     // ends 4,068,864
#define OFF_XD    ((size_t)4068864)     // 6*5120*64*2 = 3,932,160 -> 8,001,024
#define OFF_DLTB  ((size_t)8001024)     // 6*5120*1024*2 = 62,914,560 -> 70,915,584
#define OFF_XZ    OFF_DLTB              // xz (42 MB) nested; dead before k_delta writes
#define OFF_BF    ((size_t)70915584)    // 1,966,080 -> 72,881,664
#define OFF_CF    ((size_t)72881664)    // 1,966,080 -> 74,847,744
#define OFF_HLOC  ((size_t)74847744)    // 3,145,728 -> 77,993,472
#define OFF_HIN   ((size_t)77993472)    // 3,145,728 -> 81,139,200
#define OFF_STOT  ((size_t)81139200)    // 196,608  -> 81,335,808
#define OFF_UB    ((size_t)81335808)    // 62,914,560 -> 144,250,368
#define OFF_H     OFF_UB                // ln-out h (10 MB) nested; dead before conv
#define OFF_ZGB   ((size_t)144250368)   // 20,971,520 -> 165,221,888
// total ~165.2 MiB

// ---------------- K0: batched import (f32 params -> ws, bf16 or f32) ----------
struct Ent { const void* s; void* d; int n; int fmt; };
struct Tab { Ent e[32]; };

__global__ __launch_bounds__(256) void k_import(Tab t, int cnt) {
  int id = blockIdx.y;
  if (id >= cnt) return;
  Ent E = t.e[id];
  int stride = gridDim.x * 256;
  const float* s = (const float*)E.s;
  if (E.fmt == 0) {
    ushort_t* dst = (ushort_t*)E.d;
    for (int i = blockIdx.x * 256 + threadIdx.x; i < E.n; i += stride) dst[i] = f2b(s[i]);
  } else {
    float* dst = (float*)E.d;
    for (int i = blockIdx.x * 256 + threadIdx.x; i < E.n; i += stride) dst[i] = s[i];
  }
}

// ---------------- K1: LayerNorm + ReLU -> h (bf16, both batches) --------------
__global__ __launch_bounds__(256) void k_ln(const float* __restrict__ x,
    const float* __restrict__ gam, const float* __restrict__ bet,
    ushort_t* __restrict__ h) {
  int token = blockIdx.x * 4 + (threadIdx.x >> 6);
  int lane = threadIdx.x & 63;
  const float* row = x + (size_t)token * DIMX + lane * 8;
  float4 a0 = *(const float4*)(row);
  float4 a1 = *(const float4*)(row + 4);
  float v[8] = {a0.x,a0.y,a0.z,a0.w,a1.x,a1.y,a1.z,a1.w};
  float s = 0.f, ss = 0.f;
#pragma unroll
  for (int i = 0; i < 8; i++) { s += v[i]; ss += v[i]*v[i]; }
#pragma unroll
  for (int m = 1; m < 64; m <<= 1) { s += __shfl_xor(s, m, 64); ss += __shfl_xor(ss, m, 64); }
  float mean = s * (1.f / DIMX);
  float rs = rsqrtf(ss * (1.f / DIMX) - mean * mean + 1e-5f);
  ushort_t o[8];
#pragma unroll
  for (int i = 0; i < 8; i++) {
    float y = (v[i] - mean) * rs * gam[lane*8+i] + bet[lane*8+i];
    o[i] = f2b(fmaxf(y, 0.f));
  }
  ushort_t* orow = h + (size_t)token * DIMX + lane * 8;
  *(ushort4*)(orow)     = make_ushort4(o[0],o[1],o[2],o[3]);
  *(ushort4*)(orow + 4) = make_ushort4(o[4],o[5],o[6],o[7]);
}

// ---------------- K2: in_proj GEMM (M=10240): xz[bl][e] = h @ W^T -------------
__global__ __launch_bounds__(256) void k_inproj(const ushort_t* __restrict__ hA,
    const ushort_t* __restrict__ Wb, ushort_t* __restrict__ xz) {
  __shared__ ushort_t As[128*32];
  __shared__ ushort_t Bs[128*32];
  const int tid = threadIdx.x;
  const int w = tid >> 6, lane = tid & 63;
  const int wr = w >> 1, wc = w & 1;
  const int m0 = blockIdx.x * 128, n0 = blockIdx.y * 128;
  const int lrow = lane & 15, lko = (lane >> 4) * 8;
  f32x4 acc[4][4];
#pragma unroll
  for (int i = 0; i < 4; i++)
#pragma unroll
    for (int j = 0; j < 4; j++) acc[i][j] = (f32x4){0.f,0.f,0.f,0.f};
  for (int k0 = 0; k0 < DIMX; k0 += 32) {
    __syncthreads();
#pragma unroll
    for (int r = 0; r < 2; r++) {
      int e = r * 256 + tid;
      int row = e >> 2, seg = e & 3;
      glds16(hA + (size_t)(m0 + row) * DIMX + k0 + seg * 8, &As[row*32 + seg*8]);
      glds16(Wb + (size_t)(n0 + row) * DIMX + k0 + seg * 8, &Bs[row*32 + seg*8]);
    }
    __syncthreads();
    bf16x8 aF[4], bF[4];
#pragma unroll
    for (int i = 0; i < 4; i++)
      aF[i] = *(const bf16x8*)&As[(wr*64 + i*16 + lrow)*32 + lko];
#pragma unroll
    for (int j = 0; j < 4; j++)
      bF[j] = *(const bf16x8*)&Bs[(wc*64 + j*16 + lrow)*32 + lko];
#pragma unroll
    for (int i = 0; i < 4; i++)
#pragma unroll
      for (int j = 0; j < 4; j++)
        acc[i][j] = __builtin_amdgcn_mfma_f32_16x16x32_bf16(aF[i], bF[j], acc[i][j], 0, 0, 0);
  }
#pragma unroll
  for (int i = 0; i < 4; i++)
#pragma unroll
    for (int j = 0; j < 4; j++)
#pragma unroll
      for (int r = 0; r < 4; r++) {
        int m = m0 + wr*64 + i*16 + (lane>>4)*4 + r;
        int n = n0 + wc*64 + j*16 + lrow;
        xz[(size_t)m * E2 + n] = f2b(acc[i][j][r]);
      }
}

// ---------------- K4: conv + silu -> uB[ch][d>>4][t][16] (blocked) ------------
__global__ __launch_bounds__(256) void k_conv(const ushort_t* __restrict__ xz,
    const float* __restrict__ cwA, const float* __restrict__ cbA,
    ushort_t* __restrict__ uB) {
  __shared__ ushort_t xs[67][64];
  int ch = blockIdx.z, br = ch >> 1, b = ch & 1;
  int t0 = blockIdx.x * 64, d0 = blockIdx.y * 64;
  int tid = threadIdx.x, col = tid & 63, rg = tid >> 6;
  const float* cw = cwA + (size_t)br * DI * 4;
  const float* cb = cbA + (size_t)br * DI;
#pragma unroll
  for (int i = 0; i < 17; i++) {
    int row = rg + i * 4;
    if (row < 67) {
      int tau = t0 - 3 + row;
      ushort_t val = 0;
      if (tau >= 0) val = xz[((size_t)b * SEQ + pmap(br, tau)) * E2 + d0 + col];
      xs[row][col] = val;
    }
  }
  __syncthreads();
  int d = d0 + col;
  float w0 = cw[d*4+0], w1 = cw[d*4+1], w2 = cw[d*4+2], w3 = cw[d*4+3];
  float bias = cb[d];
  size_t dbbase = ((size_t)(ch * 64 + (d >> 4))) * SEQ;
#pragma unroll
  for (int i = 0; i < 16; i++) {
    int ti = rg + i * 4;
    float a = bias + w0*b2f(xs[ti][col]) + w1*b2f(xs[ti+1][col])
                   + w2*b2f(xs[ti+2][col]) + w3*b2f(xs[ti+3][col]);
    float val = a / (1.f + __expf(-a));
    uB[(dbbase + t0 + ti) * 16 + (col & 15)] = f2b(val);
  }
}

// ---------------- K4b: gate precompute -> zgB[b][d>>4][l][16] (blocked) -------
__global__ __launch_bounds__(256) void k_zg(const ushort_t* __restrict__ xz,
    const float* __restrict__ weff, ushort_t* __restrict__ zgB) {
  int b = blockIdx.z;
  int l0 = blockIdx.x * 64, d0 = blockIdx.y * 64;
  int tid = threadIdx.x, col = tid & 63, rg = tid >> 6;
  int d = d0 + col;
  float wef = weff[d];
  size_t dbbase = ((size_t)(b * 64 + (d >> 4))) * SEQ;
#pragma unroll
  for (int i = 0; i < 16; i++) {
    int l = l0 + rg + i * 4;
    float zr = b2f(xz[((size_t)b * SEQ + l) * E2 + DI + d]);
    float z = zr / (1.f + __expf(-zr));
    zgB[(dbbase + l) * 16 + (col & 15)] = f2b(z * wef);
  }
}

// ---------------- K5: x_dbl GEMM (reads blocked uB): xd[ch][t][64] ------------
__global__ __launch_bounds__(256) void k_xdbl(const ushort_t* __restrict__ uB,
    const ushort_t* __restrict__ xpwA, ushort_t* __restrict__ xdA) {
  __shared__ ushort_t As[64*32];
  __shared__ ushort_t Bs[64*32];
  int ch = blockIdx.y, br = ch >> 1;
  const ushort_t* xpw = xpwA + (size_t)br * KXP * DI;
  ushort_t* xd = xdA + (size_t)ch * SEQ * KXP;
  int t0 = blockIdx.x * 64;
  int tid = threadIdx.x, w = tid >> 6, lane = tid & 63;
  int lrow = lane & 15, lko = (lane >> 4) * 8;
  int row = tid >> 2, seg = tid & 3;
  f32x4 acc[4];
#pragma unroll
  for (int j = 0; j < 4; j++) acc[j] = (f32x4){0.f,0.f,0.f,0.f};
  for (int k0 = 0; k0 < DI; k0 += 32) {
    __syncthreads();
    glds16(uB + (((size_t)(ch*64 + (k0>>4) + (seg>>1)) * SEQ + t0 + row) * 16 + (seg&1)*8),
           &As[row*32 + seg*8]);
    glds16(xpw + (size_t)row * DI + k0 + seg * 8, &Bs[row*32 + seg*8]);
    __syncthreads();
    bf16x8 aF = *(const bf16x8*)&As[(w*16 + lrow)*32 + lko];
#pragma unroll
    for (int j = 0; j < 4; j++) {
      bf16x8 bF = *(const bf16x8*)&Bs[(j*16 + lrow)*32 + lko];
      acc[j] = __builtin_amdgcn_mfma_f32_16x16x32_bf16(aF, bF, acc[j], 0, 0, 0);
    }
  }
#pragma unroll
  for (int j = 0; j < 4; j++)
#pragma unroll
    for (int r = 0; r < 4; r++) {
      int t = t0 + w*16 + (lane>>4)*4 + r;
      xd[(size_t)t * KXP + j*16 + lrow] = f2b(acc[j][r]);
    }
}

// ---------------- K5b: expand xd B/C -> Bf/Cf[ch][n][t] f32 -------------------
__global__ __launch_bounds__(256) void k_bc(const ushort_t* __restrict__ xdA,
    float* __restrict__ Bf, float* __restrict__ Cf) {
  __shared__ float tb[128][34];
  int ch = blockIdx.y, t0 = blockIdx.x * 128;
  int tid = threadIdx.x;
  const ushort_t* xdb = xdA + (size_t)ch * SEQ * KXP;
#pragma unroll
  for (int i = 0; i < 2; i++) {
    int r = (tid >> 2) + i * 64;
    int q = tid & 3;
    const ushort_t* p = xdb + (size_t)(t0 + r) * KXP + 32 + q * 8;
    uint4 v = *(const uint4*)p;
    unsigned int wd[4] = {v.x, v.y, v.z, v.w};
    float* dst = &tb[r][q * 8];
#pragma unroll
    for (int j = 0; j < 4; j++) {
      dst[2*j]   = __uint_as_float(wd[j] << 16);
      dst[2*j+1] = __uint_as_float(wd[j] & 0xFFFF0000u);
    }
  }
  __syncthreads();
  int nn = tid >> 4, sg = tid & 15;
  float ob[8], oc[8];
#pragma unroll
  for (int j = 0; j < 8; j++) {
    ob[j] = tb[sg*8 + j][nn];
    oc[j] = tb[sg*8 + j][16 + nn];
  }
  float* Bp = Bf + ((size_t)ch * NST + nn) * SEQ + t0 + sg * 8;
  float* Cp = Cf + ((size_t)ch * NST + nn) * SEQ + t0 + sg * 8;
  *(float4*)Bp       = make_float4(ob[0],ob[1],ob[2],ob[3]);
  *(float4*)(Bp + 4) = make_float4(ob[4],ob[5],ob[6],ob[7]);
  *(float4*)Cp       = make_float4(oc[0],oc[1],oc[2],oc[3]);
  *(float4*)(Cp + 4) = make_float4(oc[4],oc[5],oc[6],oc[7]);
}

// ---------------- K6: delta GEMM (K=32) + softplus -> dltB (blocked) ----------
// grid (40 t-tiles, 8 d-tiles, 6 ch)
__global__ __launch_bounds__(256) void k_delta(const ushort_t* __restrict__ xdA,
    const ushort_t* __restrict__ dtwb, const float* __restrict__ dtbf,
    ushort_t* __restrict__ dltB) {
  __shared__ ushort_t As[128*32];
  __shared__ ushort_t Bs[128*32];
  int ch = blockIdx.z, br = ch >> 1;
  int t0 = blockIdx.x * 128, d0 = blockIdx.y * 128;
  int tid = threadIdx.x, w = tid >> 6, lane = tid & 63;
  int wr = w >> 1, wc = w & 1;
  int lrow = lane & 15, lko = (lane >> 4) * 8;
  const ushort_t* xdb = xdA + (size_t)ch * SEQ * KXP;
  const ushort_t* dwp = dtwb + (size_t)br * DI * DTR;
#pragma unroll
  for (int r = 0; r < 2; r++) {
    int e = r * 256 + tid;
    int row = e >> 2, seg = e & 3;
    glds16(xdb + (size_t)(t0 + row) * KXP + seg * 8, &As[row*32 + seg*8]);
    glds16(dwp + (size_t)(d0 + row) * DTR + seg * 8, &Bs[row*32 + seg*8]);
  }
  __syncthreads();
  bf16x8 aF[4], bF[4];
#pragma unroll
  for (int i = 0; i < 4; i++)
    aF[i] = *(const bf16x8*)&As[(wr*64 + i*16 + lrow)*32 + lko];
#pragma unroll
  for (int j = 0; j < 4; j++)
    bF[j] = *(const bf16x8*)&Bs[(wc*64 + j*16 + lrow)*32 + lko];
  f32x4 acc[4][4];
#pragma unroll
  for (int i = 0; i < 4; i++)
#pragma unroll
    for (int j = 0; j < 4; j++) {
      acc[i][j] = (f32x4){0.f,0.f,0.f,0.f};
      acc[i][j] = __builtin_amdgcn_mfma_f32_16x16x32_bf16(aF[i], bF[j], acc[i][j], 0, 0, 0);
    }
#pragma unroll
  for (int i = 0; i < 4; i++)
#pragma unroll
    for (int j = 0; j < 4; j++)
#pragma unroll
      for (int r = 0; r < 4; r++) {
        int t = t0 + wr*64 + i*16 + (lane>>4)*4 + r;
        int d = d0 + wc*64 + j*16 + lrow;
        float xv = acc[i][j][r] + dtbf[br * DI + d];
        float sp = (xv > 20.f) ? xv : log1pf(__expf(xv));
        dltB[(((size_t)(ch*64 + (d>>4))) * SEQ + t) * 16 + (d & 15)] = f2b(sp);
      }
}

// ---------------- K7a: segmented local scan (8 ch/wave, merged butterfly) -----
// grid 3072 = ch(bid>>9) x seg((bid>>6)&7) x dblk(bid&63); 128-thread blocks.
__global__ __launch_bounds__(128, 5) void k_scan1(
    const ushort_t* __restrict__ dltB, const ushort_t* __restrict__ uB,
    const ushort_t* __restrict__ zgB, const float* __restrict__ Bf,
    const float* __restrict__ Cf, const float* __restrict__ alf,
    const float* __restrict__ ddf, float* __restrict__ sc,
    float* __restrict__ Hloc, float* __restrict__ Stot) {
  __shared__ __align__(16) float BS[2][16][18];
  __shared__ __align__(16) float CS[2][16][18];
  __shared__ __align__(16) float4 dd4[2][4][17];   // (dltA, duA, dltB, duB)
  __shared__ float2 gS[2][4][17];                  // (gateA, gateB)
  int bid = blockIdx.x;
  int dblk = bid & 63, seg = (bid >> 6) & 7, ch = bid >> 9;
  int br = ch >> 1, b = ch & 1;
  int tid = threadIdx.x, w = tid >> 6, lane = tid & 63, g = lane >> 4, n = lane & 15;
  int da = w * 8 + g;            // channel A position within the 16-block
  int db = da + 4;               // channel B
  int dA = dblk * 16 + da, dB = dblk * 16 + db;
  const float L2E = 1.4426950408889634f;
  float ApA = -__expf(alf[br * (DI*NST) + dA * NST + n]) * L2E;
  float ApB = -__expf(alf[br * (DI*NST) + dB * NST + n]) * L2E;
  float DdA = ddf[br * DI + dA], DdB = ddf[br * DI + dB];
  const ushort_t* dlp = dltB + ((size_t)(ch * 64 + dblk) * SEQ) * 16;
  const ushort_t* uBp = uB   + ((size_t)(ch * 64 + dblk) * SEQ) * 16;
  const ushort_t* zgp = zgB  + ((size_t)(b  * 64 + dblk) * SEQ) * 16;
  const float* Bfp = Bf + ((size_t)ch * NST) * SEQ;
  const float* Cfp = Cf + ((size_t)ch * NST) * SEQ;
  float* srow = sc + (size_t)b * SEQ;
  float hstA = 0.f, hstB = 0.f, SaccA = 0.f, SaccB = 0.f;
  int sn = lane >> 2, sq = lane & 3;
  for (int t0 = seg * SEGL; t0 < seg * SEGL + SEGL; t0 += 16) {
    // stage B/C window (per-wave copy; wave-lockstep, no sync needed)
    *(float4*)&BS[w][sn][sq*4] = *(const float4*)&Bfp[(size_t)sn * SEQ + t0 + sq*4];
    *(float4*)&CS[w][sn][sq*4] = *(const float4*)&Cfp[(size_t)sn * SEQ + t0 + sq*4];
    size_t rowo = (size_t)(t0 + n) * 16;
    float dltA = b2f(dlp[rowo + da]);
    float dltBv = b2f(dlp[rowo + db]);
    float uA = b2f(uBp[rowo + da]);
    float uBv = b2f(uBp[rowo + db]);
    size_t growo = (size_t)pmap(br, t0 + n) * 16;
    float gA = b2f(zgp[growo + da]);
    float gB = b2f(zgp[growo + db]);
    SaccA += dltA; SaccB += dltBv;
    dd4[w][g][n] = make_float4(dltA, dltA * uA, dltBv, dltBv * uBv);
    gS[w][g][n]  = make_float2(gA, gB);
    float dug = fmaf(DdA * uA, gA, DdB * uBv * gB);  // per-timestep skip term
    float Bk[16], Ck[16];
#pragma unroll
    for (int j = 0; j < 4; j++) {
      *(float4*)&Bk[j*4] = *(const float4*)&BS[w][n][j*4];
      *(float4*)&Ck[j*4] = *(const float4*)&CS[w][n][j*4];
    }
    float hC[16];
#pragma unroll
    for (int k = 0; k < 16; k++) {
      float4 v = dd4[w][g][k];
      float2 gg = gS[w][g][k];
      hstA = fmaf(__builtin_amdgcn_exp2f(v.x * ApA), hstA, v.y * Bk[k]);
      hstB = fmaf(__builtin_amdgcn_exp2f(v.z * ApB), hstB, v.w * Bk[k]);
      hC[k] = fmaf(hstA, gg.x, hstB * gg.y) * Ck[k];
    }
    float y = bfly16(hC, n) + dug;     // both channels of this lane, gated
    y += __shfl_xor(y, 16, 64);        // + across g (4 groups = 8 channels)
    y += __shfl_xor(y, 32, 64);
    if (lane < 16) atomicAdd(srow + omap(br, t0 + lane), y);
  }
  Hloc[(((size_t)ch * NSEG + seg) * 1024 + dA) * 16 + n] = hstA;
  Hloc[(((size_t)ch * NSEG + seg) * 1024 + dB) * 16 + n] = hstB;
#pragma unroll
  for (int m = 1; m < 16; m <<= 1) {
    SaccA += __shfl_xor(SaccA, m, 64);
    SaccB += __shfl_xor(SaccB, m, 64);
  }
  if (n == 0) {
    Stot[((size_t)ch * NSEG + seg) * 1024 + dA] = SaccA;
    Stot[((size_t)ch * NSEG + seg) * 1024 + dB] = SaccB;
  }
}

// ---------------- K7b: stitch segment states ----------------------------------
__global__ __launch_bounds__(256) void k_stitch(const float* __restrict__ Stot,
    const float* __restrict__ Hloc, const float* __restrict__ alf,
    float* __restrict__ Hin) {
  int idx = blockIdx.x * 256 + threadIdx.x;     // 98304 = 6*1024*16
  int ch = idx >> 14, rem = idx & 16383, d = rem >> 4, n = rem & 15;
  int br = ch >> 1;
  float A = -__expf(alf[(size_t)br * (DI*NST) + d * NST + n]);
  float h = 0.f;
  for (int s = 0; s < NSEG; s++) {
    size_t base = ((size_t)ch * NSEG + s) * 1024 + d;
    Hin[base * 16 + n] = h;
    h = __expf(A * Stot[base]) * h + Hloc[base * 16 + n];
  }
}

// ---------------- K7c: carry correction (seg-parallel) ------------------------
// grid (1536, 7): x = ch(bid>>8) x cg(bid&255), y = seg-1. Segments are
// independent (carry resets, Hn re-loaded per seg) -> exact reformulation.
// 7x more blocks, 7x less serial depth per block (was 140 barrier-pairs).
__global__ __launch_bounds__(256, 6) void k_scan2(
    const ushort_t* __restrict__ zgB, const ushort_t* __restrict__ dltB,
    const float* __restrict__ Cf, const float* __restrict__ alf,
    const float* __restrict__ Hin, float* __restrict__ sc) {
  __shared__ float red[4][72];
  int ch = blockIdx.x >> 8, cg = blockIdx.x & 255;
  int seg = blockIdx.y + 1;
  int br = ch >> 1, b = ch & 1;
  int tid = threadIdx.x, w = tid >> 6, lane = tid & 63;
  int d = cg * 4 + w;
  const float L2E = 1.4426950408889634f;
  float A2_[16];
#pragma unroll
  for (int nn = 0; nn < 16; nn++)
    A2_[nn] = -__expf(alf[(size_t)br * (DI*NST) + d * NST + nn]) * L2E;
  const ushort_t* dlp = dltB + ((size_t)(ch * 64 + (d >> 4)) * SEQ) * 16;
  const ushort_t* zgp = zgB  + ((size_t)(b  * 64 + (d >> 4)) * SEQ) * 16;
  const float* Cfp = Cf + (size_t)ch * NST * SEQ;
  int dsub = d & 15;
  float* srow = sc + (size_t)b * SEQ;
  float Hn[16];
  const float* hp = Hin + (((size_t)ch * NSEG + seg) * 1024 + d) * 16;
#pragma unroll
  for (int nn = 0; nn < 16; nn++) Hn[nn] = hp[nn];
  float carry = 0.f;
  for (int w0 = seg * SEGL; w0 < seg * SEGL + SEGL; w0 += 64) {
    int t = w0 + lane;
    float dlt = b2f(dlp[(size_t)t * 16 + dsub]);
    float S = dlt;
#pragma unroll
    for (int ofs = 1; ofs < 64; ofs <<= 1) {
      float v = __shfl_up(S, ofs, 64);
      if (lane >= ofs) S += v;
    }
    float tot = __shfl(S, 63, 64);
    S += carry; carry += tot;
    float corr = 0.f;
#pragma unroll
    for (int nn = 0; nn < 16; nn++) {
      float Cn = Cfp[(size_t)nn * SEQ + t];
      corr = fmaf(Cn * Hn[nn], __builtin_amdgcn_exp2f(A2_[nn] * S), corr);
    }
    float gate = b2f(zgp[(size_t)pmap(br, t) * 16 + dsub]);
    float y = corr * gate;
    red[w][lane] = y;
    __syncthreads();
    if (w == 0) {
      float ytot = red[0][lane] + red[1][lane] + red[2][lane] + red[3][lane];
      atomicAdd(srow + omap(br, t), ytot);
    }
    __syncthreads();
  }
}

// ---------------- K8: w_eff[d] = lin_w . out_proj_w[:,d]; zero score_acc ------
__global__ __launch_bounds__(256) void k_weff_init(const ushort_t* __restrict__ opwb,
    const ushort_t* __restrict__ lwb, float* __restrict__ weff, float* __restrict__ sc) {
  int i = blockIdx.x * 256 + threadIdx.x;
  if (i < DI) {
    float s = 0.f;
    for (int o = 0; o < DIMX; o++) s += b2f(lwb[o]) * b2f(opwb[(size_t)o * DI + i]);
    weff[i] = s;
  }
  int j = i - DI;
  if (j >= 0 && j < 2 * SEQ) sc[j] = 0.f;
}

// ---------------- K9: outputs (f32): group interp+sigmoid, individual ---------
__global__ __launch_bounds__(256) void k_out(const float* __restrict__ g0,
    const float* __restrict__ g1, const float* __restrict__ g2,
    const float* __restrict__ sc, const float* __restrict__ lbf,
    float* __restrict__ out) {
  int idx = blockIdx.x * 256 + threadIdx.x;
  if (idx < 3 * SEQ) {
    int j = idx / SEQ, t = idx % SEQ;
    const float* g = (j == 0) ? g0 : (j == 1) ? g1 : g2;
    float pos = t * ((float)(LGS - 1) / (float)(SEQ - 1));
    int i0 = (int)floorf(pos);
    if (i0 < 0) i0 = 0; if (i0 > LGS - 2) i0 = LGS - 2;
    float wt = pos - (float)i0;
    float v = g[i0] * (1.f - wt) + g[i0 + 1] * wt;
    out[idx] = 1.f / (1.f + __expf(-v));
  } else if (idx < 5 * SEQ) {
    float t = sc[idx - 3 * SEQ] + lbf[0];
    out[idx] = 1.f / (1.f + __expf(-t));
  }
}

extern "C" void kernel_launch(void* const* d_in, const int* in_sizes, int n_in,
                              void* d_out, int out_size, void* d_ws, size_t ws_size,
                              hipStream_t stream) {
  char* ws = (char*)d_ws;
  ushort_t* lwb   = (ushort_t*)(ws + OFF_LWB);
  float*    lngf  = (float*)(ws + OFF_LNGF);
  float*    lnbf  = (float*)(ws + OFF_LNBF);
  float*    lbf   = (float*)(ws + OFF_LBF);
  float*    cwf   = (float*)(ws + OFF_CWF);
  float*    cbf   = (float*)(ws + OFF_CBF);
  float*    dtbf  = (float*)(ws + OFF_DTBF);
  float*    alf   = (float*)(ws + OFF_ALF);
  float*    ddf   = (float*)(ws + OFF_DDF);
  float*    weff  = (float*)(ws + OFF_WEFF);
  float*    sc    = (float*)(ws + OFF_SC);
  ushort_t* dtwb  = (ushort_t*)(ws + OFF_DTWB);
  ushort_t* xpwb  = (ushort_t*)(ws + OFF_XPWB);
  ushort_t* opwb  = (ushort_t*)(ws + OFF_OPWB);
  ushort_t* inwb  = (ushort_t*)(ws + OFF_INWB);
  ushort_t* xd    = (ushort_t*)(ws + OFF_XD);
  ushort_t* dltB  = (ushort_t*)(ws + OFF_DLTB);
  ushort_t* xz    = (ushort_t*)(ws + OFF_XZ);
  float*    Bf    = (float*)(ws + OFF_BF);
  float*    Cf    = (float*)(ws + OFF_CF);
  ushort_t* uB    = (ushort_t*)(ws + OFF_UB);
  ushort_t* h     = (ushort_t*)(ws + OFF_H);
  ushort_t* zgB   = (ushort_t*)(ws + OFF_ZGB);
  float*    Hloc  = (float*)(ws + OFF_HLOC);
  float*    Hin   = (float*)(ws + OFF_HIN);
  float*    Stot  = (float*)(ws + OFF_STOT);
  float*    OUT   = (float*)d_out;

  Tab tab;
  int c = 0;
  tab.e[c++] = {d_in[3], inwb, E2 * DIMX, 0};
  tab.e[c++] = {d_in[4], opwb, DIMX * DI, 0};
  tab.e[c++] = {d_in[5], lwb, DIMX, 0};
  for (int br = 0; br < 3; br++) {
    int base = 10 + br * 7;
    tab.e[c++] = {d_in[base + 2], xpwb + (size_t)br * KXP * DI, KXP * DI, 0};
    tab.e[c++] = {d_in[base + 3], dtwb + (size_t)br * DI * DTR, DI * DTR, 0};
  }
  tab.e[c++] = {d_in[1], lngf, DIMX, 1};
  tab.e[c++] = {d_in[2], lnbf, DIMX, 1};
  tab.e[c++] = {d_in[6], lbf, 1, 1};
  for (int br = 0; br < 3; br++) {
    int base = 10 + br * 7;
    tab.e[c++] = {d_in[base + 0], cwf + (size_t)br * DI * 4, DI * 4, 1};
    tab.e[c++] = {d_in[base + 1], cbf + (size_t)br * DI, DI, 1};
    tab.e[c++] = {d_in[base + 4], dtbf + (size_t)br * DI, DI, 1};
    tab.e[c++] = {d_in[base + 5], alf + (size_t)br * DI * NST, DI * NST, 1};
    tab.e[c++] = {d_in[base + 6], ddf + (size_t)br * DI, DI, 1};
  }

  dim3 blk(256);
  k_import<<<dim3(64, c), blk, 0, stream>>>(tab, c);
  k_weff_init<<<44, blk, 0, stream>>>(opwb, lwb, weff, sc);
  k_ln<<<2560, blk, 0, stream>>>((const float*)d_in[0], lngf, lnbf, h);
  k_inproj<<<dim3(80, 16), blk, 0, stream>>>(h, inwb, xz);
  k_conv<<<dim3(80, 16, 6), blk, 0, stream>>>(xz, cwf, cbf, uB);
  k_zg<<<dim3(80, 16, 2), blk, 0, stream>>>(xz, weff, zgB);
  k_xdbl<<<dim3(80, 6), blk, 0, stream>>>(uB, xpwb, xd);
  k_bc<<<dim3(40, 6), blk, 0, stream>>>(xd, Bf, Cf);
  k_delta<<<dim3(40, 8, 6), blk, 0, stream>>>(xd, dtwb, dtbf, dltB);   // xz dead now
  k_scan1<<<3072, dim3(128), 0, stream>>>(dltB, uB, zgB, Bf, Cf, alf, ddf,
                                          sc, Hloc, Stot);
  k_stitch<<<384, blk, 0, stream>>>(Stot, Hloc, alf, Hin);
  k_scan2<<<dim3(1536, NSEG - 1), blk, 0, stream>>>(zgB, dltB, Cf, alf, Hin, sc);
  k_out<<<100, blk, 0, stream>>>((const float*)d_in[7], (const float*)d_in[8],
                                 (const float*)d_in[9], sc, lbf, OUT);
}

// Round 14
// 680.119 us; speedup vs baseline: 1.3614x; 1.1040x over previous
//
#include <hip/hip_runtime.h>
#include <stdint.h>

#define SEQ  5120
#define DIMX 512
#define E2   2048
#define DI   1024
#define NST  16
#define DTR  32
#define KXP  64
#define LGS  2048
#define NSL  5
#define NSEG 8
#define SEGL 640

typedef unsigned short ushort_t;
typedef __attribute__((ext_vector_type(8))) __bf16 bf16x8;
typedef __attribute__((ext_vector_type(4))) float f32x4;

__device__ __forceinline__ float b2f(ushort_t u) {
  union { unsigned int i; float f; } v; v.i = ((unsigned int)u) << 16; return v.f;
}
__device__ __forceinline__ ushort_t f2b(float f) {
  union { float f; unsigned int i; } v; v.f = f;
  unsigned int u = v.i;
  return (ushort_t)((u + 0x7FFFu + ((u >> 16) & 1u)) >> 16);
}

#define AS1 __attribute__((address_space(1)))
#define AS3 __attribute__((address_space(3)))
__device__ __forceinline__ void glds16(const void* g, void* l) {
  __builtin_amdgcn_global_load_lds((const AS1 void*)g, (AS3 void*)l, 16, 0, 0);
}

__device__ __forceinline__ int pmap(int br, int t) {   // scan pos -> data pos
  return (br == 0) ? t : (br == 1) ? (SEQ - 1 - t) : ((t % NSL) * 1024 + t / NSL);
}
__device__ __forceinline__ int omap(int br, int t) {   // scan pos -> output pos
  return (br == 0) ? t : (br == 1) ? (SEQ - 1 - t) : ((t & 1023) * NSL + (t >> 10));
}

// 16-state transpose-reduce butterfly (proven R7 form; DPP variant regressed
// in R11: serial VALU dependency chains cost more than the ds_swizzles).
__device__ __forceinline__ float bfly16(const float* hC, int n) {
  float a8[8], a4[4], a2[2], y;
#pragma unroll
  for (int j = 0; j < 8; j++) {
    float keep = (n & 8) ? hC[j+8] : hC[j];
    float send = (n & 8) ? hC[j]   : hC[j+8];
    a8[j] = keep + __shfl_xor(send, 8, 64);
  }
#pragma unroll
  for (int j = 0; j < 4; j++) {
    float keep = (n & 4) ? a8[j+4] : a8[j];
    float send = (n & 4) ? a8[j]   : a8[j+4];
    a4[j] = keep + __shfl_xor(send, 4, 64);
  }
#pragma unroll
  for (int j = 0; j < 2; j++) {
    float keep = (n & 2) ? a4[j+2] : a4[j];
    float send = (n & 2) ? a4[j]   : a4[j+2];
    a2[j] = keep + __shfl_xor(send, 2, 64);
  }
  {
    float keep = (n & 1) ? a2[1] : a2[0];
    float send = (n & 1) ? a2[0] : a2[1];
    y = keep + __shfl_xor(send, 1, 64);
  }
  return y;
}

// ---------------- workspace layout (bytes) ------------------------------------
#define OFF_LWB   ((size_t)256)
#define OFF_LNGF  ((size_t)1280)
#define OFF_LNBF  ((size_t)3328)
#define OFF_LBF   ((size_t)5376)
#define OFF_CWF   ((size_t)5632)
#define OFF_CBF   ((size_t)54784)
#define OFF_DTBF  ((size_t)67072)
#define OFF_ALF   ((size_t)79360)
#define OFF_DDF   ((size_t)275968)
#define OFF_WEFF  ((size_t)288256)
#define OFF_SC    ((size_t)292352)
#define OFF_DTWB  ((size_t)333312)      // bf16 dt_w, 3*1024*32*2 = 196,608
#define OFF_XPWB  ((size_t)529920)
#define OFF_OPWB  ((size_t)923136)
#define OFF_INWB  ((size_t)1971712)     // ends 4,068,864
#define OFF_XD    ((size_t)4068864)     // 6*5120*64*2 = 3,932,160 -> 8,001,024
#define OFF_DLTB  ((size_t)8001024)     // 6*5120*1024*2 = 62,914,560 -> 70,915,584
#define OFF_XZ    OFF_DLTB              // xz (42 MB) nested; dead before k_delta writes
#define OFF_BF    ((size_t)70915584)    // 1,966,080 -> 72,881,664
#define OFF_CF    ((size_t)72881664)    // 1,966,080 -> 74,847,744
#define OFF_HLOC  ((size_t)74847744)    // 3,145,728 -> 77,993,472
#define OFF_HIN   ((size_t)77993472)    // 3,145,728 -> 81,139,200
#define OFF_STOT  ((size_t)81139200)    // 196,608  -> 81,335,808
#define OFF_UB    ((size_t)81335808)    // 62,914,560 -> 144,250,368
#define OFF_H     OFF_UB                // ln-out h (10 MB) nested; dead before conv
#define OFF_ZGB   ((size_t)144250368)   // 20,971,520 -> 165,221,888
// total ~165.2 MiB

// ---------------- K0: batched import (f32 params -> ws, bf16 or f32) ----------
struct Ent { const void* s; void* d; int n; int fmt; };
struct Tab { Ent e[32]; };

__global__ __launch_bounds__(256) void k_import(Tab t, int cnt) {
  int id = blockIdx.y;
  if (id >= cnt) return;
  Ent E = t.e[id];
  int stride = gridDim.x * 256;
  const float* s = (const float*)E.s;
  if (E.fmt == 0) {
    ushort_t* dst = (ushort_t*)E.d;
    for (int i = blockIdx.x * 256 + threadIdx.x; i < E.n; i += stride) dst[i] = f2b(s[i]);
  } else {
    float* dst = (float*)E.d;
    for (int i = blockIdx.x * 256 + threadIdx.x; i < E.n; i += stride) dst[i] = s[i];
  }
}

// ---------------- K1: LayerNorm + ReLU -> h (bf16, both batches) --------------
__global__ __launch_bounds__(256) void k_ln(const float* __restrict__ x,
    const float* __restrict__ gam, const float* __restrict__ bet,
    ushort_t* __restrict__ h) {
  int token = blockIdx.x * 4 + (threadIdx.x >> 6);
  int lane = threadIdx.x & 63;
  const float* row = x + (size_t)token * DIMX + lane * 8;
  float4 a0 = *(const float4*)(row);
  float4 a1 = *(const float4*)(row + 4);
  float v[8] = {a0.x,a0.y,a0.z,a0.w,a1.x,a1.y,a1.z,a1.w};
  float s = 0.f, ss = 0.f;
#pragma unroll
  for (int i = 0; i < 8; i++) { s += v[i]; ss += v[i]*v[i]; }
#pragma unroll
  for (int m = 1; m < 64; m <<= 1) { s += __shfl_xor(s, m, 64); ss += __shfl_xor(ss, m, 64); }
  float mean = s * (1.f / DIMX);
  float rs = rsqrtf(ss * (1.f / DIMX) - mean * mean + 1e-5f);
  ushort_t o[8];
#pragma unroll
  for (int i = 0; i < 8; i++) {
    float y = (v[i] - mean) * rs * gam[lane*8+i] + bet[lane*8+i];
    o[i] = f2b(fmaxf(y, 0.f));
  }
  ushort_t* orow = h + (size_t)token * DIMX + lane * 8;
  *(ushort4*)(orow)     = make_ushort4(o[0],o[1],o[2],o[3]);
  *(ushort4*)(orow + 4) = make_ushort4(o[4],o[5],o[6],o[7]);
}

// ---------------- K2: in_proj GEMM (M=10240): xz[bl][e] = h @ W^T -------------
__global__ __launch_bounds__(256) void k_inproj(const ushort_t* __restrict__ hA,
    const ushort_t* __restrict__ Wb, ushort_t* __restrict__ xz) {
  __shared__ ushort_t As[128*32];
  __shared__ ushort_t Bs[128*32];
  const int tid = threadIdx.x;
  const int w = tid >> 6, lane = tid & 63;
  const int wr = w >> 1, wc = w & 1;
  const int m0 = blockIdx.x * 128, n0 = blockIdx.y * 128;
  const int lrow = lane & 15, lko = (lane >> 4) * 8;
  f32x4 acc[4][4];
#pragma unroll
  for (int i = 0; i < 4; i++)
#pragma unroll
    for (int j = 0; j < 4; j++) acc[i][j] = (f32x4){0.f,0.f,0.f,0.f};
  for (int k0 = 0; k0 < DIMX; k0 += 32) {
    __syncthreads();
#pragma unroll
    for (int r = 0; r < 2; r++) {
      int e = r * 256 + tid;
      int row = e >> 2, seg = e & 3;
      glds16(hA + (size_t)(m0 + row) * DIMX + k0 + seg * 8, &As[row*32 + seg*8]);
      glds16(Wb + (size_t)(n0 + row) * DIMX + k0 + seg * 8, &Bs[row*32 + seg*8]);
    }
    __syncthreads();
    bf16x8 aF[4], bF[4];
#pragma unroll
    for (int i = 0; i < 4; i++)
      aF[i] = *(const bf16x8*)&As[(wr*64 + i*16 + lrow)*32 + lko];
#pragma unroll
    for (int j = 0; j < 4; j++)
      bF[j] = *(const bf16x8*)&Bs[(wc*64 + j*16 + lrow)*32 + lko];
#pragma unroll
    for (int i = 0; i < 4; i++)
#pragma unroll
      for (int j = 0; j < 4; j++)
        acc[i][j] = __builtin_amdgcn_mfma_f32_16x16x32_bf16(aF[i], bF[j], acc[i][j], 0, 0, 0);
  }
#pragma unroll
  for (int i = 0; i < 4; i++)
#pragma unroll
    for (int j = 0; j < 4; j++)
#pragma unroll
      for (int r = 0; r < 4; r++) {
        int m = m0 + wr*64 + i*16 + (lane>>4)*4 + r;
        int n = n0 + wc*64 + j*16 + lrow;
        xz[(size_t)m * E2 + n] = f2b(acc[i][j][r]);
      }
}

// ---------------- K4: conv + silu -> uB[ch][d>>4][t][16] (blocked) ------------
__global__ __launch_bounds__(256) void k_conv(const ushort_t* __restrict__ xz,
    const float* __restrict__ cwA, const float* __restrict__ cbA,
    ushort_t* __restrict__ uB) {
  __shared__ ushort_t xs[67][64];
  int ch = blockIdx.z, br = ch >> 1, b = ch & 1;
  int t0 = blockIdx.x * 64, d0 = blockIdx.y * 64;
  int tid = threadIdx.x, col = tid & 63, rg = tid >> 6;
  const float* cw = cwA + (size_t)br * DI * 4;
  const float* cb = cbA + (size_t)br * DI;
#pragma unroll
  for (int i = 0; i < 17; i++) {
    int row = rg + i * 4;
    if (row < 67) {
      int tau = t0 - 3 + row;
      ushort_t val = 0;
      if (tau >= 0) val = xz[((size_t)b * SEQ + pmap(br, tau)) * E2 + d0 + col];
      xs[row][col] = val;
    }
  }
  __syncthreads();
  int d = d0 + col;
  float w0 = cw[d*4+0], w1 = cw[d*4+1], w2 = cw[d*4+2], w3 = cw[d*4+3];
  float bias = cb[d];
  size_t dbbase = ((size_t)(ch * 64 + (d >> 4))) * SEQ;
#pragma unroll
  for (int i = 0; i < 16; i++) {
    int ti = rg + i * 4;
    float a = bias + w0*b2f(xs[ti][col]) + w1*b2f(xs[ti+1][col])
                   + w2*b2f(xs[ti+2][col]) + w3*b2f(xs[ti+3][col]);
    float val = a / (1.f + __expf(-a));
    uB[(dbbase + t0 + ti) * 16 + (col & 15)] = f2b(val);
  }
}

// ---------------- K4b: gate precompute -> zgB[b][d>>4][l][16] (blocked) -------
__global__ __launch_bounds__(256) void k_zg(const ushort_t* __restrict__ xz,
    const float* __restrict__ weff, ushort_t* __restrict__ zgB) {
  int b = blockIdx.z;
  int l0 = blockIdx.x * 64, d0 = blockIdx.y * 64;
  int tid = threadIdx.x, col = tid & 63, rg = tid >> 6;
  int d = d0 + col;
  float wef = weff[d];
  size_t dbbase = ((size_t)(b * 64 + (d >> 4))) * SEQ;
#pragma unroll
  for (int i = 0; i < 16; i++) {
    int l = l0 + rg + i * 4;
    float zr = b2f(xz[((size_t)b * SEQ + l) * E2 + DI + d]);
    float z = zr / (1.f + __expf(-zr));
    zgB[(dbbase + l) * 16 + (col & 15)] = f2b(z * wef);
  }
}

// ---------------- K5: x_dbl GEMM (reads blocked uB): xd[ch][t][64] ------------
__global__ __launch_bounds__(256) void k_xdbl(const ushort_t* __restrict__ uB,
    const ushort_t* __restrict__ xpwA, ushort_t* __restrict__ xdA) {
  __shared__ ushort_t As[64*32];
  __shared__ ushort_t Bs[64*32];
  int ch = blockIdx.y, br = ch >> 1;
  const ushort_t* xpw = xpwA + (size_t)br * KXP * DI;
  ushort_t* xd = xdA + (size_t)ch * SEQ * KXP;
  int t0 = blockIdx.x * 64;
  int tid = threadIdx.x, w = tid >> 6, lane = tid & 63;
  int lrow = lane & 15, lko = (lane >> 4) * 8;
  int row = tid >> 2, seg = tid & 3;
  f32x4 acc[4];
#pragma unroll
  for (int j = 0; j < 4; j++) acc[j] = (f32x4){0.f,0.f,0.f,0.f};
  for (int k0 = 0; k0 < DI; k0 += 32) {
    __syncthreads();
    glds16(uB + (((size_t)(ch*64 + (k0>>4) + (seg>>1)) * SEQ + t0 + row) * 16 + (seg&1)*8),
           &As[row*32 + seg*8]);
    glds16(xpw + (size_t)row * DI + k0 + seg * 8, &Bs[row*32 + seg*8]);
    __syncthreads();
    bf16x8 aF = *(const bf16x8*)&As[(w*16 + lrow)*32 + lko];
#pragma unroll
    for (int j = 0; j < 4; j++) {
      bf16x8 bF = *(const bf16x8*)&Bs[(j*16 + lrow)*32 + lko];
      acc[j] = __builtin_amdgcn_mfma_f32_16x16x32_bf16(aF, bF, acc[j], 0, 0, 0);
    }
  }
#pragma unroll
  for (int j = 0; j < 4; j++)
#pragma unroll
    for (int r = 0; r < 4; r++) {
      int t = t0 + w*16 + (lane>>4)*4 + r;
      xd[(size_t)t * KXP + j*16 + lrow] = f2b(acc[j][r]);
    }
}

// ---------------- K5b: expand xd B/C -> Bf/Cf[ch][n][t] f32 -------------------
__global__ __launch_bounds__(256) void k_bc(const ushort_t* __restrict__ xdA,
    float* __restrict__ Bf, float* __restrict__ Cf) {
  __shared__ float tb[128][34];
  int ch = blockIdx.y, t0 = blockIdx.x * 128;
  int tid = threadIdx.x;
  const ushort_t* xdb = xdA + (size_t)ch * SEQ * KXP;
#pragma unroll
  for (int i = 0; i < 2; i++) {
    int r = (tid >> 2) + i * 64;
    int q = tid & 3;
    const ushort_t* p = xdb + (size_t)(t0 + r) * KXP + 32 + q * 8;
    uint4 v = *(const uint4*)p;
    unsigned int wd[4] = {v.x, v.y, v.z, v.w};
    float* dst = &tb[r][q * 8];
#pragma unroll
    for (int j = 0; j < 4; j++) {
      dst[2*j]   = __uint_as_float(wd[j] << 16);
      dst[2*j+1] = __uint_as_float(wd[j] & 0xFFFF0000u);
    }
  }
  __syncthreads();
  int nn = tid >> 4, sg = tid & 15;
  float ob[8], oc[8];
#pragma unroll
  for (int j = 0; j < 8; j++) {
    ob[j] = tb[sg*8 + j][nn];
    oc[j] = tb[sg*8 + j][16 + nn];
  }
  float* Bp = Bf + ((size_t)ch * NST + nn) * SEQ + t0 + sg * 8;
  float* Cp = Cf + ((size_t)ch * NST + nn) * SEQ + t0 + sg * 8;
  *(float4*)Bp       = make_float4(ob[0],ob[1],ob[2],ob[3]);
  *(float4*)(Bp + 4) = make_float4(ob[4],ob[5],ob[6],ob[7]);
  *(float4*)Cp       = make_float4(oc[0],oc[1],oc[2],oc[3]);
  *(float4*)(Cp + 4) = make_float4(oc[4],oc[5],oc[6],oc[7]);
}

// ---------------- K6: delta GEMM (K=32) + softplus -> dltB (blocked) ----------
// grid (40 t-tiles, 8 d-tiles, 6 ch)
__global__ __launch_bounds__(256) void k_delta(const ushort_t* __restrict__ xdA,
    const ushort_t* __restrict__ dtwb, const float* __restrict__ dtbf,
    ushort_t* __restrict__ dltB) {
  __shared__ ushort_t As[128*32];
  __shared__ ushort_t Bs[128*32];
  int ch = blockIdx.z, br = ch >> 1;
  int t0 = blockIdx.x * 128, d0 = blockIdx.y * 128;
  int tid = threadIdx.x, w = tid >> 6, lane = tid & 63;
  int wr = w >> 1, wc = w & 1;
  int lrow = lane & 15, lko = (lane >> 4) * 8;
  const ushort_t* xdb = xdA + (size_t)ch * SEQ * KXP;
  const ushort_t* dwp = dtwb + (size_t)br * DI * DTR;
#pragma unroll
  for (int r = 0; r < 2; r++) {
    int e = r * 256 + tid;
    int row = e >> 2, seg = e & 3;
    glds16(xdb + (size_t)(t0 + row) * KXP + seg * 8, &As[row*32 + seg*8]);
    glds16(dwp + (size_t)(d0 + row) * DTR + seg * 8, &Bs[row*32 + seg*8]);
  }
  __syncthreads();
  bf16x8 aF[4], bF[4];
#pragma unroll
  for (int i = 0; i < 4; i++)
    aF[i] = *(const bf16x8*)&As[(wr*64 + i*16 + lrow)*32 + lko];
#pragma unroll
  for (int j = 0; j < 4; j++)
    bF[j] = *(const bf16x8*)&Bs[(wc*64 + j*16 + lrow)*32 + lko];
  f32x4 acc[4][4];
#pragma unroll
  for (int i = 0; i < 4; i++)
#pragma unroll
    for (int j = 0; j < 4; j++) {
      acc[i][j] = (f32x4){0.f,0.f,0.f,0.f};
      acc[i][j] = __builtin_amdgcn_mfma_f32_16x16x32_bf16(aF[i], bF[j], acc[i][j], 0, 0, 0);
    }
#pragma unroll
  for (int i = 0; i < 4; i++)
#pragma unroll
    for (int j = 0; j < 4; j++)
#pragma unroll
      for (int r = 0; r < 4; r++) {
        int t = t0 + wr*64 + i*16 + (lane>>4)*4 + r;
        int d = d0 + wc*64 + j*16 + lrow;
        float xv = acc[i][j][r] + dtbf[br * DI + d];
        float sp = (xv > 20.f) ? xv : log1pf(__expf(xv));
        dltB[(((size_t)(ch*64 + (d>>4))) * SEQ + t) * 16 + (d & 15)] = f2b(sp);
      }
}

// ---------------- K7a: segmented local scan (8 ch/wave, merged butterfly) -----
// grid 3072 = ch(bid>>9) x seg((bid>>6)&7) x dblk(bid&63); 128-thread blocks.
__global__ __launch_bounds__(128, 5) void k_scan1(
    const ushort_t* __restrict__ dltB, const ushort_t* __restrict__ uB,
    const ushort_t* __restrict__ zgB, const float* __restrict__ Bf,
    const float* __restrict__ Cf, const float* __restrict__ alf,
    const float* __restrict__ ddf, float* __restrict__ sc,
    float* __restrict__ Hloc, float* __restrict__ Stot) {
  __shared__ __align__(16) float BS[2][16][18];
  __shared__ __align__(16) float CS[2][16][18];
  __shared__ __align__(16) float4 dd4[2][4][17];   // (dltA, duA, dltB, duB)
  __shared__ float2 gS[2][4][17];                  // (gateA, gateB)
  int bid = blockIdx.x;
  int dblk = bid & 63, seg = (bid >> 6) & 7, ch = bid >> 9;
  int br = ch >> 1, b = ch & 1;
  int tid = threadIdx.x, w = tid >> 6, lane = tid & 63, g = lane >> 4, n = lane & 15;
  int da = w * 8 + g;            // channel A position within the 16-block
  int db = da + 4;               // channel B
  int dA = dblk * 16 + da, dB = dblk * 16 + db;
  const float L2E = 1.4426950408889634f;
  float ApA = -__expf(alf[br * (DI*NST) + dA * NST + n]) * L2E;
  float ApB = -__expf(alf[br * (DI*NST) + dB * NST + n]) * L2E;
  float DdA = ddf[br * DI + dA], DdB = ddf[br * DI + dB];
  const ushort_t* dlp = dltB + ((size_t)(ch * 64 + dblk) * SEQ) * 16;
  const ushort_t* uBp = uB   + ((size_t)(ch * 64 + dblk) * SEQ) * 16;
  const ushort_t* zgp = zgB  + ((size_t)(b  * 64 + dblk) * SEQ) * 16;
  const float* Bfp = Bf + ((size_t)ch * NST) * SEQ;
  const float* Cfp = Cf + ((size_t)ch * NST) * SEQ;
  float* srow = sc + (size_t)b * SEQ;
  float hstA = 0.f, hstB = 0.f, SaccA = 0.f, SaccB = 0.f;
  int sn = lane >> 2, sq = lane & 3;
  for (int t0 = seg * SEGL; t0 < seg * SEGL + SEGL; t0 += 16) {
    // stage B/C window (per-wave copy; wave-lockstep, no sync needed)
    *(float4*)&BS[w][sn][sq*4] = *(const float4*)&Bfp[(size_t)sn * SEQ + t0 + sq*4];
    *(float4*)&CS[w][sn][sq*4] = *(const float4*)&Cfp[(size_t)sn * SEQ + t0 + sq*4];
    size_t rowo = (size_t)(t0 + n) * 16;
    float dltA = b2f(dlp[rowo + da]);
    float dltBv = b2f(dlp[rowo + db]);
    float uA = b2f(uBp[rowo + da]);
    float uBv = b2f(uBp[rowo + db]);
    size_t growo = (size_t)pmap(br, t0 + n) * 16;
    float gA = b2f(zgp[growo + da]);
    float gB = b2f(zgp[growo + db]);
    SaccA += dltA; SaccB += dltBv;
    dd4[w][g][n] = make_float4(dltA, dltA * uA, dltBv, dltBv * uBv);
    gS[w][g][n]  = make_float2(gA, gB);
    float dug = fmaf(DdA * uA, gA, DdB * uBv * gB);  // per-timestep skip term
    float Bk[16], Ck[16];
#pragma unroll
    for (int j = 0; j < 4; j++) {
      *(float4*)&Bk[j*4] = *(const float4*)&BS[w][n][j*4];
      *(float4*)&Ck[j*4] = *(const float4*)&CS[w][n][j*4];
    }
    float hC[16];
#pragma unroll
    for (int k = 0; k < 16; k++) {
      float4 v = dd4[w][g][k];
      float2 gg = gS[w][g][k];
      hstA = fmaf(__builtin_amdgcn_exp2f(v.x * ApA), hstA, v.y * Bk[k]);
      hstB = fmaf(__builtin_amdgcn_exp2f(v.z * ApB), hstB, v.w * Bk[k]);
      hC[k] = fmaf(hstA, gg.x, hstB * gg.y) * Ck[k];
    }
    float y = bfly16(hC, n) + dug;     // both channels of this lane, gated
    y += __shfl_xor(y, 16, 64);        // + across g (4 groups = 8 channels)
    y += __shfl_xor(y, 32, 64);
    if (lane < 16) atomicAdd(srow + omap(br, t0 + lane), y);
  }
  Hloc[(((size_t)ch * NSEG + seg) * 1024 + dA) * 16 + n] = hstA;
  Hloc[(((size_t)ch * NSEG + seg) * 1024 + dB) * 16 + n] = hstB;
#pragma unroll
  for (int m = 1; m < 16; m <<= 1) {
    SaccA += __shfl_xor(SaccA, m, 64);
    SaccB += __shfl_xor(SaccB, m, 64);
  }
  if (n == 0) {
    Stot[((size_t)ch * NSEG + seg) * 1024 + dA] = SaccA;
    Stot[((size_t)ch * NSEG + seg) * 1024 + dB] = SaccB;
  }
}

// ---------------- K7b: stitch segment states ----------------------------------
__global__ __launch_bounds__(256) void k_stitch(const float* __restrict__ Stot,
    const float* __restrict__ Hloc, const float* __restrict__ alf,
    float* __restrict__ Hin) {
  int idx = blockIdx.x * 256 + threadIdx.x;     // 98304 = 6*1024*16
  int ch = idx >> 14, rem = idx & 16383, d = rem >> 4, n = rem & 15;
  int br = ch >> 1;
  float A = -__expf(alf[(size_t)br * (DI*NST) + d * NST + n]);
  float h = 0.f;
  for (int s = 0; s < NSEG; s++) {
    size_t base = ((size_t)ch * NSEG + s) * 1024 + d;
    Hin[base * 16 + n] = h;
    h = __expf(A * Stot[base]) * h + Hloc[base * 16 + n];
  }
}

// ---------------- K7c: carry correction (16-d group blocks, uint2 loads) ------
// grid (384, 7): x = ch*64 + grp, y = seg-1. Each wave handles 4 CONSECUTIVE
// d; in-row offset is dsub4 = w*4 (dlp/zgp bases already include grp!).
// R13 bug: used global dbase in the row index (double offset) -> wrong data.
__global__ __launch_bounds__(256, 2) void k_scan2(
    const ushort_t* __restrict__ zgB, const ushort_t* __restrict__ dltB,
    const float* __restrict__ Cf, const float* __restrict__ alf,
    const float* __restrict__ Hin, float* __restrict__ sc) {
  __shared__ float red[4][72];
  int ch = blockIdx.x >> 6, grp = blockIdx.x & 63;
  int seg = blockIdx.y + 1;
  int br = ch >> 1, b = ch & 1;
  int tid = threadIdx.x, w = tid >> 6, lane = tid & 63;
  int dsub4 = w * 4;                 // in-row offset (d & 15)
  int dbase = grp * 16 + dsub4;      // global d of this wave's first channel
  const float L2E = 1.4426950408889634f;
  float A2[4][16], Hn[4][16];
#pragma unroll
  for (int q = 0; q < 4; q++) {
    int d = dbase + q;
#pragma unroll
    for (int nn = 0; nn < 16; nn++)
      A2[q][nn] = -__expf(alf[(size_t)br * (DI*NST) + d * NST + nn]) * L2E;
    const float* hp = Hin + (((size_t)ch * NSEG + seg) * 1024 + d) * 16;
#pragma unroll
    for (int nn = 0; nn < 16; nn++) Hn[q][nn] = hp[nn];
  }
  const ushort_t* dlp = dltB + ((size_t)(ch * 64 + grp) * SEQ) * 16;
  const ushort_t* zgp = zgB  + ((size_t)(b  * 64 + grp) * SEQ) * 16;
  const float* Cfp = Cf + (size_t)ch * NST * SEQ;
  float* srow = sc + (size_t)b * SEQ;
  float c0 = 0.f, c1 = 0.f, c2 = 0.f, c3 = 0.f;   // per-d carries
  for (int w0 = seg * SEGL; w0 < seg * SEGL + SEGL; w0 += 64) {
    int t = w0 + lane;
    uint2 dv = *(const uint2*)(dlp + (size_t)t * 16 + dsub4);
    float S0 = b2f((ushort_t)(dv.x & 0xFFFF));
    float S1 = b2f((ushort_t)(dv.x >> 16));
    float S2 = b2f((ushort_t)(dv.y & 0xFFFF));
    float S3 = b2f((ushort_t)(dv.y >> 16));
#pragma unroll
    for (int ofs = 1; ofs < 64; ofs <<= 1) {
      float v0 = __shfl_up(S0, ofs, 64);
      float v1 = __shfl_up(S1, ofs, 64);
      float v2 = __shfl_up(S2, ofs, 64);
      float v3 = __shfl_up(S3, ofs, 64);
      if (lane >= ofs) { S0 += v0; S1 += v1; S2 += v2; S3 += v3; }
    }
    float t0_ = __shfl(S0, 63, 64), t1_ = __shfl(S1, 63, 64);
    float t2_ = __shfl(S2, 63, 64), t3_ = __shfl(S3, 63, 64);
    S0 += c0; c0 += t0_;
    S1 += c1; c1 += t1_;
    S2 += c2; c2 += t2_;
    S3 += c3; c3 += t3_;
    float r0 = 0.f, r1 = 0.f, r2 = 0.f, r3 = 0.f;
#pragma unroll
    for (int nn = 0; nn < 16; nn++) {
      float Cn = Cfp[(size_t)nn * SEQ + t];
      r0 = fmaf(Cn * Hn[0][nn], __builtin_amdgcn_exp2f(A2[0][nn] * S0), r0);
      r1 = fmaf(Cn * Hn[1][nn], __builtin_amdgcn_exp2f(A2[1][nn] * S1), r1);
      r2 = fmaf(Cn * Hn[2][nn], __builtin_amdgcn_exp2f(A2[2][nn] * S2), r2);
      r3 = fmaf(Cn * Hn[3][nn], __builtin_amdgcn_exp2f(A2[3][nn] * S3), r3);
    }
    uint2 zv = *(const uint2*)(zgp + (size_t)pmap(br, t) * 16 + dsub4);
    float g0 = b2f((ushort_t)(zv.x & 0xFFFF));
    float g1 = b2f((ushort_t)(zv.x >> 16));
    float g2 = b2f((ushort_t)(zv.y & 0xFFFF));
    float g3 = b2f((ushort_t)(zv.y >> 16));
    float y = fmaf(r0, g0, fmaf(r1, g1, fmaf(r2, g2, r3 * g3)));
    red[w][lane] = y;
    __syncthreads();
    if (w == 0) {
      float ytot = red[0][lane] + red[1][lane] + red[2][lane] + red[3][lane];
      atomicAdd(srow + omap(br, t), ytot);
    }
    __syncthreads();
  }
}

// ---------------- K8: w_eff[d] = lin_w . out_proj_w[:,d]; zero score_acc ------
__global__ __launch_bounds__(256) void k_weff_init(const ushort_t* __restrict__ opwb,
    const ushort_t* __restrict__ lwb, float* __restrict__ weff, float* __restrict__ sc) {
  int i = blockIdx.x * 256 + threadIdx.x;
  if (i < DI) {
    float s = 0.f;
    for (int o = 0; o < DIMX; o++) s += b2f(lwb[o]) * b2f(opwb[(size_t)o * DI + i]);
    weff[i] = s;
  }
  int j = i - DI;
  if (j >= 0 && j < 2 * SEQ) sc[j] = 0.f;
}

// ---------------- K9: outputs (f32): group interp+sigmoid, individual ---------
__global__ __launch_bounds__(256) void k_out(const float* __restrict__ g0,
    const float* __restrict__ g1, const float* __restrict__ g2,
    const float* __restrict__ sc, const float* __restrict__ lbf,
    float* __restrict__ out) {
  int idx = blockIdx.x * 256 + threadIdx.x;
  if (idx < 3 * SEQ) {
    int j = idx / SEQ, t = idx % SEQ;
    const float* g = (j == 0) ? g0 : (j == 1) ? g1 : g2;
    float pos = t * ((float)(LGS - 1) / (float)(SEQ - 1));
    int i0 = (int)floorf(pos);
    if (i0 < 0) i0 = 0; if (i0 > LGS - 2) i0 = LGS - 2;
    float wt = pos - (float)i0;
    float v = g[i0] * (1.f - wt) + g[i0 + 1] * wt;
    out[idx] = 1.f / (1.f + __expf(-v));
  } else if (idx < 5 * SEQ) {
    float t = sc[idx - 3 * SEQ] + lbf[0];
    out[idx] = 1.f / (1.f + __expf(-t));
  }
}

extern "C" void kernel_launch(void* const* d_in, const int* in_sizes, int n_in,
                              void* d_out, int out_size, void* d_ws, size_t ws_size,
                              hipStream_t stream) {
  char* ws = (char*)d_ws;
  ushort_t* lwb   = (ushort_t*)(ws + OFF_LWB);
  float*    lngf  = (float*)(ws + OFF_LNGF);
  float*    lnbf  = (float*)(ws + OFF_LNBF);
  float*    lbf   = (float*)(ws + OFF_LBF);
  float*    cwf   = (float*)(ws + OFF_CWF);
  float*    cbf   = (float*)(ws + OFF_CBF);
  float*    dtbf  = (float*)(ws + OFF_DTBF);
  float*    alf   = (float*)(ws + OFF_ALF);
  float*    ddf   = (float*)(ws + OFF_DDF);
  float*    weff  = (float*)(ws + OFF_WEFF);
  float*    sc    = (float*)(ws + OFF_SC);
  ushort_t* dtwb  = (ushort_t*)(ws + OFF_DTWB);
  ushort_t* xpwb  = (ushort_t*)(ws + OFF_XPWB);
  ushort_t* opwb  = (ushort_t*)(ws + OFF_OPWB);
  ushort_t* inwb  = (ushort_t*)(ws + OFF_INWB);
  ushort_t* xd    = (ushort_t*)(ws + OFF_XD);
  ushort_t* dltB  = (ushort_t*)(ws + OFF_DLTB);
  ushort_t* xz    = (ushort_t*)(ws + OFF_XZ);
  float*    Bf    = (float*)(ws + OFF_BF);
  float*    Cf    = (float*)(ws + OFF_CF);
  ushort_t* uB    = (ushort_t*)(ws + OFF_UB);
  ushort_t* h     = (ushort_t*)(ws + OFF_H);
  ushort_t* zgB   = (ushort_t*)(ws + OFF_ZGB);
  float*    Hloc  = (float*)(ws + OFF_HLOC);
  float*    Hin   = (float*)(ws + OFF_HIN);
  float*    Stot  = (float*)(ws + OFF_STOT);
  float*    OUT   = (float*)d_out;

  Tab tab;
  int c = 0;
  tab.e[c++] = {d_in[3], inwb, E2 * DIMX, 0};
  tab.e[c++] = {d_in[4], opwb, DIMX * DI, 0};
  tab.e[c++] = {d_in[5], lwb, DIMX, 0};
  for (int br = 0; br < 3; br++) {
    int base = 10 + br * 7;
    tab.e[c++] = {d_in[base + 2], xpwb + (size_t)br * KXP * DI, KXP * DI, 0};
    tab.e[c++] = {d_in[base + 3], dtwb + (size_t)br * DI * DTR, DI * DTR, 0};
  }
  tab.e[c++] = {d_in[1], lngf, DIMX, 1};
  tab.e[c++] = {d_in[2], lnbf, DIMX, 1};
  tab.e[c++] = {d_in[6], lbf, 1, 1};
  for (int br = 0; br < 3; br++) {
    int base = 10 + br * 7;
    tab.e[c++] = {d_in[base + 0], cwf + (size_t)br * DI * 4, DI * 4, 1};
    tab.e[c++] = {d_in[base + 1], cbf + (size_t)br * DI, DI, 1};
    tab.e[c++] = {d_in[base + 4], dtbf + (size_t)br * DI, DI, 1};
    tab.e[c++] = {d_in[base + 5], alf + (size_t)br * DI * NST, DI * NST, 1};
    tab.e[c++] = {d_in[base + 6], ddf + (size_t)br * DI, DI, 1};
  }

  dim3 blk(256);
  k_import<<<dim3(64, c), blk, 0, stream>>>(tab, c);
  k_weff_init<<<44, blk, 0, stream>>>(opwb, lwb, weff, sc);
  k_ln<<<2560, blk, 0, stream>>>((const float*)d_in[0], lngf, lnbf, h);
  k_inproj<<<dim3(80, 16), blk, 0, stream>>>(h, inwb, xz);
  k_conv<<<dim3(80, 16, 6), blk, 0, stream>>>(xz, cwf, cbf, uB);
  k_zg<<<dim3(80, 16, 2), blk, 0, stream>>>(xz, weff, zgB);
  k_xdbl<<<dim3(80, 6), blk, 0, stream>>>(uB, xpwb, xd);
  k_bc<<<dim3(40, 6), blk, 0, stream>>>(xd, Bf, Cf);
  k_delta<<<dim3(40, 8, 6), blk, 0, stream>>>(xd, dtwb, dtbf, dltB);   // xz dead now
  k_scan1<<<3072, dim3(128), 0, stream>>>(dltB, uB, zgB, Bf, Cf, alf, ddf,
                                          sc, Hloc, Stot);
  k_stitch<<<384, blk, 0, stream>>>(Stot, Hloc, alf, Hin);
  k_scan2<<<dim3(384, NSEG - 1), blk, 0, stream>>>(zgB, dltB, Cf, alf, Hin, sc);
  k_out<<<100, blk, 0, stream>>>((const float*)d_in[7], (const float*)d_in[8],
                                 (const float*)d_in[9], sc, lbf, OUT);
}

// Round 16
// 646.148 us; speedup vs baseline: 1.4330x; 1.0526x over previous
//
#include <hip/hip_runtime.h>
#include <stdint.h>

#define SEQ  5120
#define DIMX 512
#define E2   2048
#define DI   1024
#define NST  16
#define DTR  32
#define KXP  64
#define LGS  2048
#define NSL  5
#define NSEG 8
#define SEGL 640

typedef unsigned short ushort_t;
typedef __attribute__((ext_vector_type(8))) __bf16 bf16x8;
typedef __attribute__((ext_vector_type(4))) float f32x4;

__device__ __forceinline__ float b2f(ushort_t u) {
  union { unsigned int i; float f; } v; v.i = ((unsigned int)u) << 16; return v.f;
}
__device__ __forceinline__ ushort_t f2b(float f) {
  union { float f; unsigned int i; } v; v.f = f;
  unsigned int u = v.i;
  return (ushort_t)((u + 0x7FFFu + ((u >> 16) & 1u)) >> 16);
}

#define AS1 __attribute__((address_space(1)))
#define AS3 __attribute__((address_space(3)))
__device__ __forceinline__ void glds16(const void* g, void* l) {
  __builtin_amdgcn_global_load_lds((const AS1 void*)g, (AS3 void*)l, 16, 0, 0);
}

__device__ __forceinline__ int pmap(int br, int t) {   // scan pos -> data pos
  return (br == 0) ? t : (br == 1) ? (SEQ - 1 - t) : ((t % NSL) * 1024 + t / NSL);
}
__device__ __forceinline__ int omap(int br, int t) {   // scan pos -> output pos
  return (br == 0) ? t : (br == 1) ? (SEQ - 1 - t) : ((t & 1023) * NSL + (t >> 10));
}

// 16-state transpose-reduce butterfly (proven R7 form).
__device__ __forceinline__ float bfly16(const float* hC, int n) {
  float a8[8], a4[4], a2[2], y;
#pragma unroll
  for (int j = 0; j < 8; j++) {
    float keep = (n & 8) ? hC[j+8] : hC[j];
    float send = (n & 8) ? hC[j]   : hC[j+8];
    a8[j] = keep + __shfl_xor(send, 8, 64);
  }
#pragma unroll
  for (int j = 0; j < 4; j++) {
    float keep = (n & 4) ? a8[j+4] : a8[j];
    float send = (n & 4) ? a8[j]   : a8[j+4];
    a4[j] = keep + __shfl_xor(send, 4, 64);
  }
#pragma unroll
  for (int j = 0; j < 2; j++) {
    float keep = (n & 2) ? a4[j+2] : a4[j];
    float send = (n & 2) ? a4[j]   : a4[j+2];
    a2[j] = keep + __shfl_xor(send, 2, 64);
  }
  {
    float keep = (n & 1) ? a2[1] : a2[0];
    float send = (n & 1) ? a2[0] : a2[1];
    y = keep + __shfl_xor(send, 1, 64);
  }
  return y;
}

// ---------------- workspace layout (bytes) ------------------------------------
#define OFF_LWB   ((size_t)256)
#define OFF_LNGF  ((size_t)1280)
#define OFF_LNBF  ((size_t)3328)
#define OFF_LBF   ((size_t)5376)
#define OFF_CWF   ((size_t)5632)
#define OFF_CBF   ((size_t)54784)
#define OFF_DTBF  ((size_t)67072)
#define OFF_ALF   ((size_t)79360)
#define OFF_DDF   ((size_t)275968)
#define OFF_WEFF  ((size_t)288256)
#define OFF_SC    ((size_t)292352)
#define OFF_DTWB  ((size_t)333312)      // bf16 dt_w, 3*1024*32*2 = 196,608
#define OFF_XPWB  ((size_t)529920)
#define OFF_OPWB  ((size_t)923136)
#define OFF_INWB  ((size_t)1971712)     // ends 4,068,864
#define OFF_XD    ((size_t)4068864)     // 6*5120*64*2 = 3,932,160 -> 8,001,024
#define OFF_DLTB  ((size_t)8001024)     // 6*5120*1024*2 = 62,914,560 -> 70,915,584
#define OFF_XZ    OFF_DLTB              // xz (42 MB) nested; dead before k_delta writes
#define OFF_BF    ((size_t)70915584)    // 1,966,080 -> 72,881,664
#define OFF_CF    ((size_t)72881664)    // 1,966,080 -> 74,847,744
#define OFF_HLOC  ((size_t)74847744)    // 3,145,728 -> 77,993,472
#define OFF_HIN   ((size_t)77993472)    // 3,145,728 -> 81,139,200
#define OFF_STOT  ((size_t)81139200)    // 196,608  -> 81,335,808
#define OFF_UB    ((size_t)81335808)    // 62,914,560 -> 144,250,368
#define OFF_H     OFF_UB                // ln-out h (10 MB) nested; dead before conv
#define OFF_ZGB   ((size_t)144250368)   // 20,971,520 -> 165,221,888
// total ~165.2 MiB

// ---------------- K0: batched import (f32 params -> ws, bf16 or f32) ----------
struct Ent { const void* s; void* d; int n; int fmt; };
struct Tab { Ent e[32]; };

__global__ __launch_bounds__(256) void k_import(Tab t, int cnt) {
  int id = blockIdx.y;
  if (id >= cnt) return;
  Ent E = t.e[id];
  int stride = gridDim.x * 256;
  const float* s = (const float*)E.s;
  if (E.fmt == 0) {
    ushort_t* dst = (ushort_t*)E.d;
    for (int i = blockIdx.x * 256 + threadIdx.x; i < E.n; i += stride) dst[i] = f2b(s[i]);
  } else {
    float* dst = (float*)E.d;
    for (int i = blockIdx.x * 256 + threadIdx.x; i < E.n; i += stride) dst[i] = s[i];
  }
}

// ---------------- K1: LayerNorm + ReLU -> h (bf16, both batches) --------------
__global__ __launch_bounds__(256) void k_ln(const float* __restrict__ x,
    const float* __restrict__ gam, const float* __restrict__ bet,
    ushort_t* __restrict__ h) {
  int token = blockIdx.x * 4 + (threadIdx.x >> 6);
  int lane = threadIdx.x & 63;
  const float* row = x + (size_t)token * DIMX + lane * 8;
  float4 a0 = *(const float4*)(row);
  float4 a1 = *(const float4*)(row + 4);
  float v[8] = {a0.x,a0.y,a0.z,a0.w,a1.x,a1.y,a1.z,a1.w};
  float s = 0.f, ss = 0.f;
#pragma unroll
  for (int i = 0; i < 8; i++) { s += v[i]; ss += v[i]*v[i]; }
#pragma unroll
  for (int m = 1; m < 64; m <<= 1) { s += __shfl_xor(s, m, 64); ss += __shfl_xor(ss, m, 64); }
  float mean = s * (1.f / DIMX);
  float rs = rsqrtf(ss * (1.f / DIMX) - mean * mean + 1e-5f);
  ushort_t o[8];
#pragma unroll
  for (int i = 0; i < 8; i++) {
    float y = (v[i] - mean) * rs * gam[lane*8+i] + bet[lane*8+i];
    o[i] = f2b(fmaxf(y, 0.f));
  }
  ushort_t* orow = h + (size_t)token * DIMX + lane * 8;
  *(ushort4*)(orow)     = make_ushort4(o[0],o[1],o[2],o[3]);
  *(ushort4*)(orow + 4) = make_ushort4(o[4],o[5],o[6],o[7]);
}

// ---------------- K2: in_proj GEMM (M=10240): xz[bl][e] = h @ W^T -------------
__global__ __launch_bounds__(256) void k_inproj(const ushort_t* __restrict__ hA,
    const ushort_t* __restrict__ Wb, ushort_t* __restrict__ xz) {
  __shared__ ushort_t As[128*32];
  __shared__ ushort_t Bs[128*32];
  const int tid = threadIdx.x;
  const int w = tid >> 6, lane = tid & 63;
  const int wr = w >> 1, wc = w & 1;
  const int m0 = blockIdx.x * 128, n0 = blockIdx.y * 128;
  const int lrow = lane & 15, lko = (lane >> 4) * 8;
  f32x4 acc[4][4];
#pragma unroll
  for (int i = 0; i < 4; i++)
#pragma unroll
    for (int j = 0; j < 4; j++) acc[i][j] = (f32x4){0.f,0.f,0.f,0.f};
  for (int k0 = 0; k0 < DIMX; k0 += 32) {
    __syncthreads();
#pragma unroll
    for (int r = 0; r < 2; r++) {
      int e = r * 256 + tid;
      int row = e >> 2, seg = e & 3;
      glds16(hA + (size_t)(m0 + row) * DIMX + k0 + seg * 8, &As[row*32 + seg*8]);
      glds16(Wb + (size_t)(n0 + row) * DIMX + k0 + seg * 8, &Bs[row*32 + seg*8]);
    }
    __syncthreads();
    bf16x8 aF[4], bF[4];
#pragma unroll
    for (int i = 0; i < 4; i++)
      aF[i] = *(const bf16x8*)&As[(wr*64 + i*16 + lrow)*32 + lko];
#pragma unroll
    for (int j = 0; j < 4; j++)
      bF[j] = *(const bf16x8*)&Bs[(wc*64 + j*16 + lrow)*32 + lko];
#pragma unroll
    for (int i = 0; i < 4; i++)
#pragma unroll
      for (int j = 0; j < 4; j++)
        acc[i][j] = __builtin_amdgcn_mfma_f32_16x16x32_bf16(aF[i], bF[j], acc[i][j], 0, 0, 0);
  }
#pragma unroll
  for (int i = 0; i < 4; i++)
#pragma unroll
    for (int j = 0; j < 4; j++)
#pragma unroll
      for (int r = 0; r < 4; r++) {
        int m = m0 + wr*64 + i*16 + (lane>>4)*4 + r;
        int n = n0 + wc*64 + j*16 + lrow;
        xz[(size_t)m * E2 + n] = f2b(acc[i][j][r]);
      }
}

// ---------------- K4: conv + silu -> uB[ch][d>>4][t][16] (blocked) ------------
__global__ __launch_bounds__(256) void k_conv(const ushort_t* __restrict__ xz,
    const float* __restrict__ cwA, const float* __restrict__ cbA,
    ushort_t* __restrict__ uB) {
  __shared__ ushort_t xs[67][64];
  int ch = blockIdx.z, br = ch >> 1, b = ch & 1;
  int t0 = blockIdx.x * 64, d0 = blockIdx.y * 64;
  int tid = threadIdx.x, col = tid & 63, rg = tid >> 6;
  const float* cw = cwA + (size_t)br * DI * 4;
  const float* cb = cbA + (size_t)br * DI;
#pragma unroll
  for (int i = 0; i < 17; i++) {
    int row = rg + i * 4;
    if (row < 67) {
      int tau = t0 - 3 + row;
      ushort_t val = 0;
      if (tau >= 0) val = xz[((size_t)b * SEQ + pmap(br, tau)) * E2 + d0 + col];
      xs[row][col] = val;
    }
  }
  __syncthreads();
  int d = d0 + col;
  float w0 = cw[d*4+0], w1 = cw[d*4+1], w2 = cw[d*4+2], w3 = cw[d*4+3];
  float bias = cb[d];
  size_t dbbase = ((size_t)(ch * 64 + (d >> 4))) * SEQ;
#pragma unroll
  for (int i = 0; i < 16; i++) {
    int ti = rg + i * 4;
    float a = bias + w0*b2f(xs[ti][col]) + w1*b2f(xs[ti+1][col])
                   + w2*b2f(xs[ti+2][col]) + w3*b2f(xs[ti+3][col]);
    float val = a / (1.f + __expf(-a));
    uB[(dbbase + t0 + ti) * 16 + (col & 15)] = f2b(val);
  }
}

// ---------------- K4b: gate precompute -> zgB[b][d>>4][l][16] (blocked) -------
__global__ __launch_bounds__(256) void k_zg(const ushort_t* __restrict__ xz,
    const float* __restrict__ weff, ushort_t* __restrict__ zgB) {
  int b = blockIdx.z;
  int l0 = blockIdx.x * 64, d0 = blockIdx.y * 64;
  int tid = threadIdx.x, col = tid & 63, rg = tid >> 6;
  int d = d0 + col;
  float wef = weff[d];
  size_t dbbase = ((size_t)(b * 64 + (d >> 4))) * SEQ;
#pragma unroll
  for (int i = 0; i < 16; i++) {
    int l = l0 + rg + i * 4;
    float zr = b2f(xz[((size_t)b * SEQ + l) * E2 + DI + d]);
    float z = zr / (1.f + __expf(-zr));
    zgB[(dbbase + l) * 16 + (col & 15)] = f2b(z * wef);
  }
}

// ---------------- K5: x_dbl GEMM (reads blocked uB): xd[ch][t][64] ------------
__global__ __launch_bounds__(256) void k_xdbl(const ushort_t* __restrict__ uB,
    const ushort_t* __restrict__ xpwA, ushort_t* __restrict__ xdA) {
  __shared__ ushort_t As[64*32];
  __shared__ ushort_t Bs[64*32];
  int ch = blockIdx.y, br = ch >> 1;
  const ushort_t* xpw = xpwA + (size_t)br * KXP * DI;
  ushort_t* xd = xdA + (size_t)ch * SEQ * KXP;
  int t0 = blockIdx.x * 64;
  int tid = threadIdx.x, w = tid >> 6, lane = tid & 63;
  int lrow = lane & 15, lko = (lane >> 4) * 8;
  int row = tid >> 2, seg = tid & 3;
  f32x4 acc[4];
#pragma unroll
  for (int j = 0; j < 4; j++) acc[j] = (f32x4){0.f,0.f,0.f,0.f};
  for (int k0 = 0; k0 < DI; k0 += 32) {
    __syncthreads();
    glds16(uB + (((size_t)(ch*64 + (k0>>4) + (seg>>1)) * SEQ + t0 + row) * 16 + (seg&1)*8),
           &As[row*32 + seg*8]);
    glds16(xpw + (size_t)row * DI + k0 + seg * 8, &Bs[row*32 + seg*8]);
    __syncthreads();
    bf16x8 aF = *(const bf16x8*)&As[(w*16 + lrow)*32 + lko];
#pragma unroll
    for (int j = 0; j < 4; j++) {
      bf16x8 bF = *(const bf16x8*)&Bs[(j*16 + lrow)*32 + lko];
      acc[j] = __builtin_amdgcn_mfma_f32_16x16x32_bf16(aF, bF, acc[j], 0, 0, 0);
    }
  }
#pragma unroll
  for (int j = 0; j < 4; j++)
#pragma unroll
    for (int r = 0; r < 4; r++) {
      int t = t0 + w*16 + (lane>>4)*4 + r;
      xd[(size_t)t * KXP + j*16 + lrow] = f2b(acc[j][r]);
    }
}

// ---------------- K5b: expand xd B/C -> Bf/Cf[ch][n][t] f32 -------------------
__global__ __launch_bounds__(256) void k_bc(const ushort_t* __restrict__ xdA,
    float* __restrict__ Bf, float* __restrict__ Cf) {
  __shared__ float tb[128][34];
  int ch = blockIdx.y, t0 = blockIdx.x * 128;
  int tid = threadIdx.x;
  const ushort_t* xdb = xdA + (size_t)ch * SEQ * KXP;
#pragma unroll
  for (int i = 0; i < 2; i++) {
    int r = (tid >> 2) + i * 64;
    int q = tid & 3;
    const ushort_t* p = xdb + (size_t)(t0 + r) * KXP + 32 + q * 8;
    uint4 v = *(const uint4*)p;
    unsigned int wd[4] = {v.x, v.y, v.z, v.w};
    float* dst = &tb[r][q * 8];
#pragma unroll
    for (int j = 0; j < 4; j++) {
      dst[2*j]   = __uint_as_float(wd[j] << 16);
      dst[2*j+1] = __uint_as_float(wd[j] & 0xFFFF0000u);
    }
  }
  __syncthreads();
  int nn = tid >> 4, sg = tid & 15;
  float ob[8], oc[8];
#pragma unroll
  for (int j = 0; j < 8; j++) {
    ob[j] = tb[sg*8 + j][nn];
    oc[j] = tb[sg*8 + j][16 + nn];
  }
  float* Bp = Bf + ((size_t)ch * NST + nn) * SEQ + t0 + sg * 8;
  float* Cp = Cf + ((size_t)ch * NST + nn) * SEQ + t0 + sg * 8;
  *(float4*)Bp       = make_float4(ob[0],ob[1],ob[2],ob[3]);
  *(float4*)(Bp + 4) = make_float4(ob[4],ob[5],ob[6],ob[7]);
  *(float4*)Cp       = make_float4(oc[0],oc[1],oc[2],oc[3]);
  *(float4*)(Cp + 4) = make_float4(oc[4],oc[5],oc[6],oc[7]);
}

// ---------------- K6: delta GEMM (K=32) + softplus -> dltB (blocked) ----------
// grid (40 t-tiles, 8 d-tiles, 6 ch)
__global__ __launch_bounds__(256) void k_delta(const ushort_t* __restrict__ xdA,
    const ushort_t* __restrict__ dtwb, const float* __restrict__ dtbf,
    ushort_t* __restrict__ dltB) {
  __shared__ ushort_t As[128*32];
  __shared__ ushort_t Bs[128*32];
  int ch = blockIdx.z, br = ch >> 1;
  int t0 = blockIdx.x * 128, d0 = blockIdx.y * 128;
  int tid = threadIdx.x, w = tid >> 6, lane = tid & 63;
  int wr = w >> 1, wc = w & 1;
  int lrow = lane & 15, lko = (lane >> 4) * 8;
  const ushort_t* xdb = xdA + (size_t)ch * SEQ * KXP;
  const ushort_t* dwp = dtwb + (size_t)br * DI * DTR;
#pragma unroll
  for (int r = 0; r < 2; r++) {
    int e = r * 256 + tid;
    int row = e >> 2, seg = e & 3;
    glds16(xdb + (size_t)(t0 + row) * KXP + seg * 8, &As[row*32 + seg*8]);
    glds16(dwp + (size_t)(d0 + row) * DTR + seg * 8, &Bs[row*32 + seg*8]);
  }
  __syncthreads();
  bf16x8 aF[4], bF[4];
#pragma unroll
  for (int i = 0; i < 4; i++)
    aF[i] = *(const bf16x8*)&As[(wr*64 + i*16 + lrow)*32 + lko];
#pragma unroll
  for (int j = 0; j < 4; j++)
    bF[j] = *(const bf16x8*)&Bs[(wc*64 + j*16 + lrow)*32 + lko];
  f32x4 acc[4][4];
#pragma unroll
  for (int i = 0; i < 4; i++)
#pragma unroll
    for (int j = 0; j < 4; j++) {
      acc[i][j] = (f32x4){0.f,0.f,0.f,0.f};
      acc[i][j] = __builtin_amdgcn_mfma_f32_16x16x32_bf16(aF[i], bF[j], acc[i][j], 0, 0, 0);
    }
#pragma unroll
  for (int i = 0; i < 4; i++)
#pragma unroll
    for (int j = 0; j < 4; j++)
#pragma unroll
      for (int r = 0; r < 4; r++) {
        int t = t0 + wr*64 + i*16 + (lane>>4)*4 + r;
        int d = d0 + wc*64 + j*16 + lrow;
        float xv = acc[i][j][r] + dtbf[br * DI + d];
        float sp = (xv > 20.f) ? xv : log1pf(__expf(xv));
        dltB[(((size_t)(ch*64 + (d>>4))) * SEQ + t) * 16 + (d & 15)] = f2b(sp);
      }
}

// ---------------- K7a: segmented local scan (16 ch/wave, uint2 loads) ---------
// grid 1536 = ch(bid>>8) x seg((bid>>5)&7) x dblk(bid&31); 128-thr, 2 waves.
// Each wave owns a full 16-channel row-block (rb = dblk*2 + w); each lane owns
// 4 consecutive channels (uint2 per row read; 4 lanes/row tile the full 32B).
// Amortizes the channel-independent LDS work (B/C stage+reads, butterfly,
// atomics) over 16 ch: ~5.3 LDS-ops/ch vs 8.4 in the 8-ch/wave version.
__global__ __launch_bounds__(128, 4) void k_scan1(
    const ushort_t* __restrict__ dltB, const ushort_t* __restrict__ uB,
    const ushort_t* __restrict__ zgB, const float* __restrict__ Bf,
    const float* __restrict__ Cf, const float* __restrict__ alf,
    const float* __restrict__ ddf, float* __restrict__ sc,
    float* __restrict__ Hloc, float* __restrict__ Stot) {
  __shared__ __align__(16) float BS[2][16][18];
  __shared__ __align__(16) float CS[2][16][18];
  __shared__ __align__(16) float4 ddl[2][4][17];   // dlt[4ch]
  __shared__ __align__(16) float4 ddu[2][4][17];   // du[4ch]
  __shared__ __align__(16) float4 gS4[2][4][17];   // gate[4ch]
  int bid = blockIdx.x;
  int dblk = bid & 31, seg = (bid >> 5) & 7, ch = bid >> 8;
  int br = ch >> 1, b = ch & 1;
  int tid = threadIdx.x, w = tid >> 6, lane = tid & 63, g = lane >> 4, n = lane & 15;
  int rb = dblk * 2 + w;             // 16-wide row-block owned by this wave
  int dqb = rb * 16 + g * 4;         // global d of this lane's first channel
  const float L2E = 1.4426950408889634f;
  float Ap[4], Dd[4];
#pragma unroll
  for (int q = 0; q < 4; q++) {
    Ap[q] = -__expf(alf[br * (DI*NST) + (dqb + q) * NST + n]) * L2E;
    Dd[q] = ddf[br * DI + dqb + q];
  }
  const ushort_t* dlp = dltB + ((size_t)(ch * 64 + rb) * SEQ) * 16;
  const ushort_t* uBp = uB   + ((size_t)(ch * 64 + rb) * SEQ) * 16;
  const ushort_t* zgp = zgB  + ((size_t)(b  * 64 + rb) * SEQ) * 16;
  const float* Bfp = Bf + ((size_t)ch * NST) * SEQ;
  const float* Cfp = Cf + ((size_t)ch * NST) * SEQ;
  float* srow = sc + (size_t)b * SEQ;
  float hst[4] = {0.f, 0.f, 0.f, 0.f};
  float Sacc[4] = {0.f, 0.f, 0.f, 0.f};
  int sn = lane >> 2, sq = lane & 3;
  for (int t0 = seg * SEGL; t0 < seg * SEGL + SEGL; t0 += 16) {
    // stage B/C window (per-wave copy; wave-lockstep, no sync needed)
    *(float4*)&BS[w][sn][sq*4] = *(const float4*)&Bfp[(size_t)sn * SEQ + t0 + sq*4];
    *(float4*)&CS[w][sn][sq*4] = *(const float4*)&Cfp[(size_t)sn * SEQ + t0 + sq*4];
    size_t rowo = (size_t)(t0 + n) * 16 + g * 4;
    uint2 dv = *(const uint2*)(dlp + rowo);
    uint2 uv = *(const uint2*)(uBp + rowo);
    uint2 zv = *(const uint2*)(zgp + (size_t)pmap(br, t0 + n) * 16 + g * 4);
    float dl0 = b2f((ushort_t)(dv.x & 0xFFFF)), dl1 = b2f((ushort_t)(dv.x >> 16));
    float dl2 = b2f((ushort_t)(dv.y & 0xFFFF)), dl3 = b2f((ushort_t)(dv.y >> 16));
    float u0 = b2f((ushort_t)(uv.x & 0xFFFF)), u1 = b2f((ushort_t)(uv.x >> 16));
    float u2 = b2f((ushort_t)(uv.y & 0xFFFF)), u3 = b2f((ushort_t)(uv.y >> 16));
    float gz0 = b2f((ushort_t)(zv.x & 0xFFFF)), gz1 = b2f((ushort_t)(zv.x >> 16));
    float gz2 = b2f((ushort_t)(zv.y & 0xFFFF)), gz3 = b2f((ushort_t)(zv.y >> 16));
    Sacc[0] += dl0; Sacc[1] += dl1; Sacc[2] += dl2; Sacc[3] += dl3;
    ddl[w][g][n] = make_float4(dl0, dl1, dl2, dl3);
    ddu[w][g][n] = make_float4(dl0*u0, dl1*u1, dl2*u2, dl3*u3);
    gS4[w][g][n] = make_float4(gz0, gz1, gz2, gz3);
    float dug = fmaf(Dd[0]*u0, gz0, fmaf(Dd[1]*u1, gz1,
                fmaf(Dd[2]*u2, gz2, Dd[3]*u3*gz3)));
    float Bk[16], Ck[16];
#pragma unroll
    for (int j = 0; j < 4; j++) {
      *(float4*)&Bk[j*4] = *(const float4*)&BS[w][n][j*4];
      *(float4*)&Ck[j*4] = *(const float4*)&CS[w][n][j*4];
    }
    float hC[16];
#pragma unroll
    for (int k = 0; k < 16; k++) {
      float4 L = ddl[w][g][k];
      float4 U = ddu[w][g][k];
      float4 G = gS4[w][g][k];
      hst[0] = fmaf(__builtin_amdgcn_exp2f(L.x * Ap[0]), hst[0], U.x * Bk[k]);
      hst[1] = fmaf(__builtin_amdgcn_exp2f(L.y * Ap[1]), hst[1], U.y * Bk[k]);
      hst[2] = fmaf(__builtin_amdgcn_exp2f(L.z * Ap[2]), hst[2], U.z * Bk[k]);
      hst[3] = fmaf(__builtin_amdgcn_exp2f(L.w * Ap[3]), hst[3], U.w * Bk[k]);
      hC[k] = fmaf(hst[0], G.x, fmaf(hst[1], G.y,
               fmaf(hst[2], G.z, hst[3] * G.w))) * Ck[k];
    }
    float y = bfly16(hC, n) + dug;     // all 4 channels of this lane, gated
    y += __shfl_xor(y, 16, 64);        // + across g (4 groups = 16 channels)
    y += __shfl_xor(y, 32, 64);
    if (lane < 16) atomicAdd(srow + omap(br, t0 + lane), y);
  }
#pragma unroll
  for (int q = 0; q < 4; q++)
    Hloc[(((size_t)ch * NSEG + seg) * 1024 + dqb + q) * 16 + n] = hst[q];
#pragma unroll
  for (int m = 1; m < 16; m <<= 1) {
    Sacc[0] += __shfl_xor(Sacc[0], m, 64);
    Sacc[1] += __shfl_xor(Sacc[1], m, 64);
    Sacc[2] += __shfl_xor(Sacc[2], m, 64);
    Sacc[3] += __shfl_xor(Sacc[3], m, 64);
  }
  if (n == 0) {
#pragma unroll
    for (int q = 0; q < 4; q++)
      Stot[((size_t)ch * NSEG + seg) * 1024 + dqb + q] = Sacc[q];
  }
}

// ---------------- K7b: stitch segment states ----------------------------------
__global__ __launch_bounds__(256) void k_stitch(const float* __restrict__ Stot,
    const float* __restrict__ Hloc, const float* __restrict__ alf,
    float* __restrict__ Hin) {
  int idx = blockIdx.x * 256 + threadIdx.x;     // 98304 = 6*1024*16
  int ch = idx >> 14, rem = idx & 16383, d = rem >> 4, n = rem & 15;
  int br = ch >> 1;
  float A = -__expf(alf[(size_t)br * (DI*NST) + d * NST + n]);
  float h = 0.f;
  for (int s = 0; s < NSEG; s++) {
    size_t base = ((size_t)ch * NSEG + s) * 1024 + d;
    Hin[base * 16 + n] = h;
    h = __expf(A * Stot[base]) * h + Hloc[base * 16 + n];
  }
}

// ---------------- K7c: carry correction (16-d group blocks, uint2 loads) ------
// grid (384, 7): x = ch*64 + grp, y = seg-1 (validated R14).
__global__ __launch_bounds__(256, 2) void k_scan2(
    const ushort_t* __restrict__ zgB, const ushort_t* __restrict__ dltB,
    const float* __restrict__ Cf, const float* __restrict__ alf,
    const float* __restrict__ Hin, float* __restrict__ sc) {
  __shared__ float red[4][72];
  int ch = blockIdx.x >> 6, grp = blockIdx.x & 63;
  int seg = blockIdx.y + 1;
  int br = ch >> 1, b = ch & 1;
  int tid = threadIdx.x, w = tid >> 6, lane = tid & 63;
  int dsub4 = w * 4;                 // in-row offset (d & 15)
  int dbase = grp * 16 + dsub4;      // global d of this wave's first channel
  const float L2E = 1.4426950408889634f;
  float A2[4][16], Hn[4][16];
#pragma unroll
  for (int q = 0; q < 4; q++) {
    int d = dbase + q;
#pragma unroll
    for (int nn = 0; nn < 16; nn++)
      A2[q][nn] = -__expf(alf[(size_t)br * (DI*NST) + d * NST + nn]) * L2E;
    const float* hp = Hin + (((size_t)ch * NSEG + seg) * 1024 + d) * 16;
#pragma unroll
    for (int nn = 0; nn < 16; nn++) Hn[q][nn] = hp[nn];
  }
  const ushort_t* dlp = dltB + ((size_t)(ch * 64 + grp) * SEQ) * 16;
  const ushort_t* zgp = zgB  + ((size_t)(b  * 64 + grp) * SEQ) * 16;
  const float* Cfp = Cf + (size_t)ch * NST * SEQ;
  float* srow = sc + (size_t)b * SEQ;
  float c0 = 0.f, c1 = 0.f, c2 = 0.f, c3 = 0.f;   // per-d carries
  for (int w0 = seg * SEGL; w0 < seg * SEGL + SEGL; w0 += 64) {
    int t = w0 + lane;
    uint2 dv = *(const uint2*)(dlp + (size_t)t * 16 + dsub4);
    float S0 = b2f((ushort_t)(dv.x & 0xFFFF));
    float S1 = b2f((ushort_t)(dv.x >> 16));
    float S2 = b2f((ushort_t)(dv.y & 0xFFFF));
    float S3 = b2f((ushort_t)(dv.y >> 16));
#pragma unroll
    for (int ofs = 1; ofs < 64; ofs <<= 1) {
      float v0 = __shfl_up(S0, ofs, 64);
      float v1 = __shfl_up(S1, ofs, 64);
      float v2 = __shfl_up(S2, ofs, 64);
      float v3 = __shfl_up(S3, ofs, 64);
      if (lane >= ofs) { S0 += v0; S1 += v1; S2 += v2; S3 += v3; }
    }
    float t0_ = __shfl(S0, 63, 64), t1_ = __shfl(S1, 63, 64);
    float t2_ = __shfl(S2, 63, 64), t3_ = __shfl(S3, 63, 64);
    S0 += c0; c0 += t0_;
    S1 += c1; c1 += t1_;
    S2 += c2; c2 += t2_;
    S3 += c3; c3 += t3_;
    float r0 = 0.f, r1 = 0.f, r2 = 0.f, r3 = 0.f;
#pragma unroll
    for (int nn = 0; nn < 16; nn++) {
      float Cn = Cfp[(size_t)nn * SEQ + t];
      r0 = fmaf(Cn * Hn[0][nn], __builtin_amdgcn_exp2f(A2[0][nn] * S0), r0);
      r1 = fmaf(Cn * Hn[1][nn], __builtin_amdgcn_exp2f(A2[1][nn] * S1), r1);
      r2 = fmaf(Cn * Hn[2][nn], __builtin_amdgcn_exp2f(A2[2][nn] * S2), r2);
      r3 = fmaf(Cn * Hn[3][nn], __builtin_amdgcn_exp2f(A2[3][nn] * S3), r3);
    }
    uint2 zv = *(const uint2*)(zgp + (size_t)pmap(br, t) * 16 + dsub4);
    float g0 = b2f((ushort_t)(zv.x & 0xFFFF));
    float g1 = b2f((ushort_t)(zv.x >> 16));
    float g2 = b2f((ushort_t)(zv.y & 0xFFFF));
    float g3 = b2f((ushort_t)(zv.y >> 16));
    float y = fmaf(r0, g0, fmaf(r1, g1, fmaf(r2, g2, r3 * g3)));
    red[w][lane] = y;
    __syncthreads();
    if (w == 0) {
      float ytot = red[0][lane] + red[1][lane] + red[2][lane] + red[3][lane];
      atomicAdd(srow + omap(br, t), ytot);
    }
    __syncthreads();
  }
}

// ---------------- K8: w_eff[d] = lin_w . out_proj_w[:,d]; zero score_acc ------
__global__ __launch_bounds__(256) void k_weff_init(const ushort_t* __restrict__ opwb,
    const ushort_t* __restrict__ lwb, float* __restrict__ weff, float* __restrict__ sc) {
  int i = blockIdx.x * 256 + threadIdx.x;
  if (i < DI) {
    float s = 0.f;
    for (int o = 0; o < DIMX; o++) s += b2f(lwb[o]) * b2f(opwb[(size_t)o * DI + i]);
    weff[i] = s;
  }
  int j = i - DI;
  if (j >= 0 && j < 2 * SEQ) sc[j] = 0.f;
}

// ---------------- K9: outputs (f32): group interp+sigmoid, individual ---------
__global__ __launch_bounds__(256) void k_out(const float* __restrict__ g0,
    const float* __restrict__ g1, const float* __restrict__ g2,
    const float* __restrict__ sc, const float* __restrict__ lbf,
    float* __restrict__ out) {
  int idx = blockIdx.x * 256 + threadIdx.x;
  if (idx < 3 * SEQ) {
    int j = idx / SEQ, t = idx % SEQ;
    const float* g = (j == 0) ? g0 : (j == 1) ? g1 : g2;
    float pos = t * ((float)(LGS - 1) / (float)(SEQ - 1));
    int i0 = (int)floorf(pos);
    if (i0 < 0) i0 = 0; if (i0 > LGS - 2) i0 = LGS - 2;
    float wt = pos - (float)i0;
    float v = g[i0] * (1.f - wt) + g[i0 + 1] * wt;
    out[idx] = 1.f / (1.f + __expf(-v));
  } else if (idx < 5 * SEQ) {
    float t = sc[idx - 3 * SEQ] + lbf[0];
    out[idx] = 1.f / (1.f + __expf(-t));
  }
}

extern "C" void kernel_launch(void* const* d_in, const int* in_sizes, int n_in,
                              void* d_out, int out_size, void* d_ws, size_t ws_size,
                              hipStream_t stream) {
  char* ws = (char*)d_ws;
  ushort_t* lwb   = (ushort_t*)(ws + OFF_LWB);
  float*    lngf  = (float*)(ws + OFF_LNGF);
  float*    lnbf  = (float*)(ws + OFF_LNBF);
  float*    lbf   = (float*)(ws + OFF_LBF);
  float*    cwf   = (float*)(ws + OFF_CWF);
  float*    cbf   = (float*)(ws + OFF_CBF);
  float*    dtbf  = (float*)(ws + OFF_DTBF);
  float*    alf   = (float*)(ws + OFF_ALF);
  float*    ddf   = (float*)(ws + OFF_DDF);
  float*    weff  = (float*)(ws + OFF_WEFF);
  float*    sc    = (float*)(ws + OFF_SC);
  ushort_t* dtwb  = (ushort_t*)(ws + OFF_DTWB);
  ushort_t* xpwb  = (ushort_t*)(ws + OFF_XPWB);
  ushort_t* opwb  = (ushort_t*)(ws + OFF_OPWB);
  ushort_t* inwb  = (ushort_t*)(ws + OFF_INWB);
  ushort_t* xd    = (ushort_t*)(ws + OFF_XD);
  ushort_t* dltB  = (ushort_t*)(ws + OFF_DLTB);
  ushort_t* xz    = (ushort_t*)(ws + OFF_XZ);
  float*    Bf    = (float*)(ws + OFF_BF);
  float*    Cf    = (float*)(ws + OFF_CF);
  ushort_t* uB    = (ushort_t*)(ws + OFF_UB);
  ushort_t* h     = (ushort_t*)(ws + OFF_H);
  ushort_t* zgB   = (ushort_t*)(ws + OFF_ZGB);
  float*    Hloc  = (float*)(ws + OFF_HLOC);
  float*    Hin   = (float*)(ws + OFF_HIN);
  float*    Stot  = (float*)(ws + OFF_STOT);
  float*    OUT   = (float*)d_out;

  Tab tab;
  int c = 0;
  tab.e[c++] = {d_in[3], inwb, E2 * DIMX, 0};
  tab.e[c++] = {d_in[4], opwb, DIMX * DI, 0};
  tab.e[c++] = {d_in[5], lwb, DIMX, 0};
  for (int br = 0; br < 3; br++) {
    int base = 10 + br * 7;
    tab.e[c++] = {d_in[base + 2], xpwb + (size_t)br * KXP * DI, KXP * DI, 0};
    tab.e[c++] = {d_in[base + 3], dtwb + (size_t)br * DI * DTR, DI * DTR, 0};
  }
  tab.e[c++] = {d_in[1], lngf, DIMX, 1};
  tab.e[c++] = {d_in[2], lnbf, DIMX, 1};
  tab.e[c++] = {d_in[6], lbf, 1, 1};
  for (int br = 0; br < 3; br++) {
    int base = 10 + br * 7;
    tab.e[c++] = {d_in[base + 0], cwf + (size_t)br * DI * 4, DI * 4, 1};
    tab.e[c++] = {d_in[base + 1], cbf + (size_t)br * DI, DI, 1};
    tab.e[c++] = {d_in[base + 4], dtbf + (size_t)br * DI, DI, 1};
    tab.e[c++] = {d_in[base + 5], alf + (size_t)br * DI * NST, DI * NST, 1};
    tab.e[c++] = {d_in[base + 6], ddf + (size_t)br * DI, DI, 1};
  }

  dim3 blk(256);
  k_import<<<dim3(64, c), blk, 0, stream>>>(tab, c);
  k_weff_init<<<44, blk, 0, stream>>>(opwb, lwb, weff, sc);
  k_ln<<<2560, blk, 0, stream>>>((const float*)d_in[0], lngf, lnbf, h);
  k_inproj<<<dim3(80, 16), blk, 0, stream>>>(h, inwb, xz);
  k_conv<<<dim3(80, 16, 6), blk, 0, stream>>>(xz, cwf, cbf, uB);
  k_zg<<<dim3(80, 16, 2), blk, 0, stream>>>(xz, weff, zgB);
  k_xdbl<<<dim3(80, 6), blk, 0, stream>>>(uB, xpwb, xd);
  k_bc<<<dim3(40, 6), blk, 0, stream>>>(xd, Bf, Cf);
  k_delta<<<dim3(40, 8, 6), blk, 0, stream>>>(xd, dtwb, dtbf, dltB);   // xz dead now
  k_scan1<<<1536, dim3(128), 0, stream>>>(dltB, uB, zgB, Bf, Cf, alf, ddf,
                                          sc, Hloc, Stot);
  k_stitch<<<384, blk, 0, stream>>>(Stot, Hloc, alf, Hin);
  k_scan2<<<dim3(384, NSEG - 1), blk, 0, stream>>>(zgB, dltB, Cf, alf, Hin, sc);
  k_out<<<100, blk, 0, stream>>>((const float*)d_in[7], (const float*)d_in[8],
                                 (const float*)d_in[9], sc, lbf, OUT);
}